// Round 1
// baseline (699.446 us; speedup 1.0000x reference)
//
#include <hip/hip_runtime.h>
#include <hip/hip_bf16.h>
#include <math.h>

// TAGConv GNN: N=50000 nodes, E=800000 edges, K=3 hops, 3 layers (8->64, 64->64, 64->10)
// Strategy: build CSR (dst-sorted) once per call, run all propagations as
// atomic-free gather kernels; small GEMMs with LDS-staged W.

#define NN 50000
#define EE 800000
#define FX 6
#define FPOS 2
#define FIN0 8
#define HID 64
#define OUT 10

// ---------------- degree / counts ----------------
__global__ __launch_bounds__(256) void deg_kernel(const int* __restrict__ dst,
                                                  const float* __restrict__ ea,
                                                  float* __restrict__ deg,
                                                  int* __restrict__ cnt, int e) {
    int i = blockIdx.x * blockDim.x + threadIdx.x;
    if (i >= e) return;
    int d = dst[i];
    atomicAdd(&deg[d], ea[i]);
    atomicAdd(&cnt[d], 1);
}

__global__ __launch_bounds__(256) void dinv_kernel(float* __restrict__ deg, int n) {
    int i = blockIdx.x * blockDim.x + threadIdx.x;
    if (i >= n) return;
    float v = deg[i];
    deg[i] = (v > 0.f) ? rsqrtf(v) : 0.f;
}

// ---------------- exclusive scan (single block, 1024 threads) ----------------
__global__ __launch_bounds__(1024) void scan_kernel(const int* __restrict__ cnt,
                                                    int* __restrict__ row_start,
                                                    int* __restrict__ cursor, int n) {
    __shared__ int wsum[16];
    __shared__ int carry_s;
    int tid = threadIdx.x;
    int lane = tid & 63, wid = tid >> 6;
    if (tid == 0) carry_s = 0;
    __syncthreads();
    for (int base = 0; base < n; base += 1024) {
        int i = base + tid;
        int v = (i < n) ? cnt[i] : 0;
        // wave-level inclusive scan
        int x = v;
        for (int off = 1; off < 64; off <<= 1) {
            int y = __shfl_up(x, off, 64);
            if (lane >= off) x += y;
        }
        if (lane == 63) wsum[wid] = x;
        __syncthreads();
        if (wid == 0 && lane < 16) {
            int s = wsum[lane];
            for (int off = 1; off < 16; off <<= 1) {
                int y = __shfl_up(s, off, 64);
                if (lane >= off) s += y;
            }
            wsum[lane] = s; // inclusive over wave sums
        }
        __syncthreads();
        int woff = (wid == 0) ? 0 : wsum[wid - 1];
        int excl = (x - v) + woff;
        int carry = carry_s;
        if (i < n) {
            int rs = carry + excl;
            row_start[i] = rs;
            cursor[i] = rs;
        }
        int total = wsum[15];
        __syncthreads();
        if (tid == 0) carry_s = carry + total;
        __syncthreads();
    }
    if (threadIdx.x == 0) row_start[n] = carry_s;
}

// ---------------- CSR scatter (also computes norm inline) ----------------
__global__ __launch_bounds__(256) void scatter_kernel(const int* __restrict__ src,
                                                      const int* __restrict__ dst,
                                                      const float* __restrict__ ea,
                                                      const float* __restrict__ dinv,
                                                      int* __restrict__ cursor,
                                                      int* __restrict__ csr_src,
                                                      float* __restrict__ csr_norm, int e) {
    int i = blockIdx.x * blockDim.x + threadIdx.x;
    if (i >= e) return;
    int s = src[i], d = dst[i];
    int pos = atomicAdd(&cursor[d], 1);
    csr_src[pos] = s;
    csr_norm[pos] = dinv[s] * ea[i] * dinv[d];
}

// ---------------- concat x,pos -> h0 (N x 8) ----------------
__global__ __launch_bounds__(256) void concat_kernel(const float* __restrict__ x,
                                                     const float* __restrict__ pos,
                                                     float* __restrict__ h0, int n) {
    int t = blockIdx.x * blockDim.x + threadIdx.x;
    if (t >= n * FIN0) return;
    int nd = t / FIN0, j = t % FIN0;
    h0[t] = (j < FX) ? x[nd * FX + j] : pos[nd * FPOS + (j - FX)];
}

// ---------------- propagation: hout[n] = sum_{e: dst=n} norm[e]*hin[src[e]] ----------------
template <int F>
__global__ __launch_bounds__(256) void prop_kernel(const int* __restrict__ row_start,
                                                   const int* __restrict__ csr_src,
                                                   const float* __restrict__ csr_norm,
                                                   const float* __restrict__ hin,
                                                   float* __restrict__ hout, int n) {
    constexpr int TPN = F / 4; // threads per node, each handles 4 floats
    int t = blockIdx.x * blockDim.x + threadIdx.x;
    int node = t / TPN;
    int lane = t % TPN;
    if (node >= n) return;
    int beg = row_start[node], end = row_start[node + 1];
    float4 acc = make_float4(0.f, 0.f, 0.f, 0.f);
    for (int i = beg; i < end; ++i) {
        int s = csr_src[i];
        float w = csr_norm[i];
        const float4 v = *reinterpret_cast<const float4*>(hin + (size_t)s * F + lane * 4);
        acc.x += w * v.x;
        acc.y += w * v.y;
        acc.z += w * v.z;
        acc.w += w * v.w;
    }
    *reinterpret_cast<float4*>(hout + (size_t)node * F + lane * 4) = acc;
}

// ---------------- small GEMM: out[(n,FOUT)] (+)= h[(n,FIN)] @ W[(FIN,FOUT)] ----------------
template <int FIN, int FOUT, bool ACCUM>
__global__ __launch_bounds__(256) void matmul_kernel(const float* __restrict__ h,
                                                     const float* __restrict__ W,
                                                     float* __restrict__ out, int n) {
    __shared__ float Ws[FIN * FOUT];
    __shared__ float Hs[32 * FIN];
    int tid = threadIdx.x;
    int nodeBase = blockIdx.x * 32;
    for (int i = tid; i < FIN * FOUT; i += 256) Ws[i] = W[i];
    for (int i = tid; i < 32 * FIN; i += 256) {
        int nd = nodeBase + i / FIN;
        Hs[i] = (nd < n) ? h[(size_t)nd * FIN + (i % FIN)] : 0.f;
    }
    __syncthreads();
    if constexpr ((FOUT % 4) == 0) {
        constexpr int OV = FOUT / 4;
        for (int o = tid; o < 32 * OV; o += 256) {
            int nd = o / OV, f4 = o % OV;
            float4 acc = make_float4(0.f, 0.f, 0.f, 0.f);
            const float* hr = &Hs[nd * FIN];
            #pragma unroll
            for (int i = 0; i < FIN; ++i) {
                float hv = hr[i];
                const float4 w = *reinterpret_cast<const float4*>(&Ws[i * FOUT + f4 * 4]);
                acc.x += hv * w.x;
                acc.y += hv * w.y;
                acc.z += hv * w.z;
                acc.w += hv * w.w;
            }
            int gnd = nodeBase + nd;
            if (gnd < n) {
                float4* po = reinterpret_cast<float4*>(out + (size_t)gnd * FOUT + f4 * 4);
                if (ACCUM) {
                    float4 old = *po;
                    acc.x += old.x; acc.y += old.y; acc.z += old.z; acc.w += old.w;
                }
                *po = acc;
            }
        }
    } else {
        for (int o = tid; o < 32 * FOUT; o += 256) {
            int nd = o / FOUT, f = o % FOUT;
            float acc = 0.f;
            #pragma unroll
            for (int i = 0; i < FIN; ++i) acc += Hs[nd * FIN + i] * Ws[i * FOUT + f];
            int gnd = nodeBase + nd;
            if (gnd < n) {
                float* po = out + (size_t)gnd * FOUT + f;
                *po = ACCUM ? (*po + acc) : acc;
            }
        }
    }
}

// ---------------- epilogues ----------------
__global__ __launch_bounds__(256) void bias_relu_kernel(float* __restrict__ h,
                                                        const float* __restrict__ b,
                                                        int total, int f) {
    int t = blockIdx.x * blockDim.x + threadIdx.x;
    if (t >= total) return;
    float v = h[t] + b[t % f];
    h[t] = v > 0.f ? v : 0.f;
}

__global__ __launch_bounds__(256) void logsoftmax_kernel(const float* __restrict__ acc,
                                                         const float* __restrict__ b,
                                                         float* __restrict__ out, int n) {
    int i = blockIdx.x * blockDim.x + threadIdx.x;
    if (i >= n) return;
    float v[OUT];
    float m = -1e30f;
    #pragma unroll
    for (int j = 0; j < OUT; ++j) {
        v[j] = acc[i * OUT + j] + b[j];
        m = fmaxf(m, v[j]);
    }
    float s = 0.f;
    #pragma unroll
    for (int j = 0; j < OUT; ++j) s += expf(v[j] - m);
    float ls = logf(s);
    #pragma unroll
    for (int j = 0; j < OUT; ++j) out[i * OUT + j] = v[j] - m - ls;
}

extern "C" void kernel_launch(void* const* d_in, const int* in_sizes, int n_in,
                              void* d_out, int out_size, void* d_ws, size_t ws_size,
                              hipStream_t stream) {
    const float* x   = (const float*)d_in[0];   // (N,6)
    const float* pos = (const float*)d_in[1];   // (N,2)
    const float* ea  = (const float*)d_in[2];   // (E,)
    const float* W1  = (const float*)d_in[3];   // (4,8,64)
    const float* b1  = (const float*)d_in[4];   // (64,)
    const float* W2  = (const float*)d_in[5];   // (4,64,64)
    const float* b2  = (const float*)d_in[6];   // (64,)
    const float* W3  = (const float*)d_in[7];   // (4,64,10)
    const float* b3  = (const float*)d_in[8];   // (10,)
    const int* eidx  = (const int*)d_in[9];     // (2,E) int32
    const int* src = eidx;
    const int* dst = eidx + EE;
    float* outp = (float*)d_out;

    // workspace carve-up
    size_t off = 0;
    char* base = (char*)d_ws;
    auto alloc = [&](size_t bytes) -> void* {
        void* p = base + off;
        off += (bytes + 255) & ~(size_t)255;
        return p;
    };
    float* deg      = (float*)alloc(NN * 4);          // -> dinv in place
    int*   cnt      = (int*)alloc(NN * 4);
    int*   row_start= (int*)alloc((NN + 1) * 4);
    int*   cursor   = (int*)alloc(NN * 4);
    int*   csr_src  = (int*)alloc((size_t)EE * 4);
    float* csr_norm = (float*)alloc((size_t)EE * 4);
    float* h0       = (float*)alloc((size_t)NN * FIN0 * 4);
    float* pA       = (float*)alloc((size_t)NN * FIN0 * 4);
    float* pB       = (float*)alloc((size_t)NN * FIN0 * 4);
    float* bufA     = (float*)alloc((size_t)NN * HID * 4);
    float* bufB     = (float*)alloc((size_t)NN * HID * 4);
    float* bufC     = (float*)alloc((size_t)NN * HID * 4);
    float* bufD     = (float*)alloc((size_t)NN * HID * 4);
    float* accS     = (float*)alloc((size_t)NN * OUT * 4);
    (void)ws_size;

    const int B = 256;
    const int gE = (EE + B - 1) / B;
    const int gN = (NN + B - 1) / B;
    const int gMM = (NN + 31) / 32;

    hipMemsetAsync(deg, 0, NN * 4, stream);
    hipMemsetAsync(cnt, 0, NN * 4, stream);

    deg_kernel<<<gE, B, 0, stream>>>(dst, ea, deg, cnt, EE);
    dinv_kernel<<<gN, B, 0, stream>>>(deg, NN);
    scan_kernel<<<1, 1024, 0, stream>>>(cnt, row_start, cursor, NN);
    scatter_kernel<<<gE, B, 0, stream>>>(src, dst, ea, deg, cursor, csr_src, csr_norm, EE);
    concat_kernel<<<(NN * FIN0 + B - 1) / B, B, 0, stream>>>(x, pos, h0, NN);

    const int gP8  = (NN * (FIN0 / 4) + B - 1) / B;   // TPN=2
    const int gP64 = (NN * (HID / 4) + B - 1) / B;    // TPN=16

    // ---- layer 1: (N,8) -> (N,64), acc in bufC ----
    matmul_kernel<FIN0, HID, false><<<gMM, B, 0, stream>>>(h0, W1 + 0 * FIN0 * HID, bufC, NN);
    prop_kernel<FIN0><<<gP8, B, 0, stream>>>(row_start, csr_src, csr_norm, h0, pA, NN);
    matmul_kernel<FIN0, HID, true><<<gMM, B, 0, stream>>>(pA, W1 + 1 * FIN0 * HID, bufC, NN);
    prop_kernel<FIN0><<<gP8, B, 0, stream>>>(row_start, csr_src, csr_norm, pA, pB, NN);
    matmul_kernel<FIN0, HID, true><<<gMM, B, 0, stream>>>(pB, W1 + 2 * FIN0 * HID, bufC, NN);
    prop_kernel<FIN0><<<gP8, B, 0, stream>>>(row_start, csr_src, csr_norm, pB, pA, NN);
    matmul_kernel<FIN0, HID, true><<<gMM, B, 0, stream>>>(pA, W1 + 3 * FIN0 * HID, bufC, NN);
    bias_relu_kernel<<<(NN * HID + B - 1) / B, B, 0, stream>>>(bufC, b1, NN * HID, HID);

    // ---- layer 2: (N,64) -> (N,64), input bufC, acc in bufD ----
    matmul_kernel<HID, HID, false><<<gMM, B, 0, stream>>>(bufC, W2 + 0 * HID * HID, bufD, NN);
    prop_kernel<HID><<<gP64, B, 0, stream>>>(row_start, csr_src, csr_norm, bufC, bufA, NN);
    matmul_kernel<HID, HID, true><<<gMM, B, 0, stream>>>(bufA, W2 + 1 * HID * HID, bufD, NN);
    prop_kernel<HID><<<gP64, B, 0, stream>>>(row_start, csr_src, csr_norm, bufA, bufB, NN);
    matmul_kernel<HID, HID, true><<<gMM, B, 0, stream>>>(bufB, W2 + 2 * HID * HID, bufD, NN);
    prop_kernel<HID><<<gP64, B, 0, stream>>>(row_start, csr_src, csr_norm, bufB, bufA, NN);
    matmul_kernel<HID, HID, true><<<gMM, B, 0, stream>>>(bufA, W2 + 3 * HID * HID, bufD, NN);
    bias_relu_kernel<<<(NN * HID + B - 1) / B, B, 0, stream>>>(bufD, b2, NN * HID, HID);

    // ---- layer 3: (N,64) -> (N,10), input bufD, acc in accS ----
    matmul_kernel<HID, OUT, false><<<gMM, B, 0, stream>>>(bufD, W3 + 0 * HID * OUT, accS, NN);
    prop_kernel<HID><<<gP64, B, 0, stream>>>(row_start, csr_src, csr_norm, bufD, bufA, NN);
    matmul_kernel<HID, OUT, true><<<gMM, B, 0, stream>>>(bufA, W3 + 1 * HID * OUT, accS, NN);
    prop_kernel<HID><<<gP64, B, 0, stream>>>(row_start, csr_src, csr_norm, bufA, bufB, NN);
    matmul_kernel<HID, OUT, true><<<gMM, B, 0, stream>>>(bufB, W3 + 2 * HID * OUT, accS, NN);
    prop_kernel<HID><<<gP64, B, 0, stream>>>(row_start, csr_src, csr_norm, bufB, bufA, NN);
    matmul_kernel<HID, OUT, true><<<gMM, B, 0, stream>>>(bufA, W3 + 3 * HID * OUT, accS, NN);
    logsoftmax_kernel<<<gN, B, 0, stream>>>(accS, b3, outp, NN);
}

// Round 2
// 601.100 us; speedup vs baseline: 1.1636x; 1.1636x over previous
//
#include <hip/hip_runtime.h>
#include <math.h>

// TAGConv GNN: N=50000, E=800000, K=3, layers (8->64, 64->64, 64->10)
// v2: single-atomic counting + packed CSR records, Horner for layer 3
// (props at width 16 instead of 64), LDS-staged edge records in props,
// fused per-layer matmul (P[h,Ah,A2h,A3h] @ W) with bias+relu epilogue,
// fused bias+log-softmax into the final propagation.

#define NN 50000
#define EE 800000
#define HID 64
#define NOUT 10
#define CH 512

// ---------------- count in-degree (1 atomic per edge) ----------------
__global__ __launch_bounds__(256) void cnt_kernel(const int* __restrict__ dst,
                                                  int* __restrict__ cnt, int e) {
    int i = blockIdx.x * blockDim.x + threadIdx.x;
    if (i < e) atomicAdd(&cnt[dst[i]], 1);
}

// ---------------- exclusive scan, coarsened 4x (single block) ----------------
__global__ __launch_bounds__(1024) void scan_kernel(const int* __restrict__ cnt,
                                                    int* __restrict__ row_start,
                                                    int* __restrict__ cursor, int n) {
    __shared__ int wsum[16];
    __shared__ int carry_s;
    int tid = threadIdx.x;
    int lane = tid & 63, wid = tid >> 6;
    if (tid == 0) carry_s = 0;
    __syncthreads();
    for (int base = 0; base < n; base += 4096) {
        int idx = base + tid * 4;
        int4 v = make_int4(0, 0, 0, 0);
        if (idx + 3 < n) {
            v = *reinterpret_cast<const int4*>(cnt + idx);
        } else {
            if (idx < n)     v.x = cnt[idx];
            if (idx + 1 < n) v.y = cnt[idx + 1];
            if (idx + 2 < n) v.z = cnt[idx + 2];
        }
        int t = v.x + v.y + v.z + v.w;
        int x = t;
        for (int off = 1; off < 64; off <<= 1) {
            int y = __shfl_up(x, off, 64);
            if (lane >= off) x += y;
        }
        if (lane == 63) wsum[wid] = x;
        __syncthreads();
        if (wid == 0 && lane < 16) {
            int s = wsum[lane];
            for (int off = 1; off < 16; off <<= 1) {
                int y = __shfl_up(s, off, 64);
                if (lane >= off) s += y;
            }
            wsum[lane] = s;
        }
        __syncthreads();
        int woff = (wid == 0) ? 0 : wsum[wid - 1];
        int excl = carry_s + woff + (x - t);
        int e0 = excl, e1 = e0 + v.x, e2 = e1 + v.y, e3 = e2 + v.z;
        if (idx < n) {
            if (idx + 3 < n) {
                *reinterpret_cast<int4*>(row_start + idx) = make_int4(e0, e1, e2, e3);
                *reinterpret_cast<int4*>(cursor + idx)    = make_int4(e0, e1, e2, e3);
            } else {
                row_start[idx] = e0; cursor[idx] = e0;
                if (idx + 1 < n) { row_start[idx + 1] = e1; cursor[idx + 1] = e1; }
                if (idx + 2 < n) { row_start[idx + 2] = e2; cursor[idx + 2] = e2; }
            }
        }
        int tot = wsum[15];
        __syncthreads();
        if (tid == 0) carry_s += tot;
        __syncthreads();
    }
    if (tid == 0) row_start[n] = carry_s;
}

// ---------------- CSR scatter: packed {src, ea} records ----------------
__global__ __launch_bounds__(256) void scatter_kernel(const int* __restrict__ src,
                                                      const int* __restrict__ dst,
                                                      const float* __restrict__ ea,
                                                      int* __restrict__ cursor,
                                                      int2* __restrict__ edges, int e) {
    int i = blockIdx.x * blockDim.x + threadIdx.x;
    if (i >= e) return;
    int s = src[i], d = dst[i];
    int pos = atomicAdd(&cursor[d], 1);
    edges[pos] = make_int2(s, __float_as_int(ea[i]));
}

// ---------------- deg/dinv from CSR (no atomics) ----------------
__global__ __launch_bounds__(256) void dinv_kernel(const int* __restrict__ row_start,
                                                   const int2* __restrict__ edges,
                                                   float* __restrict__ dinv, int n) {
    int i = blockIdx.x * blockDim.x + threadIdx.x;
    if (i >= n) return;
    int b = row_start[i], e = row_start[i + 1];
    float s = 0.f;
    for (int j = b; j < e; ++j) s += __int_as_float(edges[j].y);
    dinv[i] = (s > 0.f) ? rsqrtf(s) : 0.f;
}

// ---------------- norm in place: w = dinv[dst]*ea*dinv[src] ----------------
__global__ __launch_bounds__(256) void norm_kernel(const int* __restrict__ row_start,
                                                   int2* __restrict__ edges,
                                                   const float* __restrict__ dinv, int n) {
    int i = blockIdx.x * blockDim.x + threadIdx.x;
    if (i >= n) return;
    float dn = dinv[i];
    int b = row_start[i], e = row_start[i + 1];
    for (int j = b; j < e; ++j) {
        int2 ed = edges[j];
        float w = dn * __int_as_float(ed.y) * dinv[ed.x];
        edges[j].y = __float_as_int(w);
    }
}

// ---------------- concat x,pos -> P1 cols 0..7 (stride 32) ----------------
__global__ __launch_bounds__(256) void concat_kernel(const float* __restrict__ x,
                                                     const float* __restrict__ pos,
                                                     float* __restrict__ P1, int n) {
    int i = blockIdx.x * blockDim.x + threadIdx.x;
    if (i >= n) return;
    float2 a = *reinterpret_cast<const float2*>(x + (size_t)i * 6);
    float2 b = *reinterpret_cast<const float2*>(x + (size_t)i * 6 + 2);
    float2 c = *reinterpret_cast<const float2*>(x + (size_t)i * 6 + 4);
    float2 p = *reinterpret_cast<const float2*>(pos + (size_t)i * 2);
    float4 v0 = make_float4(a.x, a.y, b.x, b.y);
    float4 v1 = make_float4(c.x, c.y, p.x, p.y);
    *reinterpret_cast<float4*>(P1 + (size_t)i * 32)     = v0;
    *reinterpret_cast<float4*>(P1 + (size_t)i * 32 + 4) = v1;
}

// ---------------- propagation: hout[node] (+)= sum_edges w * hin[src] ----------------
// F = TPN*4 floats per row; edge records staged in LDS (broadcast reads).
template <int TPN, bool ACC>
__global__ __launch_bounds__(256) void prop_kernel(const int* __restrict__ row_start,
                                                   const int2* __restrict__ edges,
                                                   const float* __restrict__ hin, int in_stride,
                                                   float* __restrict__ hout, int out_stride, int n) {
    constexpr int NPB = 256 / TPN;
    __shared__ int2 se[CH];
    int tid = threadIdx.x;
    int nb = blockIdx.x * NPB;
    int node = nb + tid / TPN;
    int lane = tid % TPN;
    int nbEnd = (nb + NPB < n) ? (nb + NPB) : n;
    int blkBeg = row_start[nb];
    int blkEnd = row_start[nbEnd];
    int beg = 0, end = 0;
    if (node < n) { beg = row_start[node]; end = row_start[node + 1]; }
    float ax = 0.f, ay = 0.f, az = 0.f, aw = 0.f;
    for (int base = blkBeg; base < blkEnd; base += CH) {
        int m = blkEnd - base; if (m > CH) m = CH;
        __syncthreads();
        for (int i = tid; i < m; i += 256) se[i] = edges[base + i];
        __syncthreads();
        int lo = (beg > base) ? (beg - base) : 0;
        int hi = ((end < base + m) ? end : (base + m)) - base;
        for (int i = lo; i < hi; ++i) {
            int2 e = se[i];
            float w = __int_as_float(e.y);
            const float4 v = *reinterpret_cast<const float4*>(hin + (size_t)e.x * in_stride + lane * 4);
            ax += w * v.x; ay += w * v.y; az += w * v.z; aw += w * v.w;
        }
    }
    if (node < n) {
        float4* po = reinterpret_cast<float4*>(hout + (size_t)node * out_stride + lane * 4);
        float4 r = make_float4(ax, ay, az, aw);
        if (ACC) { float4 o = *po; r.x += o.x; r.y += o.y; r.z += o.z; r.w += o.w; }
        *po = r;
    }
}

// ---------------- final prop: out = log_softmax(g0 + A*t1 + b3) ----------------
__global__ __launch_bounds__(256) void prop_final_kernel(const int* __restrict__ row_start,
                                                         const int2* __restrict__ edges,
                                                         const float* __restrict__ hin,  // t1 = T+16, stride 64
                                                         const float* __restrict__ g0,   // T chunk 0, stride 64
                                                         const float* __restrict__ b3,
                                                         float* __restrict__ out, int n) {
    constexpr int TPN = 4, NPB = 64;
    __shared__ int2 se[CH];
    int tid = threadIdx.x;
    int nb = blockIdx.x * NPB;
    int node = nb + tid / TPN;
    int lane = tid & 3;
    int nbEnd = (nb + NPB < n) ? (nb + NPB) : n;
    int blkBeg = row_start[nb];
    int blkEnd = row_start[nbEnd];
    int beg = 0, end = 0;
    if (node < n) { beg = row_start[node]; end = row_start[node + 1]; }
    float ax = 0.f, ay = 0.f, az = 0.f, aw = 0.f;
    for (int base = blkBeg; base < blkEnd; base += CH) {
        int m = blkEnd - base; if (m > CH) m = CH;
        __syncthreads();
        for (int i = tid; i < m; i += 256) se[i] = edges[base + i];
        __syncthreads();
        int lo = (beg > base) ? (beg - base) : 0;
        int hi = ((end < base + m) ? end : (base + m)) - base;
        for (int i = lo; i < hi; ++i) {
            int2 e = se[i];
            float w = __int_as_float(e.y);
            const float4 v = *reinterpret_cast<const float4*>(hin + (size_t)e.x * 64 + lane * 4);
            ax += w * v.x; ay += w * v.y; az += w * v.z; aw += w * v.w;
        }
    }
    if (node < n) {
        const float4 g = *reinterpret_cast<const float4*>(g0 + (size_t)node * 64 + lane * 4);
        float vv[4] = {ax + g.x, ay + g.y, az + g.z, aw + g.w};
        int c0 = lane * 4;
        float mloc = -1e30f;
        #pragma unroll
        for (int c = 0; c < 4; ++c) {
            int col = c0 + c;
            if (col < NOUT) { vv[c] += b3[col]; mloc = fmaxf(mloc, vv[c]); }
        }
        float mo = fmaxf(mloc, __shfl_xor(mloc, 1));
        mo = fmaxf(mo, __shfl_xor(mo, 2));
        float sl = 0.f;
        #pragma unroll
        for (int c = 0; c < 4; ++c) {
            int col = c0 + c;
            if (col < NOUT) sl += __expf(vv[c] - mo);
        }
        sl += __shfl_xor(sl, 1);
        sl += __shfl_xor(sl, 2);
        float ls = __logf(sl);
        #pragma unroll
        for (int c = 0; c < 4; ++c) {
            int col = c0 + c;
            if (col < NOUT) out[(size_t)node * NOUT + col] = vv[c] - mo - ls;
        }
    }
}

// ---------------- K-chunked matmul: out[n, 0:64] = h[n, 0:FIN] @ W + epi ----------------
// EPI: 0 = none, 1 = bias+relu.  WMODE: 0 = W contiguous (FIN,64),
// 1 = W3 pad mode: W is (4,FIN,10), logical col c -> (k=c/16, j=c%16), j>=10 -> 0.
template <int FIN, int KC, int EPI, int WMODE>
__global__ __launch_bounds__(256) void mm_kernel(const float* __restrict__ h, int hstride,
                                                 const float* __restrict__ W,
                                                 const float* __restrict__ bias,
                                                 float* __restrict__ out, int ostride, int n) {
    constexpr int FOUT = 64, OV = 16, HS = KC + 1;
    __shared__ float Ws[KC * FOUT];
    __shared__ float Hs[32 * HS];
    int tid = threadIdx.x;
    int nodeBase = blockIdx.x * 32;
    // thread covers outputs o and o+256: same f4, nodes nd and nd+16
    int ndA = tid / OV, f4 = tid % OV;
    int ndB = ndA + 16;
    float4 accA = make_float4(0.f, 0.f, 0.f, 0.f);
    float4 accB = make_float4(0.f, 0.f, 0.f, 0.f);
    for (int kc = 0; kc < FIN; kc += KC) {
        for (int i = tid; i < KC * FOUT; i += 256) {
            int r = i / FOUT, c = i % FOUT;
            float wv;
            if (WMODE == 0) {
                wv = W[(size_t)(kc + r) * FOUT + c];
            } else {
                int k = c >> 4, j = c & 15;
                wv = (j < NOUT) ? W[((size_t)k * FIN + kc + r) * NOUT + j] : 0.f;
            }
            Ws[i] = wv;
        }
        for (int i = tid; i < 32 * KC; i += 256) {
            int r = i / KC, c = i % KC;
            int nd = nodeBase + r;
            Hs[r * HS + c] = (nd < n) ? h[(size_t)nd * hstride + kc + c] : 0.f;
        }
        __syncthreads();
        const float* hrA = &Hs[ndA * HS];
        const float* hrB = &Hs[ndB * HS];
        #pragma unroll 4
        for (int i = 0; i < KC; ++i) {
            const float4 w = *reinterpret_cast<const float4*>(&Ws[i * FOUT + f4 * 4]);
            float hA = hrA[i], hB = hrB[i];
            accA.x += hA * w.x; accA.y += hA * w.y; accA.z += hA * w.z; accA.w += hA * w.w;
            accB.x += hB * w.x; accB.y += hB * w.y; accB.z += hB * w.z; accB.w += hB * w.w;
        }
        __syncthreads();
    }
    float4 bv = make_float4(0.f, 0.f, 0.f, 0.f);
    if (EPI == 1) bv = *reinterpret_cast<const float4*>(&bias[f4 * 4]);
    int gA = nodeBase + ndA, gB = nodeBase + ndB;
    if (gA < n) {
        float4 a = accA;
        if (EPI == 1) {
            a.x = fmaxf(a.x + bv.x, 0.f); a.y = fmaxf(a.y + bv.y, 0.f);
            a.z = fmaxf(a.z + bv.z, 0.f); a.w = fmaxf(a.w + bv.w, 0.f);
        }
        *reinterpret_cast<float4*>(out + (size_t)gA * ostride + f4 * 4) = a;
    }
    if (gB < n) {
        float4 a = accB;
        if (EPI == 1) {
            a.x = fmaxf(a.x + bv.x, 0.f); a.y = fmaxf(a.y + bv.y, 0.f);
            a.z = fmaxf(a.z + bv.z, 0.f); a.w = fmaxf(a.w + bv.w, 0.f);
        }
        *reinterpret_cast<float4*>(out + (size_t)gB * ostride + f4 * 4) = a;
    }
}

extern "C" void kernel_launch(void* const* d_in, const int* in_sizes, int n_in,
                              void* d_out, int out_size, void* d_ws, size_t ws_size,
                              hipStream_t stream) {
    const float* x   = (const float*)d_in[0];   // (N,6)
    const float* pos = (const float*)d_in[1];   // (N,2)
    const float* ea  = (const float*)d_in[2];   // (E,)
    const float* W1  = (const float*)d_in[3];   // (4,8,64) == (32,64)
    const float* b1  = (const float*)d_in[4];   // (64,)
    const float* W2  = (const float*)d_in[5];   // (4,64,64) == (256,64)
    const float* b2  = (const float*)d_in[6];   // (64,)
    const float* W3  = (const float*)d_in[7];   // (4,64,10)
    const float* b3  = (const float*)d_in[8];   // (10,)
    const int* eidx  = (const int*)d_in[9];     // (2,E)
    const int* src = eidx;
    const int* dst = eidx + EE;
    float* outp = (float*)d_out;

    size_t off = 0;
    char* base = (char*)d_ws;
    auto alloc = [&](size_t bytes) -> void* {
        void* p = base + off;
        off += (bytes + 255) & ~(size_t)255;
        return p;
    };
    int*   cnt       = (int*)alloc(NN * 4);              // reused as dinv after scan
    int*   row_start = (int*)alloc((NN + 1) * 4);
    int*   cursor    = (int*)alloc(NN * 4);
    int2*  edges     = (int2*)alloc((size_t)EE * 8);     // packed {src, w}
    float* S1        = (float*)alloc((size_t)NN * 64 * 4);   // P1 (N x 32) then h2 (N x 64)
    float* S2        = (float*)alloc((size_t)NN * 256 * 4);  // P2 (N x 256) then T (N x 64)
    float* dinv = (float*)cnt;
    float* P1 = S1;
    float* h2 = S1;
    float* P2 = S2;
    float* T  = S2;
    (void)ws_size;

    const int B = 256;
    const int gE = (EE + B - 1) / B;       // 3125
    const int gN = (NN + B - 1) / B;       // 196
    const int gMM = (NN + 31) / 32;        // 1563
    const int gP2  = (NN + 127) / 128;     // 391  (TPN=2,  NPB=128)
    const int gP16 = (NN + 15) / 16;       // 3125 (TPN=16, NPB=16)
    const int gP4  = (NN + 63) / 64;       // 782  (TPN=4,  NPB=64)

    hipMemsetAsync(cnt, 0, NN * 4, stream);

    // ---- CSR build ----
    cnt_kernel<<<gE, B, 0, stream>>>(dst, cnt, EE);
    scan_kernel<<<1, 1024, 0, stream>>>(cnt, row_start, cursor, NN);
    scatter_kernel<<<gE, B, 0, stream>>>(src, dst, ea, cursor, edges, EE);
    dinv_kernel<<<gN, B, 0, stream>>>(row_start, edges, dinv, NN);
    norm_kernel<<<gN, B, 0, stream>>>(row_start, edges, dinv, NN);

    // ---- layer 1: P1 = [h0, Ah0, A2h0, A3h0] (N x 32); h1 = relu(P1@W1 + b1) -> P2 cols 0:64 ----
    concat_kernel<<<gN, B, 0, stream>>>(x, pos, P1, NN);
    prop_kernel<2, false><<<gP2, B, 0, stream>>>(row_start, edges, P1,      32, P1 + 8,  32, NN);
    prop_kernel<2, false><<<gP2, B, 0, stream>>>(row_start, edges, P1 + 8,  32, P1 + 16, 32, NN);
    prop_kernel<2, false><<<gP2, B, 0, stream>>>(row_start, edges, P1 + 16, 32, P1 + 24, 32, NN);
    mm_kernel<32, 32, 1, 0><<<gMM, B, 0, stream>>>(P1, 32, W1, b1, P2, 256, NN);

    // ---- layer 2: P2 = [h1, Ah1, A2h1, A3h1] (N x 256); h2 = relu(P2@W2 + b2) ----
    prop_kernel<16, false><<<gP16, B, 0, stream>>>(row_start, edges, P2,       256, P2 + 64,  256, NN);
    prop_kernel<16, false><<<gP16, B, 0, stream>>>(row_start, edges, P2 + 64,  256, P2 + 128, 256, NN);
    prop_kernel<16, false><<<gP16, B, 0, stream>>>(row_start, edges, P2 + 128, 256, P2 + 192, 256, NN);
    mm_kernel<256, 64, 1, 0><<<gMM, B, 0, stream>>>(P2, 256, W2, b2, h2, 64, NN);

    // ---- layer 3 (Horner): T[n, k*16+j] = (h2 @ W3[k])[n,j]  (j<10, padded to 16) ----
    // t2 = G2 + A*G3 ; t1 = G1 + A*t2 ; out = log_softmax(G0 + A*t1 + b3)
    mm_kernel<64, 64, 0, 1><<<gMM, B, 0, stream>>>(h2, 64, W3, nullptr, T, 64, NN);
    prop_kernel<4, true><<<gP4, B, 0, stream>>>(row_start, edges, T + 48, 64, T + 32, 64, NN);
    prop_kernel<4, true><<<gP4, B, 0, stream>>>(row_start, edges, T + 32, 64, T + 16, 64, NN);
    prop_final_kernel<<<gP4, B, 0, stream>>>(row_start, edges, T + 16, T, b3, outp, NN);
}

// Round 3
// 573.681 us; speedup vs baseline: 1.2192x; 1.0478x over previous
//
#include <hip/hip_runtime.h>
#include <math.h>

// TAGConv GNN: N=50000, E=800000, K=3, layers (8->64, 64->64, 64->10)
// v3: register-blocked 64x64 matmul tiles (4x4 acc/thread, k-major LDS H),
// everything else from v2: single-atomic CSR build, packed edge records,
// Horner layer 3, LDS-staged edges in props, fused epilogues.

#define NN 50000
#define EE 800000
#define HID 64
#define NOUT 10
#define CH 512

// ---------------- count in-degree (1 atomic per edge) ----------------
__global__ __launch_bounds__(256) void cnt_kernel(const int* __restrict__ dst,
                                                  int* __restrict__ cnt, int e) {
    int i = blockIdx.x * blockDim.x + threadIdx.x;
    if (i < e) atomicAdd(&cnt[dst[i]], 1);
}

// ---------------- exclusive scan, coarsened 4x (single block) ----------------
__global__ __launch_bounds__(1024) void scan_kernel(const int* __restrict__ cnt,
                                                    int* __restrict__ row_start,
                                                    int* __restrict__ cursor, int n) {
    __shared__ int wsum[16];
    __shared__ int carry_s;
    int tid = threadIdx.x;
    int lane = tid & 63, wid = tid >> 6;
    if (tid == 0) carry_s = 0;
    __syncthreads();
    for (int base = 0; base < n; base += 4096) {
        int idx = base + tid * 4;
        int4 v = make_int4(0, 0, 0, 0);
        if (idx + 3 < n) {
            v = *reinterpret_cast<const int4*>(cnt + idx);
        } else {
            if (idx < n)     v.x = cnt[idx];
            if (idx + 1 < n) v.y = cnt[idx + 1];
            if (idx + 2 < n) v.z = cnt[idx + 2];
        }
        int t = v.x + v.y + v.z + v.w;
        int x = t;
        for (int off = 1; off < 64; off <<= 1) {
            int y = __shfl_up(x, off, 64);
            if (lane >= off) x += y;
        }
        if (lane == 63) wsum[wid] = x;
        __syncthreads();
        if (wid == 0 && lane < 16) {
            int s = wsum[lane];
            for (int off = 1; off < 16; off <<= 1) {
                int y = __shfl_up(s, off, 64);
                if (lane >= off) s += y;
            }
            wsum[lane] = s;
        }
        __syncthreads();
        int woff = (wid == 0) ? 0 : wsum[wid - 1];
        int excl = carry_s + woff + (x - t);
        int e0 = excl, e1 = e0 + v.x, e2 = e1 + v.y, e3 = e2 + v.z;
        if (idx < n) {
            if (idx + 3 < n) {
                *reinterpret_cast<int4*>(row_start + idx) = make_int4(e0, e1, e2, e3);
                *reinterpret_cast<int4*>(cursor + idx)    = make_int4(e0, e1, e2, e3);
            } else {
                row_start[idx] = e0; cursor[idx] = e0;
                if (idx + 1 < n) { row_start[idx + 1] = e1; cursor[idx + 1] = e1; }
                if (idx + 2 < n) { row_start[idx + 2] = e2; cursor[idx + 2] = e2; }
            }
        }
        int tot = wsum[15];
        __syncthreads();
        if (tid == 0) carry_s += tot;
        __syncthreads();
    }
    if (tid == 0) row_start[n] = carry_s;
}

// ---------------- CSR scatter: packed {src, ea} records ----------------
__global__ __launch_bounds__(256) void scatter_kernel(const int* __restrict__ src,
                                                      const int* __restrict__ dst,
                                                      const float* __restrict__ ea,
                                                      int* __restrict__ cursor,
                                                      int2* __restrict__ edges, int e) {
    int i = blockIdx.x * blockDim.x + threadIdx.x;
    if (i >= e) return;
    int s = src[i], d = dst[i];
    int pos = atomicAdd(&cursor[d], 1);
    edges[pos] = make_int2(s, __float_as_int(ea[i]));
}

// ---------------- deg/dinv from CSR (no atomics) ----------------
__global__ __launch_bounds__(256) void dinv_kernel(const int* __restrict__ row_start,
                                                   const int2* __restrict__ edges,
                                                   float* __restrict__ dinv, int n) {
    int i = blockIdx.x * blockDim.x + threadIdx.x;
    if (i >= n) return;
    int b = row_start[i], e = row_start[i + 1];
    float s = 0.f;
    for (int j = b; j < e; ++j) s += __int_as_float(edges[j].y);
    dinv[i] = (s > 0.f) ? rsqrtf(s) : 0.f;
}

// ---------------- norm in place: w = dinv[dst]*ea*dinv[src] ----------------
__global__ __launch_bounds__(256) void norm_kernel(const int* __restrict__ row_start,
                                                   int2* __restrict__ edges,
                                                   const float* __restrict__ dinv, int n) {
    int i = blockIdx.x * blockDim.x + threadIdx.x;
    if (i >= n) return;
    float dn = dinv[i];
    int b = row_start[i], e = row_start[i + 1];
    for (int j = b; j < e; ++j) {
        int2 ed = edges[j];
        float w = dn * __int_as_float(ed.y) * dinv[ed.x];
        edges[j].y = __float_as_int(w);
    }
}

// ---------------- concat x,pos -> P1 cols 0..7 (stride 32) ----------------
__global__ __launch_bounds__(256) void concat_kernel(const float* __restrict__ x,
                                                     const float* __restrict__ pos,
                                                     float* __restrict__ P1, int n) {
    int i = blockIdx.x * blockDim.x + threadIdx.x;
    if (i >= n) return;
    float2 a = *reinterpret_cast<const float2*>(x + (size_t)i * 6);
    float2 b = *reinterpret_cast<const float2*>(x + (size_t)i * 6 + 2);
    float2 c = *reinterpret_cast<const float2*>(x + (size_t)i * 6 + 4);
    float2 p = *reinterpret_cast<const float2*>(pos + (size_t)i * 2);
    float4 v0 = make_float4(a.x, a.y, b.x, b.y);
    float4 v1 = make_float4(c.x, c.y, p.x, p.y);
    *reinterpret_cast<float4*>(P1 + (size_t)i * 32)     = v0;
    *reinterpret_cast<float4*>(P1 + (size_t)i * 32 + 4) = v1;
}

// ---------------- propagation: hout[node] (+)= sum_edges w * hin[src] ----------------
template <int TPN, bool ACC>
__global__ __launch_bounds__(256) void prop_kernel(const int* __restrict__ row_start,
                                                   const int2* __restrict__ edges,
                                                   const float* __restrict__ hin, int in_stride,
                                                   float* __restrict__ hout, int out_stride, int n) {
    constexpr int NPB = 256 / TPN;
    __shared__ int2 se[CH];
    int tid = threadIdx.x;
    int nb = blockIdx.x * NPB;
    int node = nb + tid / TPN;
    int lane = tid % TPN;
    int nbEnd = (nb + NPB < n) ? (nb + NPB) : n;
    int blkBeg = row_start[nb];
    int blkEnd = row_start[nbEnd];
    int beg = 0, end = 0;
    if (node < n) { beg = row_start[node]; end = row_start[node + 1]; }
    float ax = 0.f, ay = 0.f, az = 0.f, aw = 0.f;
    for (int base = blkBeg; base < blkEnd; base += CH) {
        int m = blkEnd - base; if (m > CH) m = CH;
        __syncthreads();
        for (int i = tid; i < m; i += 256) se[i] = edges[base + i];
        __syncthreads();
        int lo = (beg > base) ? (beg - base) : 0;
        int hi = ((end < base + m) ? end : (base + m)) - base;
        for (int i = lo; i < hi; ++i) {
            int2 e = se[i];
            float w = __int_as_float(e.y);
            const float4 v = *reinterpret_cast<const float4*>(hin + (size_t)e.x * in_stride + lane * 4);
            ax += w * v.x; ay += w * v.y; az += w * v.z; aw += w * v.w;
        }
    }
    if (node < n) {
        float4* po = reinterpret_cast<float4*>(hout + (size_t)node * out_stride + lane * 4);
        float4 r = make_float4(ax, ay, az, aw);
        if (ACC) { float4 o = *po; r.x += o.x; r.y += o.y; r.z += o.z; r.w += o.w; }
        *po = r;
    }
}

// ---------------- final prop: out = log_softmax(g0 + A*t1 + b3) ----------------
__global__ __launch_bounds__(256) void prop_final_kernel(const int* __restrict__ row_start,
                                                         const int2* __restrict__ edges,
                                                         const float* __restrict__ hin,
                                                         const float* __restrict__ g0,
                                                         const float* __restrict__ b3,
                                                         float* __restrict__ out, int n) {
    constexpr int TPN = 4, NPB = 64;
    __shared__ int2 se[CH];
    int tid = threadIdx.x;
    int nb = blockIdx.x * NPB;
    int node = nb + tid / TPN;
    int lane = tid & 3;
    int nbEnd = (nb + NPB < n) ? (nb + NPB) : n;
    int blkBeg = row_start[nb];
    int blkEnd = row_start[nbEnd];
    int beg = 0, end = 0;
    if (node < n) { beg = row_start[node]; end = row_start[node + 1]; }
    float ax = 0.f, ay = 0.f, az = 0.f, aw = 0.f;
    for (int base = blkBeg; base < blkEnd; base += CH) {
        int m = blkEnd - base; if (m > CH) m = CH;
        __syncthreads();
        for (int i = tid; i < m; i += 256) se[i] = edges[base + i];
        __syncthreads();
        int lo = (beg > base) ? (beg - base) : 0;
        int hi = ((end < base + m) ? end : (base + m)) - base;
        for (int i = lo; i < hi; ++i) {
            int2 e = se[i];
            float w = __int_as_float(e.y);
            const float4 v = *reinterpret_cast<const float4*>(hin + (size_t)e.x * 64 + lane * 4);
            ax += w * v.x; ay += w * v.y; az += w * v.z; aw += w * v.w;
        }
    }
    if (node < n) {
        const float4 g = *reinterpret_cast<const float4*>(g0 + (size_t)node * 64 + lane * 4);
        float vv[4] = {ax + g.x, ay + g.y, az + g.z, aw + g.w};
        int c0 = lane * 4;
        float mloc = -1e30f;
        #pragma unroll
        for (int c = 0; c < 4; ++c) {
            int col = c0 + c;
            if (col < NOUT) { vv[c] += b3[col]; mloc = fmaxf(mloc, vv[c]); }
        }
        float mo = fmaxf(mloc, __shfl_xor(mloc, 1));
        mo = fmaxf(mo, __shfl_xor(mo, 2));
        float sl = 0.f;
        #pragma unroll
        for (int c = 0; c < 4; ++c) {
            int col = c0 + c;
            if (col < NOUT) sl += __expf(vv[c] - mo);
        }
        sl += __shfl_xor(sl, 1);
        sl += __shfl_xor(sl, 2);
        float ls = __logf(sl);
        #pragma unroll
        for (int c = 0; c < 4; ++c) {
            int col = c0 + c;
            if (col < NOUT) out[(size_t)node * NOUT + col] = vv[c] - mo - ls;
        }
    }
}

// ---------------- register-blocked matmul: 64 nodes x 64 outs per block ----------------
// out[n, 0:64] = h[n, 0:FIN] @ W (+ epi). Thread (ndq, f4) owns 4 nodes x 4 outs.
// HsT is k-major in LDS (padded 68/row), so the inner loop is 2x ds_read_b128 + 16 FMA.
// EPI: 0 = none, 1 = bias+relu. WMODE: 0 = W contiguous (FIN,64),
// 1 = W3 pad mode: W is (4,FIN,10), col c -> (k=c/16, j=c%16), j>=10 -> 0.
template <int FIN, int KC, int EPI, int WMODE>
__global__ __launch_bounds__(256) void mm2_kernel(const float* __restrict__ h, int hstride,
                                                  const float* __restrict__ W,
                                                  const float* __restrict__ bias,
                                                  float* __restrict__ out, int ostride, int n) {
    constexpr int HP = 68;                   // padded HsT row (272 B, 16-aligned)
    __shared__ float HsT[KC * HP];
    __shared__ float Ws[KC * 64];
    int tid = threadIdx.x;
    int ndq = tid >> 4;                      // 0..15: node quad
    int f4  = tid & 15;                      // 0..15: output quad
    int nd  = tid & 63;                      // staging: node
    int wv  = tid >> 6;                      // staging: wave id 0..3
    int nodeBase = blockIdx.x * 64;

    float4 acc0 = make_float4(0.f, 0.f, 0.f, 0.f);
    float4 acc1 = make_float4(0.f, 0.f, 0.f, 0.f);
    float4 acc2 = make_float4(0.f, 0.f, 0.f, 0.f);
    float4 acc3 = make_float4(0.f, 0.f, 0.f, 0.f);

    for (int kc = 0; kc < FIN; kc += KC) {
        // stage W chunk
        if (WMODE == 0) {
            for (int i = tid * 4; i < KC * 64; i += 1024)
                *reinterpret_cast<float4*>(&Ws[i]) =
                    *reinterpret_cast<const float4*>(&W[(size_t)kc * 64 + i]);
        } else {
            for (int i = tid; i < KC * 64; i += 256) {
                int r = i >> 6, c = i & 63;
                int k = c >> 4, j = c & 15;
                Ws[i] = (j < NOUT) ? W[((size_t)k * FIN + kc + r) * NOUT + j] : 0.f;
            }
        }
        // stage H chunk, k-major: HsT[k][nd]
        int node = nodeBase + nd;
        #pragma unroll
        for (int r = 0; r < KC / 16; ++r) {
            int k0 = wv * 4 + r * 16;
            float4 hv = make_float4(0.f, 0.f, 0.f, 0.f);
            if (node < n)
                hv = *reinterpret_cast<const float4*>(&h[(size_t)node * hstride + kc + k0]);
            HsT[(k0 + 0) * HP + nd] = hv.x;
            HsT[(k0 + 1) * HP + nd] = hv.y;
            HsT[(k0 + 2) * HP + nd] = hv.z;
            HsT[(k0 + 3) * HP + nd] = hv.w;
        }
        __syncthreads();
        #pragma unroll 8
        for (int k = 0; k < KC; ++k) {
            const float4 hq = *reinterpret_cast<const float4*>(&HsT[k * HP + ndq * 4]);
            const float4 wq = *reinterpret_cast<const float4*>(&Ws[k * 64 + f4 * 4]);
            acc0.x += hq.x * wq.x; acc0.y += hq.x * wq.y; acc0.z += hq.x * wq.z; acc0.w += hq.x * wq.w;
            acc1.x += hq.y * wq.x; acc1.y += hq.y * wq.y; acc1.z += hq.y * wq.z; acc1.w += hq.y * wq.w;
            acc2.x += hq.z * wq.x; acc2.y += hq.z * wq.y; acc2.z += hq.z * wq.z; acc2.w += hq.z * wq.w;
            acc3.x += hq.w * wq.x; acc3.y += hq.w * wq.y; acc3.z += hq.w * wq.z; acc3.w += hq.w * wq.w;
        }
        __syncthreads();
    }

    float4 bv = make_float4(0.f, 0.f, 0.f, 0.f);
    if (EPI == 1) bv = *reinterpret_cast<const float4*>(&bias[f4 * 4]);
    float4 accs[4] = {acc0, acc1, acc2, acc3};
    #pragma unroll
    for (int i = 0; i < 4; ++i) {
        int node = nodeBase + ndq * 4 + i;
        if (node < n) {
            float4 a = accs[i];
            if (EPI == 1) {
                a.x = fmaxf(a.x + bv.x, 0.f); a.y = fmaxf(a.y + bv.y, 0.f);
                a.z = fmaxf(a.z + bv.z, 0.f); a.w = fmaxf(a.w + bv.w, 0.f);
            }
            *reinterpret_cast<float4*>(out + (size_t)node * ostride + f4 * 4) = a;
        }
    }
}

extern "C" void kernel_launch(void* const* d_in, const int* in_sizes, int n_in,
                              void* d_out, int out_size, void* d_ws, size_t ws_size,
                              hipStream_t stream) {
    const float* x   = (const float*)d_in[0];
    const float* pos = (const float*)d_in[1];
    const float* ea  = (const float*)d_in[2];
    const float* W1  = (const float*)d_in[3];   // (4,8,64) == (32,64)
    const float* b1  = (const float*)d_in[4];
    const float* W2  = (const float*)d_in[5];   // (4,64,64) == (256,64)
    const float* b2  = (const float*)d_in[6];
    const float* W3  = (const float*)d_in[7];   // (4,64,10)
    const float* b3  = (const float*)d_in[8];
    const int* eidx  = (const int*)d_in[9];
    const int* src = eidx;
    const int* dst = eidx + EE;
    float* outp = (float*)d_out;

    size_t off = 0;
    char* base = (char*)d_ws;
    auto alloc = [&](size_t bytes) -> void* {
        void* p = base + off;
        off += (bytes + 255) & ~(size_t)255;
        return p;
    };
    int*   cnt       = (int*)alloc(NN * 4);
    int*   row_start = (int*)alloc((NN + 1) * 4);
    int*   cursor    = (int*)alloc(NN * 4);
    int2*  edges     = (int2*)alloc((size_t)EE * 8);
    float* S1        = (float*)alloc((size_t)NN * 64 * 4);
    float* S2        = (float*)alloc((size_t)NN * 256 * 4);
    float* dinv = (float*)cnt;
    float* P1 = S1;
    float* h2 = S1;
    float* P2 = S2;
    float* T  = S2;
    (void)ws_size;

    const int B = 256;
    const int gE = (EE + B - 1) / B;
    const int gN = (NN + B - 1) / B;
    const int gMM2 = (NN + 63) / 64;       // 782
    const int gP2  = (NN + 127) / 128;
    const int gP16 = (NN + 15) / 16;
    const int gP4  = (NN + 63) / 64;

    hipMemsetAsync(cnt, 0, NN * 4, stream);

    // ---- CSR build ----
    cnt_kernel<<<gE, B, 0, stream>>>(dst, cnt, EE);
    scan_kernel<<<1, 1024, 0, stream>>>(cnt, row_start, cursor, NN);
    scatter_kernel<<<gE, B, 0, stream>>>(src, dst, ea, cursor, edges, EE);
    dinv_kernel<<<gN, B, 0, stream>>>(row_start, edges, dinv, NN);
    norm_kernel<<<gN, B, 0, stream>>>(row_start, edges, dinv, NN);

    // ---- layer 1 ----
    concat_kernel<<<gN, B, 0, stream>>>(x, pos, P1, NN);
    prop_kernel<2, false><<<gP2, B, 0, stream>>>(row_start, edges, P1,      32, P1 + 8,  32, NN);
    prop_kernel<2, false><<<gP2, B, 0, stream>>>(row_start, edges, P1 + 8,  32, P1 + 16, 32, NN);
    prop_kernel<2, false><<<gP2, B, 0, stream>>>(row_start, edges, P1 + 16, 32, P1 + 24, 32, NN);
    mm2_kernel<32, 32, 1, 0><<<gMM2, B, 0, stream>>>(P1, 32, W1, b1, P2, 256, NN);

    // ---- layer 2 ----
    prop_kernel<16, false><<<gP16, B, 0, stream>>>(row_start, edges, P2,       256, P2 + 64,  256, NN);
    prop_kernel<16, false><<<gP16, B, 0, stream>>>(row_start, edges, P2 + 64,  256, P2 + 128, 256, NN);
    prop_kernel<16, false><<<gP16, B, 0, stream>>>(row_start, edges, P2 + 128, 256, P2 + 192, 256, NN);
    mm2_kernel<256, 64, 1, 0><<<gMM2, B, 0, stream>>>(P2, 256, W2, b2, h2, 64, NN);

    // ---- layer 3 (Horner) ----
    mm2_kernel<64, 64, 0, 1><<<gMM2, B, 0, stream>>>(h2, 64, W3, nullptr, T, 64, NN);
    prop_kernel<4, true><<<gP4, B, 0, stream>>>(row_start, edges, T + 48, 64, T + 32, 64, NN);
    prop_kernel<4, true><<<gP4, B, 0, stream>>>(row_start, edges, T + 32, 64, T + 16, 64, NN);
    prop_final_kernel<<<gP4, B, 0, stream>>>(row_start, edges, T + 16, T, b3, outp, NN);
}

// Round 4
// 501.027 us; speedup vs baseline: 1.3960x; 1.1450x over previous
//
#include <hip/hip_runtime.h>
#include <math.h>

// TAGConv GNN: N=50000, E=800000, K=3, layers (8->64, 64->64, 64->10)
// v4: atomic-free-ish CSR build via 128-node bucket sort:
//   K1 bucket_scatter: LDS histogram + 1 global atomic per (block,bucket),
//      edges scattered into capacity-strided bucket regions (packed fine|src, ea)
//   K2 bucket_build:   per-bucket LDS fine-sort -> row_start, dinv, w0=ea*dinv[dst]
//   K3 srcscale:       w = w0 * dinv[src] flat pass
// Props read the strided CSR (ends clamped to real bucket counts).
// Register-blocked 64x64 matmuls, Horner layer 3, fused epilogues (from v3).

#define NN 50000
#define EE 800000
#define HID 64
#define NOUT 10
#define CH 512

#define NB 391        // ceil(50000/128) buckets of 128 nodes
#define CAP 2400      // region capacity (mean 2047, +7.8 sigma)
#define K1_EPB 4096   // edges per K1 block

// ---------------- K1: coarse bucket scatter ----------------
__global__ __launch_bounds__(256) void bucket_scatter_kernel(
        const int* __restrict__ src, const int* __restrict__ dst,
        const float* __restrict__ ea, int* __restrict__ cursor,
        int2* __restrict__ regions, int e) {
    __shared__ int hist[NB];
    __shared__ int base[NB];
    int tid = threadIdx.x;
    int e0 = blockIdx.x * K1_EPB;
    int e1 = e0 + K1_EPB; if (e1 > e) e1 = e;
    for (int i = tid; i < NB; i += 256) hist[i] = 0;
    __syncthreads();
    for (int i = e0 + tid; i < e1; i += 256)
        atomicAdd(&hist[dst[i] >> 7], 1);
    __syncthreads();
    for (int b = tid; b < NB; b += 256) {
        int c = hist[b];
        base[b] = (c > 0) ? atomicAdd(&cursor[b], c) : 0;
        hist[b] = 0;   // reuse as local cursor
    }
    __syncthreads();
    for (int i = e0 + tid; i < e1; i += 256) {
        int d = dst[i];
        int b = d >> 7;
        int r = atomicAdd(&hist[b], 1);
        int pos = base[b] + r;
        if (pos < CAP)
            regions[(size_t)b * CAP + pos] =
                make_int2(((d & 127) << 16) | src[i], __float_as_int(ea[i]));
    }
}

// ---------------- K2: per-bucket fine sort + row_start + dinv + w0 ----------------
__global__ __launch_bounds__(256) void bucket_build_kernel(
        const int* __restrict__ cursor, int2* __restrict__ regions,
        float* __restrict__ dinv, int* __restrict__ row_start, int n) {
    __shared__ int2 rec[CAP];
    __shared__ int hist[128];
    __shared__ float easum[128];
    __shared__ float dl[128];
    __shared__ int off[129];
    __shared__ int lcur[128];
    int b = blockIdx.x;
    int tid = threadIdx.x;
    int cnt = cursor[b]; if (cnt > CAP) cnt = CAP;
    size_t rb = (size_t)b * CAP;
    if (tid < 128) { hist[tid] = 0; easum[tid] = 0.f; lcur[tid] = 0; }
    __syncthreads();
    for (int i = tid; i < cnt; i += 256) {
        int2 r = regions[rb + i];
        rec[i] = r;
        int f = r.x >> 16;
        atomicAdd(&hist[f], 1);
        atomicAdd(&easum[f], __int_as_float(r.y));
    }
    __syncthreads();
    if (tid < 128) {
        int lane = tid & 63;
        int v = hist[tid];
        for (int o2 = 1; o2 < 64; o2 <<= 1) {
            int y = __shfl_up(v, o2, 64);
            if (lane >= o2) v += y;
        }
        off[tid + 1] = v;     // wave-local inclusive
        float s2 = easum[tid];
        dl[tid] = (s2 > 0.f) ? rsqrtf(s2) : 0.f;
    }
    __syncthreads();
    if (tid == 255) off[0] = 0;
    if (tid >= 64 && tid < 128) off[tid + 1] += off[64];
    __syncthreads();
    if (tid < 128) {
        int node = b * 128 + tid;
        if (node <= n) row_start[node] = b * CAP + off[tid];
        if (node < n)  dinv[node] = dl[tid];
    }
    __syncthreads();
    for (int i = tid; i < cnt; i += 256) {
        int2 r = rec[i];
        int f = r.x >> 16;
        int s = r.x & 0xFFFF;
        int p = atomicAdd(&lcur[f], 1);
        float w0 = __int_as_float(r.y) * dl[f];
        regions[rb + off[f] + p] = make_int2(s, __float_as_int(w0));
    }
}

// ---------------- K3: w *= dinv[src] ----------------
__global__ __launch_bounds__(256) void srcscale_kernel(
        const int* __restrict__ cursor, const float* __restrict__ dinv,
        int2* __restrict__ regions) {
    int i = blockIdx.x * blockDim.x + threadIdx.x;
    int b = i / CAP;
    if (b >= NB) return;
    int off = i - b * CAP;
    int cnt = cursor[b]; if (cnt > CAP) cnt = CAP;
    if (off >= cnt) return;
    int2 r = regions[i];
    r.y = __float_as_int(__int_as_float(r.y) * dinv[r.x]);
    regions[i] = r;
}

// ---------------- concat x,pos -> P1 cols 0..7 (stride 32) ----------------
__global__ __launch_bounds__(256) void concat_kernel(const float* __restrict__ x,
                                                     const float* __restrict__ pos,
                                                     float* __restrict__ P1, int n) {
    int i = blockIdx.x * blockDim.x + threadIdx.x;
    if (i >= n) return;
    float2 a = *reinterpret_cast<const float2*>(x + (size_t)i * 6);
    float2 b = *reinterpret_cast<const float2*>(x + (size_t)i * 6 + 2);
    float2 c = *reinterpret_cast<const float2*>(x + (size_t)i * 6 + 4);
    float2 p = *reinterpret_cast<const float2*>(pos + (size_t)i * 2);
    float4 v0 = make_float4(a.x, a.y, b.x, b.y);
    float4 v1 = make_float4(c.x, c.y, p.x, p.y);
    *reinterpret_cast<float4*>(P1 + (size_t)i * 32)     = v0;
    *reinterpret_cast<float4*>(P1 + (size_t)i * 32 + 4) = v1;
}

// ---------------- propagation: hout[node] (+)= sum_edges w * hin[src] ----------------
// Edges live in capacity-strided bucket regions; row_start embeds region bases.
// NPB must divide 128 so a block never spans a bucket; ends clamped to bucket count.
template <int TPN, bool ACC>
__global__ __launch_bounds__(256) void prop_kernel(const int* __restrict__ row_start,
                                                   const int* __restrict__ cursor,
                                                   const int2* __restrict__ edges,
                                                   const float* __restrict__ hin, int in_stride,
                                                   float* __restrict__ hout, int out_stride, int n) {
    constexpr int NPB = 256 / TPN;
    __shared__ int2 se[CH];
    int tid = threadIdx.x;
    int nb = blockIdx.x * NPB;
    int node = nb + tid / TPN;
    int lane = tid % TPN;
    int nbEnd = (nb + NPB < n) ? (nb + NPB) : n;
    int bkt = nb >> 7;
    int cc = cursor[bkt]; if (cc > CAP) cc = CAP;
    int ce = bkt * CAP + cc;
    int blkBeg = row_start[nb];
    int blkEnd = row_start[nbEnd]; if (blkEnd > ce) blkEnd = ce;
    int beg = 0, end = 0;
    if (node < n) {
        beg = row_start[node];
        end = row_start[node + 1]; if (end > ce) end = ce;
    }
    float ax = 0.f, ay = 0.f, az = 0.f, aw = 0.f;
    for (int base = blkBeg; base < blkEnd; base += CH) {
        int m = blkEnd - base; if (m > CH) m = CH;
        __syncthreads();
        for (int i = tid; i < m; i += 256) se[i] = edges[base + i];
        __syncthreads();
        int lo = (beg > base) ? (beg - base) : 0;
        int hi = ((end < base + m) ? end : (base + m)) - base;
        for (int i = lo; i < hi; ++i) {
            int2 e = se[i];
            float w = __int_as_float(e.y);
            const float4 v = *reinterpret_cast<const float4*>(hin + (size_t)e.x * in_stride + lane * 4);
            ax += w * v.x; ay += w * v.y; az += w * v.z; aw += w * v.w;
        }
    }
    if (node < n) {
        float4* po = reinterpret_cast<float4*>(hout + (size_t)node * out_stride + lane * 4);
        float4 r = make_float4(ax, ay, az, aw);
        if (ACC) { float4 o = *po; r.x += o.x; r.y += o.y; r.z += o.z; r.w += o.w; }
        *po = r;
    }
}

// ---------------- final prop: out = log_softmax(g0 + A*t1 + b3) ----------------
__global__ __launch_bounds__(256) void prop_final_kernel(const int* __restrict__ row_start,
                                                         const int* __restrict__ cursor,
                                                         const int2* __restrict__ edges,
                                                         const float* __restrict__ hin,
                                                         const float* __restrict__ g0,
                                                         const float* __restrict__ b3,
                                                         float* __restrict__ out, int n) {
    constexpr int TPN = 4, NPB = 64;
    __shared__ int2 se[CH];
    int tid = threadIdx.x;
    int nb = blockIdx.x * NPB;
    int node = nb + tid / TPN;
    int lane = tid & 3;
    int nbEnd = (nb + NPB < n) ? (nb + NPB) : n;
    int bkt = nb >> 7;
    int cc = cursor[bkt]; if (cc > CAP) cc = CAP;
    int ce = bkt * CAP + cc;
    int blkBeg = row_start[nb];
    int blkEnd = row_start[nbEnd]; if (blkEnd > ce) blkEnd = ce;
    int beg = 0, end = 0;
    if (node < n) {
        beg = row_start[node];
        end = row_start[node + 1]; if (end > ce) end = ce;
    }
    float ax = 0.f, ay = 0.f, az = 0.f, aw = 0.f;
    for (int base = blkBeg; base < blkEnd; base += CH) {
        int m = blkEnd - base; if (m > CH) m = CH;
        __syncthreads();
        for (int i = tid; i < m; i += 256) se[i] = edges[base + i];
        __syncthreads();
        int lo = (beg > base) ? (beg - base) : 0;
        int hi = ((end < base + m) ? end : (base + m)) - base;
        for (int i = lo; i < hi; ++i) {
            int2 e = se[i];
            float w = __int_as_float(e.y);
            const float4 v = *reinterpret_cast<const float4*>(hin + (size_t)e.x * 64 + lane * 4);
            ax += w * v.x; ay += w * v.y; az += w * v.z; aw += w * v.w;
        }
    }
    if (node < n) {
        const float4 g = *reinterpret_cast<const float4*>(g0 + (size_t)node * 64 + lane * 4);
        float vv[4] = {ax + g.x, ay + g.y, az + g.z, aw + g.w};
        int c0 = lane * 4;
        float mloc = -1e30f;
        #pragma unroll
        for (int c = 0; c < 4; ++c) {
            int col = c0 + c;
            if (col < NOUT) { vv[c] += b3[col]; mloc = fmaxf(mloc, vv[c]); }
        }
        float mo = fmaxf(mloc, __shfl_xor(mloc, 1));
        mo = fmaxf(mo, __shfl_xor(mo, 2));
        float sl = 0.f;
        #pragma unroll
        for (int c = 0; c < 4; ++c) {
            int col = c0 + c;
            if (col < NOUT) sl += __expf(vv[c] - mo);
        }
        sl += __shfl_xor(sl, 1);
        sl += __shfl_xor(sl, 2);
        float ls = __logf(sl);
        #pragma unroll
        for (int c = 0; c < 4; ++c) {
            int col = c0 + c;
            if (col < NOUT) out[(size_t)node * NOUT + col] = vv[c] - mo - ls;
        }
    }
}

// ---------------- register-blocked matmul: 64 nodes x 64 outs per block ----------------
template <int FIN, int KC, int EPI, int WMODE>
__global__ __launch_bounds__(256) void mm2_kernel(const float* __restrict__ h, int hstride,
                                                  const float* __restrict__ W,
                                                  const float* __restrict__ bias,
                                                  float* __restrict__ out, int ostride, int n) {
    constexpr int HP = 68;
    __shared__ float HsT[KC * HP];
    __shared__ float Ws[KC * 64];
    int tid = threadIdx.x;
    int ndq = tid >> 4;
    int f4  = tid & 15;
    int nd  = tid & 63;
    int wv  = tid >> 6;
    int nodeBase = blockIdx.x * 64;

    float4 acc0 = make_float4(0.f, 0.f, 0.f, 0.f);
    float4 acc1 = make_float4(0.f, 0.f, 0.f, 0.f);
    float4 acc2 = make_float4(0.f, 0.f, 0.f, 0.f);
    float4 acc3 = make_float4(0.f, 0.f, 0.f, 0.f);

    for (int kc = 0; kc < FIN; kc += KC) {
        if (WMODE == 0) {
            for (int i = tid * 4; i < KC * 64; i += 1024)
                *reinterpret_cast<float4*>(&Ws[i]) =
                    *reinterpret_cast<const float4*>(&W[(size_t)kc * 64 + i]);
        } else {
            for (int i = tid; i < KC * 64; i += 256) {
                int r = i >> 6, c = i & 63;
                int k = c >> 4, j = c & 15;
                Ws[i] = (j < NOUT) ? W[((size_t)k * FIN + kc + r) * NOUT + j] : 0.f;
            }
        }
        int node = nodeBase + nd;
        #pragma unroll
        for (int r = 0; r < KC / 16; ++r) {
            int k0 = wv * 4 + r * 16;
            float4 hv = make_float4(0.f, 0.f, 0.f, 0.f);
            if (node < n)
                hv = *reinterpret_cast<const float4*>(&h[(size_t)node * hstride + kc + k0]);
            HsT[(k0 + 0) * HP + nd] = hv.x;
            HsT[(k0 + 1) * HP + nd] = hv.y;
            HsT[(k0 + 2) * HP + nd] = hv.z;
            HsT[(k0 + 3) * HP + nd] = hv.w;
        }
        __syncthreads();
        #pragma unroll 8
        for (int k = 0; k < KC; ++k) {
            const float4 hq = *reinterpret_cast<const float4*>(&HsT[k * HP + ndq * 4]);
            const float4 wq = *reinterpret_cast<const float4*>(&Ws[k * 64 + f4 * 4]);
            acc0.x += hq.x * wq.x; acc0.y += hq.x * wq.y; acc0.z += hq.x * wq.z; acc0.w += hq.x * wq.w;
            acc1.x += hq.y * wq.x; acc1.y += hq.y * wq.y; acc1.z += hq.y * wq.z; acc1.w += hq.y * wq.w;
            acc2.x += hq.z * wq.x; acc2.y += hq.z * wq.y; acc2.z += hq.z * wq.z; acc2.w += hq.z * wq.w;
            acc3.x += hq.w * wq.x; acc3.y += hq.w * wq.y; acc3.z += hq.w * wq.z; acc3.w += hq.w * wq.w;
        }
        __syncthreads();
    }

    float4 bv = make_float4(0.f, 0.f, 0.f, 0.f);
    if (EPI == 1) bv = *reinterpret_cast<const float4*>(&bias[f4 * 4]);
    float4 accs[4] = {acc0, acc1, acc2, acc3};
    #pragma unroll
    for (int i = 0; i < 4; ++i) {
        int node = nodeBase + ndq * 4 + i;
        if (node < n) {
            float4 a = accs[i];
            if (EPI == 1) {
                a.x = fmaxf(a.x + bv.x, 0.f); a.y = fmaxf(a.y + bv.y, 0.f);
                a.z = fmaxf(a.z + bv.z, 0.f); a.w = fmaxf(a.w + bv.w, 0.f);
            }
            *reinterpret_cast<float4*>(out + (size_t)node * ostride + f4 * 4) = a;
        }
    }
}

extern "C" void kernel_launch(void* const* d_in, const int* in_sizes, int n_in,
                              void* d_out, int out_size, void* d_ws, size_t ws_size,
                              hipStream_t stream) {
    const float* x   = (const float*)d_in[0];
    const float* pos = (const float*)d_in[1];
    const float* ea  = (const float*)d_in[2];
    const float* W1  = (const float*)d_in[3];   // (4,8,64) == (32,64)
    const float* b1  = (const float*)d_in[4];
    const float* W2  = (const float*)d_in[5];   // (4,64,64) == (256,64)
    const float* b2  = (const float*)d_in[6];
    const float* W3  = (const float*)d_in[7];   // (4,64,10)
    const float* b3  = (const float*)d_in[8];
    const int* eidx  = (const int*)d_in[9];
    const int* src = eidx;
    const int* dst = eidx + EE;
    float* outp = (float*)d_out;

    size_t off = 0;
    char* base = (char*)d_ws;
    auto alloc = [&](size_t bytes) -> void* {
        void* p = base + off;
        off += (bytes + 255) & ~(size_t)255;
        return p;
    };
    int*   cursor    = (int*)alloc(NB * 4);
    int*   row_start = (int*)alloc((NN + 1) * 4);
    float* dinv      = (float*)alloc(NN * 4);
    int2*  edges     = (int2*)alloc((size_t)NB * CAP * 8);   // strided bucket regions
    float* S1        = (float*)alloc((size_t)NN * 64 * 4);   // P1 (N x 32) / h2 (N x 64)
    float* S2        = (float*)alloc((size_t)NN * 256 * 4);  // P2 (N x 256) / T (N x 64)
    float* P1 = S1;
    float* h2 = S1;
    float* P2 = S2;
    float* T  = S2;
    (void)ws_size;

    const int B = 256;
    const int gN = (NN + B - 1) / B;
    const int gK1 = (EE + K1_EPB - 1) / K1_EPB;      // 196
    const int gK3 = (NB * CAP + B - 1) / B;          // 3666
    const int gMM2 = (NN + 63) / 64;                 // 782
    const int gP2  = (NN + 127) / 128;               // 391
    const int gP16 = (NN + 15) / 16;                 // 3125
    const int gP4  = (NN + 63) / 64;                 // 782

    hipMemsetAsync(cursor, 0, NB * 4, stream);

    // ---- CSR build (bucketed, atomic-light) ----
    bucket_scatter_kernel<<<gK1, B, 0, stream>>>(src, dst, ea, cursor, edges, EE);
    bucket_build_kernel<<<NB, B, 0, stream>>>(cursor, edges, dinv, row_start, NN);
    srcscale_kernel<<<gK3, B, 0, stream>>>(cursor, dinv, edges);

    // ---- layer 1: P1 = [h0, Ah0, A2h0, A3h0] (N x 32); h1 = relu(P1@W1+b1) -> P2 cols 0:64 ----
    concat_kernel<<<gN, B, 0, stream>>>(x, pos, P1, NN);
    prop_kernel<2, false><<<gP2, B, 0, stream>>>(row_start, cursor, edges, P1,      32, P1 + 8,  32, NN);
    prop_kernel<2, false><<<gP2, B, 0, stream>>>(row_start, cursor, edges, P1 + 8,  32, P1 + 16, 32, NN);
    prop_kernel<2, false><<<gP2, B, 0, stream>>>(row_start, cursor, edges, P1 + 16, 32, P1 + 24, 32, NN);
    mm2_kernel<32, 32, 1, 0><<<gMM2, B, 0, stream>>>(P1, 32, W1, b1, P2, 256, NN);

    // ---- layer 2: P2 = [h1, Ah1, A2h1, A3h1] (N x 256); h2 = relu(P2@W2+b2) ----
    prop_kernel<16, false><<<gP16, B, 0, stream>>>(row_start, cursor, edges, P2,       256, P2 + 64,  256, NN);
    prop_kernel<16, false><<<gP16, B, 0, stream>>>(row_start, cursor, edges, P2 + 64,  256, P2 + 128, 256, NN);
    prop_kernel<16, false><<<gP16, B, 0, stream>>>(row_start, cursor, edges, P2 + 128, 256, P2 + 192, 256, NN);
    mm2_kernel<256, 64, 1, 0><<<gMM2, B, 0, stream>>>(P2, 256, W2, b2, h2, 64, NN);

    // ---- layer 3 (Horner): T[n, k*16+j] = (h2 @ W3[k])[n,j] (j<10 padded to 16) ----
    mm2_kernel<64, 64, 0, 1><<<gMM2, B, 0, stream>>>(h2, 64, W3, nullptr, T, 64, NN);
    prop_kernel<4, true><<<gP4, B, 0, stream>>>(row_start, cursor, edges, T + 48, 64, T + 32, 64, NN);
    prop_kernel<4, true><<<gP4, B, 0, stream>>>(row_start, cursor, edges, T + 32, 64, T + 16, 64, NN);
    prop_final_kernel<<<gP4, B, 0, stream>>>(row_start, cursor, edges, T + 16, T, b3, outp, NN);
}

// Round 5
// 361.838 us; speedup vs baseline: 1.9330x; 1.3847x over previous
//
#include <hip/hip_runtime.h>
#include <math.h>

// TAGConv GNN: N=50000, E=800000, K=3, layers (8->64, 64->64, 64->10)
// v5: edge-split prop teams (TPN x ES threads per node, shfl_xor merge) to fix
// the latency-bound narrow propagations (occupancy 11% -> ~50%+).
// Rest from v4: bucketed atomic-light CSR build, register-blocked 64x64 matmuls,
// Horner layer 3, fused epilogues.

#define NN 50000
#define EE 800000
#define HID 64
#define NOUT 10
#define CH 512

#define NB 391        // ceil(50000/128) buckets of 128 nodes
#define CAP 2400      // region capacity (mean 2047, +7.8 sigma)
#define K1_EPB 4096   // edges per K1 block

// ---------------- K1: coarse bucket scatter ----------------
__global__ __launch_bounds__(256) void bucket_scatter_kernel(
        const int* __restrict__ src, const int* __restrict__ dst,
        const float* __restrict__ ea, int* __restrict__ cursor,
        int2* __restrict__ regions, int e) {
    __shared__ int hist[NB];
    __shared__ int base[NB];
    int tid = threadIdx.x;
    int e0 = blockIdx.x * K1_EPB;
    int e1 = e0 + K1_EPB; if (e1 > e) e1 = e;
    for (int i = tid; i < NB; i += 256) hist[i] = 0;
    __syncthreads();
    for (int i = e0 + tid; i < e1; i += 256)
        atomicAdd(&hist[dst[i] >> 7], 1);
    __syncthreads();
    for (int b = tid; b < NB; b += 256) {
        int c = hist[b];
        base[b] = (c > 0) ? atomicAdd(&cursor[b], c) : 0;
        hist[b] = 0;   // reuse as local cursor
    }
    __syncthreads();
    for (int i = e0 + tid; i < e1; i += 256) {
        int d = dst[i];
        int b = d >> 7;
        int r = atomicAdd(&hist[b], 1);
        int pos = base[b] + r;
        if (pos < CAP)
            regions[(size_t)b * CAP + pos] =
                make_int2(((d & 127) << 16) | src[i], __float_as_int(ea[i]));
    }
}

// ---------------- K2: per-bucket fine sort + row_start + dinv + w0 ----------------
__global__ __launch_bounds__(256) void bucket_build_kernel(
        const int* __restrict__ cursor, int2* __restrict__ regions,
        float* __restrict__ dinv, int* __restrict__ row_start, int n) {
    __shared__ int2 rec[CAP];
    __shared__ int hist[128];
    __shared__ float easum[128];
    __shared__ float dl[128];
    __shared__ int off[129];
    __shared__ int lcur[128];
    int b = blockIdx.x;
    int tid = threadIdx.x;
    int cnt = cursor[b]; if (cnt > CAP) cnt = CAP;
    size_t rb = (size_t)b * CAP;
    if (tid < 128) { hist[tid] = 0; easum[tid] = 0.f; lcur[tid] = 0; }
    __syncthreads();
    for (int i = tid; i < cnt; i += 256) {
        int2 r = regions[rb + i];
        rec[i] = r;
        int f = r.x >> 16;
        atomicAdd(&hist[f], 1);
        atomicAdd(&easum[f], __int_as_float(r.y));
    }
    __syncthreads();
    if (tid < 128) {
        int lane = tid & 63;
        int v = hist[tid];
        for (int o2 = 1; o2 < 64; o2 <<= 1) {
            int y = __shfl_up(v, o2, 64);
            if (lane >= o2) v += y;
        }
        off[tid + 1] = v;     // wave-local inclusive
        float s2 = easum[tid];
        dl[tid] = (s2 > 0.f) ? rsqrtf(s2) : 0.f;
    }
    __syncthreads();
    if (tid == 255) off[0] = 0;
    if (tid >= 64 && tid < 128) off[tid + 1] += off[64];
    __syncthreads();
    if (tid < 128) {
        int node = b * 128 + tid;
        if (node <= n) row_start[node] = b * CAP + off[tid];
        if (node < n)  dinv[node] = dl[tid];
    }
    __syncthreads();
    for (int i = tid; i < cnt; i += 256) {
        int2 r = rec[i];
        int f = r.x >> 16;
        int s = r.x & 0xFFFF;
        int p = atomicAdd(&lcur[f], 1);
        float w0 = __int_as_float(r.y) * dl[f];
        regions[rb + off[f] + p] = make_int2(s, __float_as_int(w0));
    }
}

// ---------------- K3: w *= dinv[src] ----------------
__global__ __launch_bounds__(256) void srcscale_kernel(
        const int* __restrict__ cursor, const float* __restrict__ dinv,
        int2* __restrict__ regions) {
    int i = blockIdx.x * blockDim.x + threadIdx.x;
    int b = i / CAP;
    if (b >= NB) return;
    int off = i - b * CAP;
    int cnt = cursor[b]; if (cnt > CAP) cnt = CAP;
    if (off >= cnt) return;
    int2 r = regions[i];
    r.y = __float_as_int(__int_as_float(r.y) * dinv[r.x]);
    regions[i] = r;
}

// ---------------- concat x,pos -> P1 cols 0..7 (stride 32) ----------------
__global__ __launch_bounds__(256) void concat_kernel(const float* __restrict__ x,
                                                     const float* __restrict__ pos,
                                                     float* __restrict__ P1, int n) {
    int i = blockIdx.x * blockDim.x + threadIdx.x;
    if (i >= n) return;
    float2 a = *reinterpret_cast<const float2*>(x + (size_t)i * 6);
    float2 b = *reinterpret_cast<const float2*>(x + (size_t)i * 6 + 2);
    float2 c = *reinterpret_cast<const float2*>(x + (size_t)i * 6 + 4);
    float2 p = *reinterpret_cast<const float2*>(pos + (size_t)i * 2);
    float4 v0 = make_float4(a.x, a.y, b.x, b.y);
    float4 v1 = make_float4(c.x, c.y, p.x, p.y);
    *reinterpret_cast<float4*>(P1 + (size_t)i * 32)     = v0;
    *reinterpret_cast<float4*>(P1 + (size_t)i * 32 + 4) = v1;
}

// ---------------- propagation: hout[node] (+)= sum_edges w * hin[src] ----------------
// Team of TPN*ES threads per node: TPN lanes cover the feature width (float4 each),
// ES sub-teams partition the edge list (stride ES) and merge via shfl_xor butterfly.
// NPB = 256/(TPN*ES) must divide 128 so a block never spans a bucket.
template <int TPN, int ES, bool ACC>
__global__ __launch_bounds__(256) void prop_kernel(const int* __restrict__ row_start,
                                                   const int* __restrict__ cursor,
                                                   const int2* __restrict__ edges,
                                                   const float* __restrict__ hin, int in_stride,
                                                   float* __restrict__ hout, int out_stride, int n) {
    constexpr int TEAM = TPN * ES;
    constexpr int NPB = 256 / TEAM;
    __shared__ int2 se[CH];
    int tid = threadIdx.x;
    int nb = blockIdx.x * NPB;
    int node = nb + tid / TEAM;
    int t = tid % TEAM;
    int es = t / TPN;          // edge-split sub-team 0..ES-1
    int lane = t % TPN;        // feature quad 0..TPN-1
    int nbEnd = (nb + NPB < n) ? (nb + NPB) : n;
    int bkt = nb >> 7;
    int cc = cursor[bkt]; if (cc > CAP) cc = CAP;
    int ce = bkt * CAP + cc;
    int blkBeg = row_start[nb];
    int blkEnd = row_start[nbEnd]; if (blkEnd > ce) blkEnd = ce;
    int beg = 0, end = 0;
    if (node < n) {
        beg = row_start[node];
        end = row_start[node + 1]; if (end > ce) end = ce;
    }
    float ax = 0.f, ay = 0.f, az = 0.f, aw = 0.f;
    for (int base = blkBeg; base < blkEnd; base += CH) {
        int m = blkEnd - base; if (m > CH) m = CH;
        __syncthreads();
        for (int i = tid; i < m; i += 256) se[i] = edges[base + i];
        __syncthreads();
        int lo = (beg > base) ? (beg - base) : 0;
        int hi = ((end < base + m) ? end : (base + m)) - base;
        for (int i = lo + es; i < hi; i += ES) {
            int2 e = se[i];
            float w = __int_as_float(e.y);
            const float4 v = *reinterpret_cast<const float4*>(hin + (size_t)e.x * in_stride + lane * 4);
            ax += w * v.x; ay += w * v.y; az += w * v.z; aw += w * v.w;
        }
    }
    // merge edge-split partials (teams are wave-aligned: TEAM divides 64)
    #pragma unroll
    for (int msk = TPN; msk < TEAM; msk <<= 1) {
        ax += __shfl_xor(ax, msk);
        ay += __shfl_xor(ay, msk);
        az += __shfl_xor(az, msk);
        aw += __shfl_xor(aw, msk);
    }
    if (node < n && es == 0) {
        float4* po = reinterpret_cast<float4*>(hout + (size_t)node * out_stride + lane * 4);
        float4 r = make_float4(ax, ay, az, aw);
        if (ACC) { float4 o = *po; r.x += o.x; r.y += o.y; r.z += o.z; r.w += o.w; }
        *po = r;
    }
}

// ---------------- final prop: out = log_softmax(g0 + A*t1 + b3) ----------------
// Team of 8 (TPN=4 x ES=2) per node.
__global__ __launch_bounds__(256) void prop_final_kernel(const int* __restrict__ row_start,
                                                         const int* __restrict__ cursor,
                                                         const int2* __restrict__ edges,
                                                         const float* __restrict__ hin,
                                                         const float* __restrict__ g0,
                                                         const float* __restrict__ b3,
                                                         float* __restrict__ out, int n) {
    constexpr int TPN = 4, ES = 2, TEAM = 8, NPB = 32;
    __shared__ int2 se[CH];
    int tid = threadIdx.x;
    int nb = blockIdx.x * NPB;
    int node = nb + tid / TEAM;
    int t = tid % TEAM;
    int es = t / TPN;
    int lane = t % TPN;
    int nbEnd = (nb + NPB < n) ? (nb + NPB) : n;
    int bkt = nb >> 7;
    int cc = cursor[bkt]; if (cc > CAP) cc = CAP;
    int ce = bkt * CAP + cc;
    int blkBeg = row_start[nb];
    int blkEnd = row_start[nbEnd]; if (blkEnd > ce) blkEnd = ce;
    int beg = 0, end = 0;
    if (node < n) {
        beg = row_start[node];
        end = row_start[node + 1]; if (end > ce) end = ce;
    }
    float ax = 0.f, ay = 0.f, az = 0.f, aw = 0.f;
    for (int base = blkBeg; base < blkEnd; base += CH) {
        int m = blkEnd - base; if (m > CH) m = CH;
        __syncthreads();
        for (int i = tid; i < m; i += 256) se[i] = edges[base + i];
        __syncthreads();
        int lo = (beg > base) ? (beg - base) : 0;
        int hi = ((end < base + m) ? end : (base + m)) - base;
        for (int i = lo + es; i < hi; i += ES) {
            int2 e = se[i];
            float w = __int_as_float(e.y);
            const float4 v = *reinterpret_cast<const float4*>(hin + (size_t)e.x * 64 + lane * 4);
            ax += w * v.x; ay += w * v.y; az += w * v.z; aw += w * v.w;
        }
    }
    ax += __shfl_xor(ax, TPN);
    ay += __shfl_xor(ay, TPN);
    az += __shfl_xor(az, TPN);
    aw += __shfl_xor(aw, TPN);
    if (node < n && es == 0) {
        const float4 g = *reinterpret_cast<const float4*>(g0 + (size_t)node * 64 + lane * 4);
        float vv[4] = {ax + g.x, ay + g.y, az + g.z, aw + g.w};
        int c0 = lane * 4;
        float mloc = -1e30f;
        #pragma unroll
        for (int c = 0; c < 4; ++c) {
            int col = c0 + c;
            if (col < NOUT) { vv[c] += b3[col]; mloc = fmaxf(mloc, vv[c]); }
        }
        float mo = fmaxf(mloc, __shfl_xor(mloc, 1));
        mo = fmaxf(mo, __shfl_xor(mo, 2));
        float sl = 0.f;
        #pragma unroll
        for (int c = 0; c < 4; ++c) {
            int col = c0 + c;
            if (col < NOUT) sl += __expf(vv[c] - mo);
        }
        sl += __shfl_xor(sl, 1);
        sl += __shfl_xor(sl, 2);
        float ls = __logf(sl);
        #pragma unroll
        for (int c = 0; c < 4; ++c) {
            int col = c0 + c;
            if (col < NOUT) out[(size_t)node * NOUT + col] = vv[c] - mo - ls;
        }
    }
}

// ---------------- register-blocked matmul: 64 nodes x 64 outs per block ----------------
template <int FIN, int KC, int EPI, int WMODE>
__global__ __launch_bounds__(256) void mm2_kernel(const float* __restrict__ h, int hstride,
                                                  const float* __restrict__ W,
                                                  const float* __restrict__ bias,
                                                  float* __restrict__ out, int ostride, int n) {
    constexpr int HP = 68;
    __shared__ float HsT[KC * HP];
    __shared__ float Ws[KC * 64];
    int tid = threadIdx.x;
    int ndq = tid >> 4;
    int f4  = tid & 15;
    int nd  = tid & 63;
    int wv  = tid >> 6;
    int nodeBase = blockIdx.x * 64;

    float4 acc0 = make_float4(0.f, 0.f, 0.f, 0.f);
    float4 acc1 = make_float4(0.f, 0.f, 0.f, 0.f);
    float4 acc2 = make_float4(0.f, 0.f, 0.f, 0.f);
    float4 acc3 = make_float4(0.f, 0.f, 0.f, 0.f);

    for (int kc = 0; kc < FIN; kc += KC) {
        if (WMODE == 0) {
            for (int i = tid * 4; i < KC * 64; i += 1024)
                *reinterpret_cast<float4*>(&Ws[i]) =
                    *reinterpret_cast<const float4*>(&W[(size_t)kc * 64 + i]);
        } else {
            for (int i = tid; i < KC * 64; i += 256) {
                int r = i >> 6, c = i & 63;
                int k = c >> 4, j = c & 15;
                Ws[i] = (j < NOUT) ? W[((size_t)k * FIN + kc + r) * NOUT + j] : 0.f;
            }
        }
        int node = nodeBase + nd;
        #pragma unroll
        for (int r = 0; r < KC / 16; ++r) {
            int k0 = wv * 4 + r * 16;
            float4 hv = make_float4(0.f, 0.f, 0.f, 0.f);
            if (node < n)
                hv = *reinterpret_cast<const float4*>(&h[(size_t)node * hstride + kc + k0]);
            HsT[(k0 + 0) * HP + nd] = hv.x;
            HsT[(k0 + 1) * HP + nd] = hv.y;
            HsT[(k0 + 2) * HP + nd] = hv.z;
            HsT[(k0 + 3) * HP + nd] = hv.w;
        }
        __syncthreads();
        #pragma unroll 8
        for (int k = 0; k < KC; ++k) {
            const float4 hq = *reinterpret_cast<const float4*>(&HsT[k * HP + ndq * 4]);
            const float4 wq = *reinterpret_cast<const float4*>(&Ws[k * 64 + f4 * 4]);
            acc0.x += hq.x * wq.x; acc0.y += hq.x * wq.y; acc0.z += hq.x * wq.z; acc0.w += hq.x * wq.w;
            acc1.x += hq.y * wq.x; acc1.y += hq.y * wq.y; acc1.z += hq.y * wq.z; acc1.w += hq.y * wq.w;
            acc2.x += hq.z * wq.x; acc2.y += hq.z * wq.y; acc2.z += hq.z * wq.z; acc2.w += hq.z * wq.w;
            acc3.x += hq.w * wq.x; acc3.y += hq.w * wq.y; acc3.z += hq.w * wq.z; acc3.w += hq.w * wq.w;
        }
        __syncthreads();
    }

    float4 bv = make_float4(0.f, 0.f, 0.f, 0.f);
    if (EPI == 1) bv = *reinterpret_cast<const float4*>(&bias[f4 * 4]);
    float4 accs[4] = {acc0, acc1, acc2, acc3};
    #pragma unroll
    for (int i = 0; i < 4; ++i) {
        int node = nodeBase + ndq * 4 + i;
        if (node < n) {
            float4 a = accs[i];
            if (EPI == 1) {
                a.x = fmaxf(a.x + bv.x, 0.f); a.y = fmaxf(a.y + bv.y, 0.f);
                a.z = fmaxf(a.z + bv.z, 0.f); a.w = fmaxf(a.w + bv.w, 0.f);
            }
            *reinterpret_cast<float4*>(out + (size_t)node * ostride + f4 * 4) = a;
        }
    }
}

extern "C" void kernel_launch(void* const* d_in, const int* in_sizes, int n_in,
                              void* d_out, int out_size, void* d_ws, size_t ws_size,
                              hipStream_t stream) {
    const float* x   = (const float*)d_in[0];
    const float* pos = (const float*)d_in[1];
    const float* ea  = (const float*)d_in[2];
    const float* W1  = (const float*)d_in[3];   // (4,8,64) == (32,64)
    const float* b1  = (const float*)d_in[4];
    const float* W2  = (const float*)d_in[5];   // (4,64,64) == (256,64)
    const float* b2  = (const float*)d_in[6];
    const float* W3  = (const float*)d_in[7];   // (4,64,10)
    const float* b3  = (const float*)d_in[8];
    const int* eidx  = (const int*)d_in[9];
    const int* src = eidx;
    const int* dst = eidx + EE;
    float* outp = (float*)d_out;

    size_t off = 0;
    char* base = (char*)d_ws;
    auto alloc = [&](size_t bytes) -> void* {
        void* p = base + off;
        off += (bytes + 255) & ~(size_t)255;
        return p;
    };
    int*   cursor    = (int*)alloc(NB * 4);
    int*   row_start = (int*)alloc((NN + 1) * 4);
    float* dinv      = (float*)alloc(NN * 4);
    int2*  edges     = (int2*)alloc((size_t)NB * CAP * 8);   // strided bucket regions
    float* S1        = (float*)alloc((size_t)NN * 64 * 4);   // P1 (N x 32) / h2 (N x 64)
    float* S2        = (float*)alloc((size_t)NN * 256 * 4);  // P2 (N x 256) / T (N x 64)
    float* P1 = S1;
    float* h2 = S1;
    float* P2 = S2;
    float* T  = S2;
    (void)ws_size;

    const int B = 256;
    const int gN = (NN + B - 1) / B;
    const int gK1 = (EE + K1_EPB - 1) / K1_EPB;      // 196
    const int gK3 = (NB * CAP + B - 1) / B;          // 3666
    const int gMM2 = (NN + 63) / 64;                 // 782
    const int gP32 = (NN + 31) / 32;                 // 1563 (NPB=32 teams)
    const int gP16 = (NN + 15) / 16;                 // 3125 (NPB=16)

    hipMemsetAsync(cursor, 0, NB * 4, stream);

    // ---- CSR build (bucketed, atomic-light) ----
    bucket_scatter_kernel<<<gK1, B, 0, stream>>>(src, dst, ea, cursor, edges, EE);
    bucket_build_kernel<<<NB, B, 0, stream>>>(cursor, edges, dinv, row_start, NN);
    srcscale_kernel<<<gK3, B, 0, stream>>>(cursor, dinv, edges);

    // ---- layer 1: P1 = [h0, Ah0, A2h0, A3h0] (N x 32); h1 = relu(P1@W1+b1) -> P2 cols 0:64 ----
    concat_kernel<<<gN, B, 0, stream>>>(x, pos, P1, NN);
    prop_kernel<2, 4, false><<<gP32, B, 0, stream>>>(row_start, cursor, edges, P1,      32, P1 + 8,  32, NN);
    prop_kernel<2, 4, false><<<gP32, B, 0, stream>>>(row_start, cursor, edges, P1 + 8,  32, P1 + 16, 32, NN);
    prop_kernel<2, 4, false><<<gP32, B, 0, stream>>>(row_start, cursor, edges, P1 + 16, 32, P1 + 24, 32, NN);
    mm2_kernel<32, 32, 1, 0><<<gMM2, B, 0, stream>>>(P1, 32, W1, b1, P2, 256, NN);

    // ---- layer 2: P2 = [h1, Ah1, A2h1, A3h1] (N x 256); h2 = relu(P2@W2+b2) ----
    prop_kernel<16, 1, false><<<gP16, B, 0, stream>>>(row_start, cursor, edges, P2,       256, P2 + 64,  256, NN);
    prop_kernel<16, 1, false><<<gP16, B, 0, stream>>>(row_start, cursor, edges, P2 + 64,  256, P2 + 128, 256, NN);
    prop_kernel<16, 1, false><<<gP16, B, 0, stream>>>(row_start, cursor, edges, P2 + 128, 256, P2 + 192, 256, NN);
    mm2_kernel<256, 64, 1, 0><<<gMM2, B, 0, stream>>>(P2, 256, W2, b2, h2, 64, NN);

    // ---- layer 3 (Horner): T[n, k*16+j] = (h2 @ W3[k])[n,j] (j<10 padded to 16) ----
    mm2_kernel<64, 64, 0, 1><<<gMM2, B, 0, stream>>>(h2, 64, W3, nullptr, T, 64, NN);
    prop_kernel<4, 2, true><<<gP32, B, 0, stream>>>(row_start, cursor, edges, T + 48, 64, T + 32, 64, NN);
    prop_kernel<4, 2, true><<<gP32, B, 0, stream>>>(row_start, cursor, edges, T + 32, 64, T + 16, 64, NN);
    prop_final_kernel<<<gP32, B, 0, stream>>>(row_start, cursor, edges, T + 16, T, b3, outp, NN);
}

// Round 6
// 320.324 us; speedup vs baseline: 2.1836x; 1.1296x over previous
//
#include <hip/hip_runtime.h>
#include <math.h>

// TAGConv GNN: N=50000, E=800000, K=3, layers (8->64, 64->64, 64->10)
// v6: layer-2 feature chain in bf16 (G table, N x 256 bf16): layer-1 mm writes
// bf16 h1; width-64 props gather bf16 rows (TPN=8 lanes x 16B, ES=4 edge-split,
// fp32 accumulate, bf16 RNE writeback); layer-2 mm reads bf16 G (fp32 FMA).
// Layer-1/3 remain fp32 (Horner layer 3, fused final log-softmax).
// CSR build: bucketed atomic-light (v4). Narrow props: edge-split teams (v5).

#define NN 50000
#define EE 800000
#define HID 64
#define NOUT 10
#define CH 512

#define NB 391        // ceil(50000/128) buckets of 128 nodes
#define CAP 2400      // region capacity (mean 2047, +7.8 sigma)
#define K1_EPB 4096   // edges per K1 block

// ---------------- bf16 helpers ----------------
__device__ __forceinline__ unsigned bf16rnd(float x) {
    unsigned u = __float_as_uint(x);
    return (u + 0x7FFFu + ((u >> 16) & 1u)) >> 16;
}
__device__ __forceinline__ unsigned packbf2(float a, float b) {
    return bf16rnd(a) | (bf16rnd(b) << 16);
}
__device__ __forceinline__ float bflo(unsigned u) { return __uint_as_float(u << 16); }
__device__ __forceinline__ float bfhi(unsigned u) { return __uint_as_float(u & 0xFFFF0000u); }

// ---------------- K1: coarse bucket scatter ----------------
__global__ __launch_bounds__(256) void bucket_scatter_kernel(
        const int* __restrict__ src, const int* __restrict__ dst,
        const float* __restrict__ ea, int* __restrict__ cursor,
        int2* __restrict__ regions, int e) {
    __shared__ int hist[NB];
    __shared__ int base[NB];
    int tid = threadIdx.x;
    int e0 = blockIdx.x * K1_EPB;
    int e1 = e0 + K1_EPB; if (e1 > e) e1 = e;
    for (int i = tid; i < NB; i += 256) hist[i] = 0;
    __syncthreads();
    for (int i = e0 + tid; i < e1; i += 256)
        atomicAdd(&hist[dst[i] >> 7], 1);
    __syncthreads();
    for (int b = tid; b < NB; b += 256) {
        int c = hist[b];
        base[b] = (c > 0) ? atomicAdd(&cursor[b], c) : 0;
        hist[b] = 0;   // reuse as local cursor
    }
    __syncthreads();
    for (int i = e0 + tid; i < e1; i += 256) {
        int d = dst[i];
        int b = d >> 7;
        int r = atomicAdd(&hist[b], 1);
        int pos = base[b] + r;
        if (pos < CAP)
            regions[(size_t)b * CAP + pos] =
                make_int2(((d & 127) << 16) | src[i], __float_as_int(ea[i]));
    }
}

// ---------------- K2: per-bucket fine sort + row_start + dinv + w0 ----------------
__global__ __launch_bounds__(256) void bucket_build_kernel(
        const int* __restrict__ cursor, int2* __restrict__ regions,
        float* __restrict__ dinv, int* __restrict__ row_start, int n) {
    __shared__ int2 rec[CAP];
    __shared__ int hist[128];
    __shared__ float easum[128];
    __shared__ float dl[128];
    __shared__ int off[129];
    __shared__ int lcur[128];
    int b = blockIdx.x;
    int tid = threadIdx.x;
    int cnt = cursor[b]; if (cnt > CAP) cnt = CAP;
    size_t rb = (size_t)b * CAP;
    if (tid < 128) { hist[tid] = 0; easum[tid] = 0.f; lcur[tid] = 0; }
    __syncthreads();
    for (int i = tid; i < cnt; i += 256) {
        int2 r = regions[rb + i];
        rec[i] = r;
        int f = r.x >> 16;
        atomicAdd(&hist[f], 1);
        atomicAdd(&easum[f], __int_as_float(r.y));
    }
    __syncthreads();
    if (tid < 128) {
        int lane = tid & 63;
        int v = hist[tid];
        for (int o2 = 1; o2 < 64; o2 <<= 1) {
            int y = __shfl_up(v, o2, 64);
            if (lane >= o2) v += y;
        }
        off[tid + 1] = v;     // wave-local inclusive
        float s2 = easum[tid];
        dl[tid] = (s2 > 0.f) ? rsqrtf(s2) : 0.f;
    }
    __syncthreads();
    if (tid == 255) off[0] = 0;
    if (tid >= 64 && tid < 128) off[tid + 1] += off[64];
    __syncthreads();
    if (tid < 128) {
        int node = b * 128 + tid;
        if (node <= n) row_start[node] = b * CAP + off[tid];
        if (node < n)  dinv[node] = dl[tid];
    }
    __syncthreads();
    for (int i = tid; i < cnt; i += 256) {
        int2 r = rec[i];
        int f = r.x >> 16;
        int s = r.x & 0xFFFF;
        int p = atomicAdd(&lcur[f], 1);
        float w0 = __int_as_float(r.y) * dl[f];
        regions[rb + off[f] + p] = make_int2(s, __float_as_int(w0));
    }
}

// ---------------- K3: w *= dinv[src] ----------------
__global__ __launch_bounds__(256) void srcscale_kernel(
        const int* __restrict__ cursor, const float* __restrict__ dinv,
        int2* __restrict__ regions) {
    int i = blockIdx.x * blockDim.x + threadIdx.x;
    int b = i / CAP;
    if (b >= NB) return;
    int off = i - b * CAP;
    int cnt = cursor[b]; if (cnt > CAP) cnt = CAP;
    if (off >= cnt) return;
    int2 r = regions[i];
    r.y = __float_as_int(__int_as_float(r.y) * dinv[r.x]);
    regions[i] = r;
}

// ---------------- concat x,pos -> P1 cols 0..7 (stride 32) ----------------
__global__ __launch_bounds__(256) void concat_kernel(const float* __restrict__ x,
                                                     const float* __restrict__ pos,
                                                     float* __restrict__ P1, int n) {
    int i = blockIdx.x * blockDim.x + threadIdx.x;
    if (i >= n) return;
    float2 a = *reinterpret_cast<const float2*>(x + (size_t)i * 6);
    float2 b = *reinterpret_cast<const float2*>(x + (size_t)i * 6 + 2);
    float2 c = *reinterpret_cast<const float2*>(x + (size_t)i * 6 + 4);
    float2 p = *reinterpret_cast<const float2*>(pos + (size_t)i * 2);
    float4 v0 = make_float4(a.x, a.y, b.x, b.y);
    float4 v1 = make_float4(c.x, c.y, p.x, p.y);
    *reinterpret_cast<float4*>(P1 + (size_t)i * 32)     = v0;
    *reinterpret_cast<float4*>(P1 + (size_t)i * 32 + 4) = v1;
}

// ---------------- fp32 propagation (layer 1 / layer 3) ----------------
template <int TPN, int ES, bool ACC>
__global__ __launch_bounds__(256) void prop_kernel(const int* __restrict__ row_start,
                                                   const int* __restrict__ cursor,
                                                   const int2* __restrict__ edges,
                                                   const float* __restrict__ hin, int in_stride,
                                                   float* __restrict__ hout, int out_stride, int n) {
    constexpr int TEAM = TPN * ES;
    constexpr int NPB = 256 / TEAM;
    __shared__ int2 se[CH];
    int tid = threadIdx.x;
    int nb = blockIdx.x * NPB;
    int node = nb + tid / TEAM;
    int t = tid % TEAM;
    int es = t / TPN;
    int lane = t % TPN;
    int nbEnd = (nb + NPB < n) ? (nb + NPB) : n;
    int bkt = nb >> 7;
    int cc = cursor[bkt]; if (cc > CAP) cc = CAP;
    int ce = bkt * CAP + cc;
    int blkBeg = row_start[nb];
    int blkEnd = row_start[nbEnd]; if (blkEnd > ce) blkEnd = ce;
    int beg = 0, end = 0;
    if (node < n) {
        beg = row_start[node];
        end = row_start[node + 1]; if (end > ce) end = ce;
    }
    float ax = 0.f, ay = 0.f, az = 0.f, aw = 0.f;
    for (int base = blkBeg; base < blkEnd; base += CH) {
        int m = blkEnd - base; if (m > CH) m = CH;
        __syncthreads();
        for (int i = tid; i < m; i += 256) se[i] = edges[base + i];
        __syncthreads();
        int lo = (beg > base) ? (beg - base) : 0;
        int hi = ((end < base + m) ? end : (base + m)) - base;
        for (int i = lo + es; i < hi; i += ES) {
            int2 e = se[i];
            float w = __int_as_float(e.y);
            const float4 v = *reinterpret_cast<const float4*>(hin + (size_t)e.x * in_stride + lane * 4);
            ax += w * v.x; ay += w * v.y; az += w * v.z; aw += w * v.w;
        }
    }
    #pragma unroll
    for (int msk = TPN; msk < TEAM; msk <<= 1) {
        ax += __shfl_xor(ax, msk);
        ay += __shfl_xor(ay, msk);
        az += __shfl_xor(az, msk);
        aw += __shfl_xor(aw, msk);
    }
    if (node < n && es == 0) {
        float4* po = reinterpret_cast<float4*>(hout + (size_t)node * out_stride + lane * 4);
        float4 r = make_float4(ax, ay, az, aw);
        if (ACC) { float4 o = *po; r.x += o.x; r.y += o.y; r.z += o.z; r.w += o.w; }
        *po = r;
    }
}

// ---------------- bf16 width-64 propagation (layer 2): Gout = A * Gin ----------------
// TPN=8 lanes x 8 bf16 (16B), ES=4 edge-split (TEAM=32, NPB=8). fp32 accumulate.
__global__ __launch_bounds__(256) void prop64b_kernel(const int* __restrict__ row_start,
                                                      const int* __restrict__ cursor,
                                                      const int2* __restrict__ edges,
                                                      const unsigned short* __restrict__ Gin,
                                                      unsigned short* __restrict__ Gout, int n) {
    constexpr int TPN = 8, ES = 4, TEAM = 32, NPB = 8;
    __shared__ int2 se[CH];
    int tid = threadIdx.x;
    int nb = blockIdx.x * NPB;
    int node = nb + tid / TEAM;
    int t = tid % TEAM;
    int es = t / TPN;
    int lane = t % TPN;
    int nbEnd = (nb + NPB < n) ? (nb + NPB) : n;
    int bkt = nb >> 7;
    int cc = cursor[bkt]; if (cc > CAP) cc = CAP;
    int ce = bkt * CAP + cc;
    int blkBeg = row_start[nb];
    int blkEnd = row_start[nbEnd]; if (blkEnd > ce) blkEnd = ce;
    int beg = 0, end = 0;
    if (node < n) {
        beg = row_start[node];
        end = row_start[node + 1]; if (end > ce) end = ce;
    }
    float a0 = 0.f, a1 = 0.f, a2 = 0.f, a3 = 0.f, a4 = 0.f, a5 = 0.f, a6 = 0.f, a7 = 0.f;
    for (int base = blkBeg; base < blkEnd; base += CH) {
        int m = blkEnd - base; if (m > CH) m = CH;
        __syncthreads();
        for (int i = tid; i < m; i += 256) se[i] = edges[base + i];
        __syncthreads();
        int lo = (beg > base) ? (beg - base) : 0;
        int hi = ((end < base + m) ? end : (base + m)) - base;
        for (int i = lo + es; i < hi; i += ES) {
            int2 e = se[i];
            float w = __int_as_float(e.y);
            const uint4 v = *reinterpret_cast<const uint4*>(Gin + (size_t)e.x * 256 + lane * 8);
            a0 += w * bflo(v.x); a1 += w * bfhi(v.x);
            a2 += w * bflo(v.y); a3 += w * bfhi(v.y);
            a4 += w * bflo(v.z); a5 += w * bfhi(v.z);
            a6 += w * bflo(v.w); a7 += w * bfhi(v.w);
        }
    }
    #pragma unroll
    for (int msk = TPN; msk < TEAM; msk <<= 1) {
        a0 += __shfl_xor(a0, msk); a1 += __shfl_xor(a1, msk);
        a2 += __shfl_xor(a2, msk); a3 += __shfl_xor(a3, msk);
        a4 += __shfl_xor(a4, msk); a5 += __shfl_xor(a5, msk);
        a6 += __shfl_xor(a6, msk); a7 += __shfl_xor(a7, msk);
    }
    if (node < n && es == 0) {
        uint4 o;
        o.x = packbf2(a0, a1);
        o.y = packbf2(a2, a3);
        o.z = packbf2(a4, a5);
        o.w = packbf2(a6, a7);
        *reinterpret_cast<uint4*>(Gout + (size_t)node * 256 + lane * 8) = o;
    }
}

// ---------------- final prop: out = log_softmax(g0 + A*t1 + b3) ----------------
__global__ __launch_bounds__(256) void prop_final_kernel(const int* __restrict__ row_start,
                                                         const int* __restrict__ cursor,
                                                         const int2* __restrict__ edges,
                                                         const float* __restrict__ hin,
                                                         const float* __restrict__ g0,
                                                         const float* __restrict__ b3,
                                                         float* __restrict__ out, int n) {
    constexpr int TPN = 4, ES = 2, TEAM = 8, NPB = 32;
    __shared__ int2 se[CH];
    int tid = threadIdx.x;
    int nb = blockIdx.x * NPB;
    int node = nb + tid / TEAM;
    int t = tid % TEAM;
    int es = t / TPN;
    int lane = t % TPN;
    int nbEnd = (nb + NPB < n) ? (nb + NPB) : n;
    int bkt = nb >> 7;
    int cc = cursor[bkt]; if (cc > CAP) cc = CAP;
    int ce = bkt * CAP + cc;
    int blkBeg = row_start[nb];
    int blkEnd = row_start[nbEnd]; if (blkEnd > ce) blkEnd = ce;
    int beg = 0, end = 0;
    if (node < n) {
        beg = row_start[node];
        end = row_start[node + 1]; if (end > ce) end = ce;
    }
    float ax = 0.f, ay = 0.f, az = 0.f, aw = 0.f;
    for (int base = blkBeg; base < blkEnd; base += CH) {
        int m = blkEnd - base; if (m > CH) m = CH;
        __syncthreads();
        for (int i = tid; i < m; i += 256) se[i] = edges[base + i];
        __syncthreads();
        int lo = (beg > base) ? (beg - base) : 0;
        int hi = ((end < base + m) ? end : (base + m)) - base;
        for (int i = lo + es; i < hi; i += ES) {
            int2 e = se[i];
            float w = __int_as_float(e.y);
            const float4 v = *reinterpret_cast<const float4*>(hin + (size_t)e.x * 64 + lane * 4);
            ax += w * v.x; ay += w * v.y; az += w * v.z; aw += w * v.w;
        }
    }
    ax += __shfl_xor(ax, TPN);
    ay += __shfl_xor(ay, TPN);
    az += __shfl_xor(az, TPN);
    aw += __shfl_xor(aw, TPN);
    if (node < n && es == 0) {
        const float4 g = *reinterpret_cast<const float4*>(g0 + (size_t)node * 64 + lane * 4);
        float vv[4] = {ax + g.x, ay + g.y, az + g.z, aw + g.w};
        int c0 = lane * 4;
        float mloc = -1e30f;
        #pragma unroll
        for (int c = 0; c < 4; ++c) {
            int col = c0 + c;
            if (col < NOUT) { vv[c] += b3[col]; mloc = fmaxf(mloc, vv[c]); }
        }
        float mo = fmaxf(mloc, __shfl_xor(mloc, 1));
        mo = fmaxf(mo, __shfl_xor(mo, 2));
        float sl = 0.f;
        #pragma unroll
        for (int c = 0; c < 4; ++c) {
            int col = c0 + c;
            if (col < NOUT) sl += __expf(vv[c] - mo);
        }
        sl += __shfl_xor(sl, 1);
        sl += __shfl_xor(sl, 2);
        float ls = __logf(sl);
        #pragma unroll
        for (int c = 0; c < 4; ++c) {
            int col = c0 + c;
            if (col < NOUT) out[(size_t)node * NOUT + col] = vv[c] - mo - ls;
        }
    }
}

// ---------------- register-blocked matmul: 64 nodes x 64 outs per block ----------------
// INBF16: input rows are bf16 (hstride in ushorts, requires KC==64).
// OUTBF16: output rows are bf16 (ostride in ushorts).
// EPI: 0 none, 1 bias+relu. WMODE: 0 contiguous (FIN,64); 1 W3 pad mode.
template <int FIN, int KC, int EPI, int WMODE, int INBF16, int OUTBF16>
__global__ __launch_bounds__(256) void mm2_kernel(const void* __restrict__ hraw, int hstride,
                                                  const float* __restrict__ W,
                                                  const float* __restrict__ bias,
                                                  void* __restrict__ outraw, int ostride, int n) {
    constexpr int HP = 68;
    __shared__ float HsT[KC * HP];
    __shared__ float Ws[KC * 64];
    int tid = threadIdx.x;
    int ndq = tid >> 4;
    int f4  = tid & 15;
    int nd  = tid & 63;
    int wv  = tid >> 6;
    int nodeBase = blockIdx.x * 64;

    float4 acc0 = make_float4(0.f, 0.f, 0.f, 0.f);
    float4 acc1 = make_float4(0.f, 0.f, 0.f, 0.f);
    float4 acc2 = make_float4(0.f, 0.f, 0.f, 0.f);
    float4 acc3 = make_float4(0.f, 0.f, 0.f, 0.f);

    for (int kc = 0; kc < FIN; kc += KC) {
        if (WMODE == 0) {
            for (int i = tid * 4; i < KC * 64; i += 1024)
                *reinterpret_cast<float4*>(&Ws[i]) =
                    *reinterpret_cast<const float4*>(&W[(size_t)kc * 64 + i]);
        } else {
            for (int i = tid; i < KC * 64; i += 256) {
                int r = i >> 6, c = i & 63;
                int k = c >> 4, j = c & 15;
                Ws[i] = (j < NOUT) ? W[((size_t)k * FIN + kc + r) * NOUT + j] : 0.f;
            }
        }
        int node = nodeBase + nd;
        if constexpr (INBF16) {
            // KC == 64: thread (nd, wv) stages k = wv*16 .. wv*16+15 from bf16
            const unsigned short* hb = (const unsigned short*)hraw;
            int k0 = wv * 16;
            uint4 q0 = make_uint4(0, 0, 0, 0), q1 = make_uint4(0, 0, 0, 0);
            if (node < n) {
                const unsigned short* row = hb + (size_t)node * hstride + kc + k0;
                q0 = *reinterpret_cast<const uint4*>(row);
                q1 = *reinterpret_cast<const uint4*>(row + 8);
            }
            HsT[(k0 + 0) * HP + nd] = bflo(q0.x);  HsT[(k0 + 1) * HP + nd] = bfhi(q0.x);
            HsT[(k0 + 2) * HP + nd] = bflo(q0.y);  HsT[(k0 + 3) * HP + nd] = bfhi(q0.y);
            HsT[(k0 + 4) * HP + nd] = bflo(q0.z);  HsT[(k0 + 5) * HP + nd] = bfhi(q0.z);
            HsT[(k0 + 6) * HP + nd] = bflo(q0.w);  HsT[(k0 + 7) * HP + nd] = bfhi(q0.w);
            HsT[(k0 + 8) * HP + nd] = bflo(q1.x);  HsT[(k0 + 9) * HP + nd] = bfhi(q1.x);
            HsT[(k0 + 10) * HP + nd] = bflo(q1.y); HsT[(k0 + 11) * HP + nd] = bfhi(q1.y);
            HsT[(k0 + 12) * HP + nd] = bflo(q1.z); HsT[(k0 + 13) * HP + nd] = bfhi(q1.z);
            HsT[(k0 + 14) * HP + nd] = bflo(q1.w); HsT[(k0 + 15) * HP + nd] = bfhi(q1.w);
        } else {
            const float* hf = (const float*)hraw;
            #pragma unroll
            for (int r = 0; r < KC / 16; ++r) {
                int k0 = wv * 4 + r * 16;
                float4 hv = make_float4(0.f, 0.f, 0.f, 0.f);
                if (node < n)
                    hv = *reinterpret_cast<const float4*>(&hf[(size_t)node * hstride + kc + k0]);
                HsT[(k0 + 0) * HP + nd] = hv.x;
                HsT[(k0 + 1) * HP + nd] = hv.y;
                HsT[(k0 + 2) * HP + nd] = hv.z;
                HsT[(k0 + 3) * HP + nd] = hv.w;
            }
        }
        __syncthreads();
        #pragma unroll 8
        for (int k = 0; k < KC; ++k) {
            const float4 hq = *reinterpret_cast<const float4*>(&HsT[k * HP + ndq * 4]);
            const float4 wq = *reinterpret_cast<const float4*>(&Ws[k * 64 + f4 * 4]);
            acc0.x += hq.x * wq.x; acc0.y += hq.x * wq.y; acc0.z += hq.x * wq.z; acc0.w += hq.x * wq.w;
            acc1.x += hq.y * wq.x; acc1.y += hq.y * wq.y; acc1.z += hq.y * wq.z; acc1.w += hq.y * wq.w;
            acc2.x += hq.z * wq.x; acc2.y += hq.z * wq.y; acc2.z += hq.z * wq.z; acc2.w += hq.z * wq.w;
            acc3.x += hq.w * wq.x; acc3.y += hq.w * wq.y; acc3.z += hq.w * wq.z; acc3.w += hq.w * wq.w;
        }
        __syncthreads();
    }

    float4 bv = make_float4(0.f, 0.f, 0.f, 0.f);
    if (EPI == 1) bv = *reinterpret_cast<const float4*>(&bias[f4 * 4]);
    float4 accs[4] = {acc0, acc1, acc2, acc3};
    #pragma unroll
    for (int i = 0; i < 4; ++i) {
        int node = nodeBase + ndq * 4 + i;
        if (node < n) {
            float4 a = accs[i];
            if (EPI == 1) {
                a.x = fmaxf(a.x + bv.x, 0.f); a.y = fmaxf(a.y + bv.y, 0.f);
                a.z = fmaxf(a.z + bv.z, 0.f); a.w = fmaxf(a.w + bv.w, 0.f);
            }
            if constexpr (OUTBF16) {
                unsigned short* ob = (unsigned short*)outraw;
                uint2 o;
                o.x = packbf2(a.x, a.y);
                o.y = packbf2(a.z, a.w);
                *reinterpret_cast<uint2*>(ob + (size_t)node * ostride + f4 * 4) = o;
            } else {
                float* of = (float*)outraw;
                *reinterpret_cast<float4*>(of + (size_t)node * ostride + f4 * 4) = a;
            }
        }
    }
}

extern "C" void kernel_launch(void* const* d_in, const int* in_sizes, int n_in,
                              void* d_out, int out_size, void* d_ws, size_t ws_size,
                              hipStream_t stream) {
    const float* x   = (const float*)d_in[0];
    const float* pos = (const float*)d_in[1];
    const float* ea  = (const float*)d_in[2];
    const float* W1  = (const float*)d_in[3];   // (4,8,64) == (32,64)
    const float* b1  = (const float*)d_in[4];
    const float* W2  = (const float*)d_in[5];   // (4,64,64) == (256,64)
    const float* b2  = (const float*)d_in[6];
    const float* W3  = (const float*)d_in[7];   // (4,64,10)
    const float* b3  = (const float*)d_in[8];
    const int* eidx  = (const int*)d_in[9];
    const int* src = eidx;
    const int* dst = eidx + EE;
    float* outp = (float*)d_out;

    size_t off = 0;
    char* base = (char*)d_ws;
    auto alloc = [&](size_t bytes) -> void* {
        void* p = base + off;
        off += (bytes + 255) & ~(size_t)255;
        return p;
    };
    int*   cursor    = (int*)alloc(NB * 4);
    int*   row_start = (int*)alloc((NN + 1) * 4);
    float* dinv      = (float*)alloc(NN * 4);
    int2*  edges     = (int2*)alloc((size_t)NB * CAP * 8);       // strided bucket regions
    unsigned short* G = (unsigned short*)alloc((size_t)NN * 256 * 2);  // bf16 [h1|Ah1|A2h1|A3h1]
    float* P1        = (float*)alloc((size_t)NN * 32 * 4);       // layer-1 P (N x 32)
    float* h2        = (float*)alloc((size_t)NN * 64 * 4);       // relu(P2@W2+b2)
    float* T         = (float*)alloc((size_t)NN * 64 * 4);       // layer-3 Horner buffer
    (void)ws_size;

    const int B = 256;
    const int gN = (NN + B - 1) / B;
    const int gK1 = (EE + K1_EPB - 1) / K1_EPB;      // 196
    const int gK3 = (NB * CAP + B - 1) / B;          // 3666
    const int gMM2 = (NN + 63) / 64;                 // 782
    const int gP32 = (NN + 31) / 32;                 // 1563 (TEAM=8,  NPB=32)
    const int gP8  = (NN + 7) / 8;                   // 6250 (TEAM=32, NPB=8)

    hipMemsetAsync(cursor, 0, NB * 4, stream);

    // ---- CSR build (bucketed, atomic-light) ----
    bucket_scatter_kernel<<<gK1, B, 0, stream>>>(src, dst, ea, cursor, edges, EE);
    bucket_build_kernel<<<NB, B, 0, stream>>>(cursor, edges, dinv, row_start, NN);
    srcscale_kernel<<<gK3, B, 0, stream>>>(cursor, dinv, edges);

    // ---- layer 1: P1 = [h0, Ah0, A2h0, A3h0] (N x 32 fp32); h1 = relu(P1@W1+b1) -> G chunk0 (bf16) ----
    concat_kernel<<<gN, B, 0, stream>>>(x, pos, P1, NN);
    prop_kernel<2, 4, false><<<gP32, B, 0, stream>>>(row_start, cursor, edges, P1,      32, P1 + 8,  32, NN);
    prop_kernel<2, 4, false><<<gP32, B, 0, stream>>>(row_start, cursor, edges, P1 + 8,  32, P1 + 16, 32, NN);
    prop_kernel<2, 4, false><<<gP32, B, 0, stream>>>(row_start, cursor, edges, P1 + 16, 32, P1 + 24, 32, NN);
    mm2_kernel<32, 32, 1, 0, 0, 1><<<gMM2, B, 0, stream>>>(P1, 32, W1, b1, G, 256, NN);

    // ---- layer 2: G chunks 1..3 = A^k h1 (bf16 gathers); h2 = relu(G@W2+b2) fp32 ----
    prop64b_kernel<<<gP8, B, 0, stream>>>(row_start, cursor, edges, G,       G + 64,  NN);
    prop64b_kernel<<<gP8, B, 0, stream>>>(row_start, cursor, edges, G + 64,  G + 128, NN);
    prop64b_kernel<<<gP8, B, 0, stream>>>(row_start, cursor, edges, G + 128, G + 192, NN);
    mm2_kernel<256, 64, 1, 0, 1, 0><<<gMM2, B, 0, stream>>>(G, 256, W2, b2, h2, 64, NN);

    // ---- layer 3 (Horner, fp32): T[n, k*16+j] = (h2 @ W3[k])[n,j] (j<10 padded to 16) ----
    mm2_kernel<64, 64, 0, 1, 0, 0><<<gMM2, B, 0, stream>>>(h2, 64, W3, nullptr, T, 64, NN);
    prop_kernel<4, 2, true><<<gP32, B, 0, stream>>>(row_start, cursor, edges, T + 48, 64, T + 32, 64, NN);
    prop_kernel<4, 2, true><<<gP32, B, 0, stream>>>(row_start, cursor, edges, T + 32, 64, T + 16, 64, NN);
    prop_final_kernel<<<gP32, B, 0, stream>>>(row_start, cursor, edges, T + 16, T, b3, outp, NN);
}

// Round 7
// 300.259 us; speedup vs baseline: 2.3295x; 1.0668x over previous
//
#include <hip/hip_runtime.h>
#include <math.h>

// TAGConv GNN: N=50000, E=800000, K=3, layers (8->64, 64->64, 64->10)
// v7: CSR build at 512 thr/block (latency hiding); layer-1 chain in bf16
// (1-load 16B row gathers, TPN=1 x ES=8 teams, concat folded into bf16 pack);
// fused mm2+mm3 (h2 stays in registers/LDS, no global round-trip).
// From v6: bf16 layer-2 G table + prop64b; bucketed CSR; Horner layer 3 fp32.

#define NN 50000
#define EE 800000
#define HID 64
#define NOUT 10
#define CH 512

#define NB 391        // ceil(50000/128) buckets of 128 nodes
#define CAP 2400      // region capacity (mean 2047, +7.8 sigma)
#define K1_EPB 4096   // edges per K1 block

// ---------------- bf16 helpers ----------------
__device__ __forceinline__ unsigned bf16rnd(float x) {
    unsigned u = __float_as_uint(x);
    return (u + 0x7FFFu + ((u >> 16) & 1u)) >> 16;
}
__device__ __forceinline__ unsigned packbf2(float a, float b) {
    return bf16rnd(a) | (bf16rnd(b) << 16);
}
__device__ __forceinline__ float bflo(unsigned u) { return __uint_as_float(u << 16); }
__device__ __forceinline__ float bfhi(unsigned u) { return __uint_as_float(u & 0xFFFF0000u); }

// ---------------- K1: coarse bucket scatter (512 thr) ----------------
__global__ __launch_bounds__(512) void bucket_scatter_kernel(
        const int* __restrict__ src, const int* __restrict__ dst,
        const float* __restrict__ ea, int* __restrict__ cursor,
        int2* __restrict__ regions, int e) {
    __shared__ int hist[NB];
    __shared__ int base[NB];
    int tid = threadIdx.x;
    int e0 = blockIdx.x * K1_EPB;
    int e1 = e0 + K1_EPB; if (e1 > e) e1 = e;
    for (int i = tid; i < NB; i += 512) hist[i] = 0;
    __syncthreads();
    for (int i = e0 + tid; i < e1; i += 512)
        atomicAdd(&hist[dst[i] >> 7], 1);
    __syncthreads();
    for (int b = tid; b < NB; b += 512) {
        int c = hist[b];
        base[b] = (c > 0) ? atomicAdd(&cursor[b], c) : 0;
        hist[b] = 0;   // reuse as local cursor
    }
    __syncthreads();
    for (int i = e0 + tid; i < e1; i += 512) {
        int d = dst[i];
        int b = d >> 7;
        int r = atomicAdd(&hist[b], 1);
        int pos = base[b] + r;
        if (pos < CAP)
            regions[(size_t)b * CAP + pos] =
                make_int2(((d & 127) << 16) | src[i], __float_as_int(ea[i]));
    }
}

// ---------------- K2: per-bucket fine sort + row_start + dinv + w0 (512 thr) ----------------
__global__ __launch_bounds__(512) void bucket_build_kernel(
        const int* __restrict__ cursor, int2* __restrict__ regions,
        float* __restrict__ dinv, int* __restrict__ row_start, int n) {
    __shared__ int2 rec[CAP];
    __shared__ int hist[128];
    __shared__ float easum[128];
    __shared__ float dl[128];
    __shared__ int off[129];
    __shared__ int lcur[128];
    int b = blockIdx.x;
    int tid = threadIdx.x;
    int cnt = cursor[b]; if (cnt > CAP) cnt = CAP;
    size_t rb = (size_t)b * CAP;
    if (tid < 128) { hist[tid] = 0; easum[tid] = 0.f; lcur[tid] = 0; }
    __syncthreads();
    for (int i = tid; i < cnt; i += 512) {
        int2 r = regions[rb + i];
        rec[i] = r;
        int f = r.x >> 16;
        atomicAdd(&hist[f], 1);
        atomicAdd(&easum[f], __int_as_float(r.y));
    }
    __syncthreads();
    if (tid < 128) {
        int lane = tid & 63;
        int v = hist[tid];
        for (int o2 = 1; o2 < 64; o2 <<= 1) {
            int y = __shfl_up(v, o2, 64);
            if (lane >= o2) v += y;
        }
        off[tid + 1] = v;     // wave-local inclusive
        float s2 = easum[tid];
        dl[tid] = (s2 > 0.f) ? rsqrtf(s2) : 0.f;
    }
    __syncthreads();
    if (tid == 255) off[0] = 0;
    if (tid >= 64 && tid < 128) off[tid + 1] += off[64];
    __syncthreads();
    if (tid < 128) {
        int node = b * 128 + tid;
        if (node <= n) row_start[node] = b * CAP + off[tid];
        if (node < n)  dinv[node] = dl[tid];
    }
    __syncthreads();
    for (int i = tid; i < cnt; i += 512) {
        int2 r = rec[i];
        int f = r.x >> 16;
        int s = r.x & 0xFFFF;
        int p = atomicAdd(&lcur[f], 1);
        float w0 = __int_as_float(r.y) * dl[f];
        regions[rb + off[f] + p] = make_int2(s, __float_as_int(w0));
    }
}

// ---------------- K3: w *= dinv[src] ----------------
__global__ __launch_bounds__(256) void srcscale_kernel(
        const int* __restrict__ cursor, const float* __restrict__ dinv,
        int2* __restrict__ regions) {
    int i = blockIdx.x * blockDim.x + threadIdx.x;
    int b = i / CAP;
    if (b >= NB) return;
    int off = i - b * CAP;
    int cnt = cursor[b]; if (cnt > CAP) cnt = CAP;
    if (off >= cnt) return;
    int2 r = regions[i];
    r.y = __float_as_int(__int_as_float(r.y) * dinv[r.x]);
    regions[i] = r;
}

// ---------------- pack x,pos -> B1 chunk0 (bf16, stride 32 ushorts) ----------------
__global__ __launch_bounds__(256) void pack1_kernel(const float* __restrict__ x,
                                                    const float* __restrict__ pos,
                                                    unsigned short* __restrict__ B1, int n) {
    int i = blockIdx.x * blockDim.x + threadIdx.x;
    if (i >= n) return;
    float2 a = *reinterpret_cast<const float2*>(x + (size_t)i * 6);
    float2 b = *reinterpret_cast<const float2*>(x + (size_t)i * 6 + 2);
    float2 c = *reinterpret_cast<const float2*>(x + (size_t)i * 6 + 4);
    float2 p = *reinterpret_cast<const float2*>(pos + (size_t)i * 2);
    uint4 o;
    o.x = packbf2(a.x, a.y);
    o.y = packbf2(b.x, b.y);
    o.z = packbf2(c.x, c.y);
    o.w = packbf2(p.x, p.y);
    *reinterpret_cast<uint4*>(B1 + (size_t)i * 32) = o;
}

// ---------------- bf16 width-8 propagation (layer 1): 1 load/edge ----------------
// TPN=1 (one 16B row load), ES=8 edge-split, TEAM=8, NPB=32.
__global__ __launch_bounds__(256) void prop8b_kernel(const int* __restrict__ row_start,
                                                     const int* __restrict__ cursor,
                                                     const int2* __restrict__ edges,
                                                     const unsigned short* __restrict__ Gin,
                                                     unsigned short* __restrict__ Gout, int n) {
    constexpr int TEAM = 8, NPB = 32;
    __shared__ int2 se[CH];
    int tid = threadIdx.x;
    int nb = blockIdx.x * NPB;
    int node = nb + tid / TEAM;
    int es = tid % TEAM;
    int nbEnd = (nb + NPB < n) ? (nb + NPB) : n;
    int bkt = nb >> 7;
    int cc = cursor[bkt]; if (cc > CAP) cc = CAP;
    int ce = bkt * CAP + cc;
    int blkBeg = row_start[nb];
    int blkEnd = row_start[nbEnd]; if (blkEnd > ce) blkEnd = ce;
    int beg = 0, end = 0;
    if (node < n) {
        beg = row_start[node];
        end = row_start[node + 1]; if (end > ce) end = ce;
    }
    float a0 = 0.f, a1 = 0.f, a2 = 0.f, a3 = 0.f, a4 = 0.f, a5 = 0.f, a6 = 0.f, a7 = 0.f;
    for (int base = blkBeg; base < blkEnd; base += CH) {
        int m = blkEnd - base; if (m > CH) m = CH;
        __syncthreads();
        for (int i = tid; i < m; i += 256) se[i] = edges[base + i];
        __syncthreads();
        int lo = (beg > base) ? (beg - base) : 0;
        int hi = ((end < base + m) ? end : (base + m)) - base;
        for (int i = lo + es; i < hi; i += TEAM) {
            int2 e = se[i];
            float w = __int_as_float(e.y);
            const uint4 v = *reinterpret_cast<const uint4*>(Gin + (size_t)e.x * 32);
            a0 += w * bflo(v.x); a1 += w * bfhi(v.x);
            a2 += w * bflo(v.y); a3 += w * bfhi(v.y);
            a4 += w * bflo(v.z); a5 += w * bfhi(v.z);
            a6 += w * bflo(v.w); a7 += w * bfhi(v.w);
        }
    }
    #pragma unroll
    for (int msk = 1; msk < TEAM; msk <<= 1) {
        a0 += __shfl_xor(a0, msk); a1 += __shfl_xor(a1, msk);
        a2 += __shfl_xor(a2, msk); a3 += __shfl_xor(a3, msk);
        a4 += __shfl_xor(a4, msk); a5 += __shfl_xor(a5, msk);
        a6 += __shfl_xor(a6, msk); a7 += __shfl_xor(a7, msk);
    }
    if (node < n && es == 0) {
        uint4 o;
        o.x = packbf2(a0, a1);
        o.y = packbf2(a2, a3);
        o.z = packbf2(a4, a5);
        o.w = packbf2(a6, a7);
        *reinterpret_cast<uint4*>(Gout + (size_t)node * 32) = o;
    }
}

// ---------------- fp32 propagation (layer 3) ----------------
template <int TPN, int ES, bool ACC>
__global__ __launch_bounds__(256) void prop_kernel(const int* __restrict__ row_start,
                                                   const int* __restrict__ cursor,
                                                   const int2* __restrict__ edges,
                                                   const float* __restrict__ hin, int in_stride,
                                                   float* __restrict__ hout, int out_stride, int n) {
    constexpr int TEAM = TPN * ES;
    constexpr int NPB = 256 / TEAM;
    __shared__ int2 se[CH];
    int tid = threadIdx.x;
    int nb = blockIdx.x * NPB;
    int node = nb + tid / TEAM;
    int t = tid % TEAM;
    int es = t / TPN;
    int lane = t % TPN;
    int nbEnd = (nb + NPB < n) ? (nb + NPB) : n;
    int bkt = nb >> 7;
    int cc = cursor[bkt]; if (cc > CAP) cc = CAP;
    int ce = bkt * CAP + cc;
    int blkBeg = row_start[nb];
    int blkEnd = row_start[nbEnd]; if (blkEnd > ce) blkEnd = ce;
    int beg = 0, end = 0;
    if (node < n) {
        beg = row_start[node];
        end = row_start[node + 1]; if (end > ce) end = ce;
    }
    float ax = 0.f, ay = 0.f, az = 0.f, aw = 0.f;
    for (int base = blkBeg; base < blkEnd; base += CH) {
        int m = blkEnd - base; if (m > CH) m = CH;
        __syncthreads();
        for (int i = tid; i < m; i += 256) se[i] = edges[base + i];
        __syncthreads();
        int lo = (beg > base) ? (beg - base) : 0;
        int hi = ((end < base + m) ? end : (base + m)) - base;
        for (int i = lo + es; i < hi; i += ES) {
            int2 e = se[i];
            float w = __int_as_float(e.y);
            const float4 v = *reinterpret_cast<const float4*>(hin + (size_t)e.x * in_stride + lane * 4);
            ax += w * v.x; ay += w * v.y; az += w * v.z; aw += w * v.w;
        }
    }
    #pragma unroll
    for (int msk = TPN; msk < TEAM; msk <<= 1) {
        ax += __shfl_xor(ax, msk);
        ay += __shfl_xor(ay, msk);
        az += __shfl_xor(az, msk);
        aw += __shfl_xor(aw, msk);
    }
    if (node < n && es == 0) {
        float4* po = reinterpret_cast<float4*>(hout + (size_t)node * out_stride + lane * 4);
        float4 r = make_float4(ax, ay, az, aw);
        if (ACC) { float4 o = *po; r.x += o.x; r.y += o.y; r.z += o.z; r.w += o.w; }
        *po = r;
    }
}

// ---------------- bf16 width-64 propagation (layer 2): Gout = A * Gin ----------------
__global__ __launch_bounds__(256) void prop64b_kernel(const int* __restrict__ row_start,
                                                      const int* __restrict__ cursor,
                                                      const int2* __restrict__ edges,
                                                      const unsigned short* __restrict__ Gin,
                                                      unsigned short* __restrict__ Gout, int n) {
    constexpr int TPN = 8, ES = 4, TEAM = 32, NPB = 8;
    __shared__ int2 se[CH];
    int tid = threadIdx.x;
    int nb = blockIdx.x * NPB;
    int node = nb + tid / TEAM;
    int t = tid % TEAM;
    int es = t / TPN;
    int lane = t % TPN;
    int nbEnd = (nb + NPB < n) ? (nb + NPB) : n;
    int bkt = nb >> 7;
    int cc = cursor[bkt]; if (cc > CAP) cc = CAP;
    int ce = bkt * CAP + cc;
    int blkBeg = row_start[nb];
    int blkEnd = row_start[nbEnd]; if (blkEnd > ce) blkEnd = ce;
    int beg = 0, end = 0;
    if (node < n) {
        beg = row_start[node];
        end = row_start[node + 1]; if (end > ce) end = ce;
    }
    float a0 = 0.f, a1 = 0.f, a2 = 0.f, a3 = 0.f, a4 = 0.f, a5 = 0.f, a6 = 0.f, a7 = 0.f;
    for (int base = blkBeg; base < blkEnd; base += CH) {
        int m = blkEnd - base; if (m > CH) m = CH;
        __syncthreads();
        for (int i = tid; i < m; i += 256) se[i] = edges[base + i];
        __syncthreads();
        int lo = (beg > base) ? (beg - base) : 0;
        int hi = ((end < base + m) ? end : (base + m)) - base;
        for (int i = lo + es; i < hi; i += ES) {
            int2 e = se[i];
            float w = __int_as_float(e.y);
            const uint4 v = *reinterpret_cast<const uint4*>(Gin + (size_t)e.x * 256 + lane * 8);
            a0 += w * bflo(v.x); a1 += w * bfhi(v.x);
            a2 += w * bflo(v.y); a3 += w * bfhi(v.y);
            a4 += w * bflo(v.z); a5 += w * bfhi(v.z);
            a6 += w * bflo(v.w); a7 += w * bfhi(v.w);
        }
    }
    #pragma unroll
    for (int msk = TPN; msk < TEAM; msk <<= 1) {
        a0 += __shfl_xor(a0, msk); a1 += __shfl_xor(a1, msk);
        a2 += __shfl_xor(a2, msk); a3 += __shfl_xor(a3, msk);
        a4 += __shfl_xor(a4, msk); a5 += __shfl_xor(a5, msk);
        a6 += __shfl_xor(a6, msk); a7 += __shfl_xor(a7, msk);
    }
    if (node < n && es == 0) {
        uint4 o;
        o.x = packbf2(a0, a1);
        o.y = packbf2(a2, a3);
        o.z = packbf2(a4, a5);
        o.w = packbf2(a6, a7);
        *reinterpret_cast<uint4*>(Gout + (size_t)node * 256 + lane * 8) = o;
    }
}

// ---------------- final prop: out = log_softmax(g0 + A*t1 + b3) ----------------
__global__ __launch_bounds__(256) void prop_final_kernel(const int* __restrict__ row_start,
                                                         const int* __restrict__ cursor,
                                                         const int2* __restrict__ edges,
                                                         const float* __restrict__ hin,
                                                         const float* __restrict__ g0,
                                                         const float* __restrict__ b3,
                                                         float* __restrict__ out, int n) {
    constexpr int TPN = 4, ES = 2, TEAM = 8, NPB = 32;
    __shared__ int2 se[CH];
    int tid = threadIdx.x;
    int nb = blockIdx.x * NPB;
    int node = nb + tid / TEAM;
    int t = tid % TEAM;
    int es = t / TPN;
    int lane = t % TPN;
    int nbEnd = (nb + NPB < n) ? (nb + NPB) : n;
    int bkt = nb >> 7;
    int cc = cursor[bkt]; if (cc > CAP) cc = CAP;
    int ce = bkt * CAP + cc;
    int blkBeg = row_start[nb];
    int blkEnd = row_start[nbEnd]; if (blkEnd > ce) blkEnd = ce;
    int beg = 0, end = 0;
    if (node < n) {
        beg = row_start[node];
        end = row_start[node + 1]; if (end > ce) end = ce;
    }
    float ax = 0.f, ay = 0.f, az = 0.f, aw = 0.f;
    for (int base = blkBeg; base < blkEnd; base += CH) {
        int m = blkEnd - base; if (m > CH) m = CH;
        __syncthreads();
        for (int i = tid; i < m; i += 256) se[i] = edges[base + i];
        __syncthreads();
        int lo = (beg > base) ? (beg - base) : 0;
        int hi = ((end < base + m) ? end : (base + m)) - base;
        for (int i = lo + es; i < hi; i += ES) {
            int2 e = se[i];
            float w = __int_as_float(e.y);
            const float4 v = *reinterpret_cast<const float4*>(hin + (size_t)e.x * 64 + lane * 4);
            ax += w * v.x; ay += w * v.y; az += w * v.z; aw += w * v.w;
        }
    }
    ax += __shfl_xor(ax, TPN);
    ay += __shfl_xor(ay, TPN);
    az += __shfl_xor(az, TPN);
    aw += __shfl_xor(aw, TPN);
    if (node < n && es == 0) {
        const float4 g = *reinterpret_cast<const float4*>(g0 + (size_t)node * 64 + lane * 4);
        float vv[4] = {ax + g.x, ay + g.y, az + g.z, aw + g.w};
        int c0 = lane * 4;
        float mloc = -1e30f;
        #pragma unroll
        for (int c = 0; c < 4; ++c) {
            int col = c0 + c;
            if (col < NOUT) { vv[c] += b3[col]; mloc = fmaxf(mloc, vv[c]); }
        }
        float mo = fmaxf(mloc, __shfl_xor(mloc, 1));
        mo = fmaxf(mo, __shfl_xor(mo, 2));
        float sl = 0.f;
        #pragma unroll
        for (int c = 0; c < 4; ++c) {
            int col = c0 + c;
            if (col < NOUT) sl += __expf(vv[c] - mo);
        }
        sl += __shfl_xor(sl, 1);
        sl += __shfl_xor(sl, 2);
        float ls = __logf(sl);
        #pragma unroll
        for (int c = 0; c < 4; ++c) {
            int col = c0 + c;
            if (col < NOUT) out[(size_t)node * NOUT + col] = vv[c] - mo - ls;
        }
    }
}

// ---------------- register-blocked matmul: 64 nodes x 64 outs per block ----------------
// INBF16 staging supports KC=32/64 (KC/4 ks per thread, uint4 loads).
template <int FIN, int KC, int EPI, int WMODE, int INBF16, int OUTBF16>
__global__ __launch_bounds__(256) void mm2_kernel(const void* __restrict__ hraw, int hstride,
                                                  const float* __restrict__ W,
                                                  const float* __restrict__ bias,
                                                  void* __restrict__ outraw, int ostride, int n) {
    constexpr int HP = 68;
    __shared__ float HsT[KC * HP];
    __shared__ float Ws[KC * 64];
    int tid = threadIdx.x;
    int ndq = tid >> 4;
    int f4  = tid & 15;
    int nd  = tid & 63;
    int wv  = tid >> 6;
    int nodeBase = blockIdx.x * 64;

    float4 acc0 = make_float4(0.f, 0.f, 0.f, 0.f);
    float4 acc1 = make_float4(0.f, 0.f, 0.f, 0.f);
    float4 acc2 = make_float4(0.f, 0.f, 0.f, 0.f);
    float4 acc3 = make_float4(0.f, 0.f, 0.f, 0.f);

    for (int kc = 0; kc < FIN; kc += KC) {
        if (WMODE == 0) {
            for (int i = tid * 4; i < KC * 64; i += 1024)
                *reinterpret_cast<float4*>(&Ws[i]) =
                    *reinterpret_cast<const float4*>(&W[(size_t)kc * 64 + i]);
        } else {
            for (int i = tid; i < KC * 64; i += 256) {
                int r = i >> 6, c = i & 63;
                int k = c >> 4, j = c & 15;
                Ws[i] = (j < NOUT) ? W[((size_t)k * FIN + kc + r) * NOUT + j] : 0.f;
            }
        }
        int node = nodeBase + nd;
        if constexpr (INBF16) {
            const unsigned short* hb = (const unsigned short*)hraw;
            constexpr int KPT = KC / 4;
            int k0 = wv * KPT;
            #pragma unroll
            for (int q = 0; q < KPT / 8; ++q) {
                uint4 v = make_uint4(0, 0, 0, 0);
                if (node < n)
                    v = *reinterpret_cast<const uint4*>(hb + (size_t)node * hstride + kc + k0 + q * 8);
                int kk = k0 + q * 8;
                HsT[(kk + 0) * HP + nd] = bflo(v.x); HsT[(kk + 1) * HP + nd] = bfhi(v.x);
                HsT[(kk + 2) * HP + nd] = bflo(v.y); HsT[(kk + 3) * HP + nd] = bfhi(v.y);
                HsT[(kk + 4) * HP + nd] = bflo(v.z); HsT[(kk + 5) * HP + nd] = bfhi(v.z);
                HsT[(kk + 6) * HP + nd] = bflo(v.w); HsT[(kk + 7) * HP + nd] = bfhi(v.w);
            }
        } else {
            const float* hf = (const float*)hraw;
            #pragma unroll
            for (int r = 0; r < KC / 16; ++r) {
                int k0 = wv * 4 + r * 16;
                float4 hv = make_float4(0.f, 0.f, 0.f, 0.f);
                if (node < n)
                    hv = *reinterpret_cast<const float4*>(&hf[(size_t)node * hstride + kc + k0]);
                HsT[(k0 + 0) * HP + nd] = hv.x;
                HsT[(k0 + 1) * HP + nd] = hv.y;
                HsT[(k0 + 2) * HP + nd] = hv.z;
                HsT[(k0 + 3) * HP + nd] = hv.w;
            }
        }
        __syncthreads();
        #pragma unroll 8
        for (int k = 0; k < KC; ++k) {
            const float4 hq = *reinterpret_cast<const float4*>(&HsT[k * HP + ndq * 4]);
            const float4 wq = *reinterpret_cast<const float4*>(&Ws[k * 64 + f4 * 4]);
            acc0.x += hq.x * wq.x; acc0.y += hq.x * wq.y; acc0.z += hq.x * wq.z; acc0.w += hq.x * wq.w;
            acc1.x += hq.y * wq.x; acc1.y += hq.y * wq.y; acc1.z += hq.y * wq.z; acc1.w += hq.y * wq.w;
            acc2.x += hq.z * wq.x; acc2.y += hq.z * wq.y; acc2.z += hq.z * wq.z; acc2.w += hq.z * wq.w;
            acc3.x += hq.w * wq.x; acc3.y += hq.w * wq.y; acc3.z += hq.w * wq.z; acc3.w += hq.w * wq.w;
        }
        __syncthreads();
    }

    float4 bv = make_float4(0.f, 0.f, 0.f, 0.f);
    if (EPI == 1) bv = *reinterpret_cast<const float4*>(&bias[f4 * 4]);
    float4 accs[4] = {acc0, acc1, acc2, acc3};
    #pragma unroll
    for (int i = 0; i < 4; ++i) {
        int node = nodeBase + ndq * 4 + i;
        if (node < n) {
            float4 a = accs[i];
            if (EPI == 1) {
                a.x = fmaxf(a.x + bv.x, 0.f); a.y = fmaxf(a.y + bv.y, 0.f);
                a.z = fmaxf(a.z + bv.z, 0.f); a.w = fmaxf(a.w + bv.w, 0.f);
            }
            if constexpr (OUTBF16) {
                unsigned short* ob = (unsigned short*)outraw;
                uint2 o;
                o.x = packbf2(a.x, a.y);
                o.y = packbf2(a.z, a.w);
                *reinterpret_cast<uint2*>(ob + (size_t)node * ostride + f4 * 4) = o;
            } else {
                float* of = (float*)outraw;
                *reinterpret_cast<float4*>(of + (size_t)node * ostride + f4 * 4) = a;
            }
        }
    }
}

// ---------------- fused mm2+mm3: h2 = relu(G@W2+b2) (regs) ; T = h2 @ W3pad ----------------
__global__ __launch_bounds__(256) void mm23_kernel(const unsigned short* __restrict__ G,
                                                   const float* __restrict__ W2,
                                                   const float* __restrict__ b2,
                                                   const float* __restrict__ W3,
                                                   float* __restrict__ T, int n) {
    constexpr int HP = 68;
    __shared__ float HsT[64 * HP];
    __shared__ float Ws[64 * 64];
    int tid = threadIdx.x;
    int ndq = tid >> 4;
    int f4  = tid & 15;
    int nd  = tid & 63;
    int wv  = tid >> 6;
    int nodeBase = blockIdx.x * 64;

    float4 acc0 = make_float4(0.f, 0.f, 0.f, 0.f);
    float4 acc1 = make_float4(0.f, 0.f, 0.f, 0.f);
    float4 acc2 = make_float4(0.f, 0.f, 0.f, 0.f);
    float4 acc3 = make_float4(0.f, 0.f, 0.f, 0.f);

    // ---- phase 1: h2 = relu(G @ W2 + b2), G is N x 256 bf16 ----
    for (int kc = 0; kc < 256; kc += 64) {
        for (int i = tid * 4; i < 64 * 64; i += 1024)
            *reinterpret_cast<float4*>(&Ws[i]) =
                *reinterpret_cast<const float4*>(&W2[(size_t)kc * 64 + i]);
        int node = nodeBase + nd;
        int k0 = wv * 16;
        uint4 q0 = make_uint4(0, 0, 0, 0), q1 = make_uint4(0, 0, 0, 0);
        if (node < n) {
            const unsigned short* row = G + (size_t)node * 256 + kc + k0;
            q0 = *reinterpret_cast<const uint4*>(row);
            q1 = *reinterpret_cast<const uint4*>(row + 8);
        }
        HsT[(k0 + 0) * HP + nd] = bflo(q0.x);  HsT[(k0 + 1) * HP + nd] = bfhi(q0.x);
        HsT[(k0 + 2) * HP + nd] = bflo(q0.y);  HsT[(k0 + 3) * HP + nd] = bfhi(q0.y);
        HsT[(k0 + 4) * HP + nd] = bflo(q0.z);  HsT[(k0 + 5) * HP + nd] = bfhi(q0.z);
        HsT[(k0 + 6) * HP + nd] = bflo(q0.w);  HsT[(k0 + 7) * HP + nd] = bfhi(q0.w);
        HsT[(k0 + 8) * HP + nd] = bflo(q1.x);  HsT[(k0 + 9) * HP + nd] = bfhi(q1.x);
        HsT[(k0 + 10) * HP + nd] = bflo(q1.y); HsT[(k0 + 11) * HP + nd] = bfhi(q1.y);
        HsT[(k0 + 12) * HP + nd] = bflo(q1.z); HsT[(k0 + 13) * HP + nd] = bfhi(q1.z);
        HsT[(k0 + 14) * HP + nd] = bflo(q1.w); HsT[(k0 + 15) * HP + nd] = bfhi(q1.w);
        __syncthreads();
        #pragma unroll 8
        for (int k = 0; k < 64; ++k) {
            const float4 hq = *reinterpret_cast<const float4*>(&HsT[k * HP + ndq * 4]);
            const float4 wq = *reinterpret_cast<const float4*>(&Ws[k * 64 + f4 * 4]);
            acc0.x += hq.x * wq.x; acc0.y += hq.x * wq.y; acc0.z += hq.x * wq.z; acc0.w += hq.x * wq.w;
            acc1.x += hq.y * wq.x; acc1.y += hq.y * wq.y; acc1.z += hq.y * wq.z; acc1.w += hq.y * wq.w;
            acc2.x += hq.z * wq.x; acc2.y += hq.z * wq.y; acc2.z += hq.z * wq.z; acc2.w += hq.z * wq.w;
            acc3.x += hq.w * wq.x; acc3.y += hq.w * wq.y; acc3.z += hq.w * wq.z; acc3.w += hq.w * wq.w;
        }
        __syncthreads();
    }

    // ---- transpose h2 tile into HsT (k-major) with bias+relu ----
    {
        const float4 bv = *reinterpret_cast<const float4*>(&b2[f4 * 4]);
        float4 accs[4] = {acc0, acc1, acc2, acc3};
        #pragma unroll
        for (int i = 0; i < 4; ++i) {
            float4 a = accs[i];
            a.x = fmaxf(a.x + bv.x, 0.f); a.y = fmaxf(a.y + bv.y, 0.f);
            a.z = fmaxf(a.z + bv.z, 0.f); a.w = fmaxf(a.w + bv.w, 0.f);
            int col = ndq * 4 + i;   // node index within tile
            HsT[(f4 * 4 + 0) * HP + col] = a.x;
            HsT[(f4 * 4 + 1) * HP + col] = a.y;
            HsT[(f4 * 4 + 2) * HP + col] = a.z;
            HsT[(f4 * 4 + 3) * HP + col] = a.w;
        }
    }
    __syncthreads();
    // ---- stage padded W3 (4,64,10) -> 64x64 ----
    for (int i = tid; i < 64 * 64; i += 256) {
        int r = i >> 6, c = i & 63;
        int k = c >> 4, j = c & 15;
        Ws[i] = (j < NOUT) ? W3[((size_t)k * 64 + r) * NOUT + j] : 0.f;
    }
    __syncthreads();
    // ---- phase 2: T = h2 @ W3pad ----
    float4 t0 = make_float4(0.f, 0.f, 0.f, 0.f);
    float4 t1 = make_float4(0.f, 0.f, 0.f, 0.f);
    float4 t2 = make_float4(0.f, 0.f, 0.f, 0.f);
    float4 t3 = make_float4(0.f, 0.f, 0.f, 0.f);
    #pragma unroll 8
    for (int k = 0; k < 64; ++k) {
        const float4 hq = *reinterpret_cast<const float4*>(&HsT[k * HP + ndq * 4]);
        const float4 wq = *reinterpret_cast<const float4*>(&Ws[k * 64 + f4 * 4]);
        t0.x += hq.x * wq.x; t0.y += hq.x * wq.y; t0.z += hq.x * wq.z; t0.w += hq.x * wq.w;
        t1.x += hq.y * wq.x; t1.y += hq.y * wq.y; t1.z += hq.y * wq.z; t1.w += hq.y * wq.w;
        t2.x += hq.z * wq.x; t2.y += hq.z * wq.y; t2.z += hq.z * wq.z; t2.w += hq.z * wq.w;
        t3.x += hq.w * wq.x; t3.y += hq.w * wq.y; t3.z += hq.w * wq.z; t3.w += hq.w * wq.w;
    }
    float4 ts[4] = {t0, t1, t2, t3};
    #pragma unroll
    for (int i = 0; i < 4; ++i) {
        int node = nodeBase + ndq * 4 + i;
        if (node < n)
            *reinterpret_cast<float4*>(T + (size_t)node * 64 + f4 * 4) = ts[i];
    }
}

extern "C" void kernel_launch(void* const* d_in, const int* in_sizes, int n_in,
                              void* d_out, int out_size, void* d_ws, size_t ws_size,
                              hipStream_t stream) {
    const float* x   = (const float*)d_in[0];
    const float* pos = (const float*)d_in[1];
    const float* ea  = (const float*)d_in[2];
    const float* W1  = (const float*)d_in[3];   // (4,8,64) == (32,64)
    const float* b1  = (const float*)d_in[4];
    const float* W2  = (const float*)d_in[5];   // (4,64,64) == (256,64)
    const float* b2  = (const float*)d_in[6];
    const float* W3  = (const float*)d_in[7];   // (4,64,10)
    const float* b3  = (const float*)d_in[8];
    const int* eidx  = (const int*)d_in[9];
    const int* src = eidx;
    const int* dst = eidx + EE;
    float* outp = (float*)d_out;

    size_t off = 0;
    char* base = (char*)d_ws;
    auto alloc = [&](size_t bytes) -> void* {
        void* p = base + off;
        off += (bytes + 255) & ~(size_t)255;
        return p;
    };
    int*   cursor    = (int*)alloc(NB * 4);
    int*   row_start = (int*)alloc((NN + 1) * 4);
    float* dinv      = (float*)alloc(NN * 4);
    int2*  edges     = (int2*)alloc((size_t)NB * CAP * 8);        // strided bucket regions
    unsigned short* G  = (unsigned short*)alloc((size_t)NN * 256 * 2); // bf16 [h1|Ah1|A2h1|A3h1]
    unsigned short* B1 = (unsigned short*)alloc((size_t)NN * 32 * 2);  // bf16 [h0|Ah0|A2h0|A3h0]
    float* T         = (float*)alloc((size_t)NN * 64 * 4);        // layer-3 Horner buffer
    (void)ws_size;

    const int B = 256;
    const int gN = (NN + B - 1) / B;
    const int gK1 = (EE + K1_EPB - 1) / K1_EPB;      // 196
    const int gK3 = (NB * CAP + B - 1) / B;          // 3666
    const int gMM2 = (NN + 63) / 64;                 // 782
    const int gP32 = (NN + 31) / 32;                 // 1563 (TEAM=8,  NPB=32)
    const int gP8  = (NN + 7) / 8;                   // 6250 (TEAM=32, NPB=8)

    hipMemsetAsync(cursor, 0, NB * 4, stream);

    // ---- CSR build (bucketed, atomic-light, 512 thr) ----
    bucket_scatter_kernel<<<gK1, 512, 0, stream>>>(src, dst, ea, cursor, edges, EE);
    bucket_build_kernel<<<NB, 512, 0, stream>>>(cursor, edges, dinv, row_start, NN);
    srcscale_kernel<<<gK3, B, 0, stream>>>(cursor, dinv, edges);

    // ---- layer 1 (bf16): B1 = [h0|Ah0|A2h0|A3h0]; h1 = relu(B1@W1+b1) -> G chunk0 ----
    pack1_kernel<<<gN, B, 0, stream>>>(x, pos, B1, NN);
    prop8b_kernel<<<gP32, B, 0, stream>>>(row_start, cursor, edges, B1,      B1 + 8,  NN);
    prop8b_kernel<<<gP32, B, 0, stream>>>(row_start, cursor, edges, B1 + 8,  B1 + 16, NN);
    prop8b_kernel<<<gP32, B, 0, stream>>>(row_start, cursor, edges, B1 + 16, B1 + 24, NN);
    mm2_kernel<32, 32, 1, 0, 1, 1><<<gMM2, B, 0, stream>>>(B1, 32, W1, b1, G, 256, NN);

    // ---- layer 2 (bf16): G chunks 1..3 = A^k h1; T = relu(G@W2+b2) @ W3pad (fused) ----
    prop64b_kernel<<<gP8, B, 0, stream>>>(row_start, cursor, edges, G,       G + 64,  NN);
    prop64b_kernel<<<gP8, B, 0, stream>>>(row_start, cursor, edges, G + 64,  G + 128, NN);
    prop64b_kernel<<<gP8, B, 0, stream>>>(row_start, cursor, edges, G + 128, G + 192, NN);
    mm23_kernel<<<gMM2, B, 0, stream>>>(G, W2, b2, W3, T, NN);

    // ---- layer 3 (Horner, fp32): t2 = G2 + A*G3 ; t1 = G1 + A*t2 ; out = lsm(G0 + A*t1 + b3) ----
    prop_kernel<4, 2, true><<<gP32, B, 0, stream>>>(row_start, cursor, edges, T + 48, 64, T + 32, 64, NN);
    prop_kernel<4, 2, true><<<gP32, B, 0, stream>>>(row_start, cursor, edges, T + 32, 64, T + 16, 64, NN);
    prop_final_kernel<<<gP32, B, 0, stream>>>(row_start, cursor, edges, T + 16, T, b3, outp, NN);
}

// Round 8
// 279.415 us; speedup vs baseline: 2.5032x; 1.0746x over previous
//
#include <hip/hip_runtime.h>
#include <math.h>

// TAGConv GNN: N=50000, E=800000, K=3, layers (8->64, 64->64, 64->10)
// v8: mm23 phase-1 (h2 = relu(G@W2+b2), the 50000x256x64 GEMM) rewritten with
// v_mfma_f32_16x16x32_bf16: A-fragments load directly from bf16 G rows (1x16B
// global load), W2 pre-swizzled to bf16 B-fragments in LDS. Phase-2 (T = h2@W3pad)
// stays fp32 VALU. Everything else identical to v7.

#define NN 50000
#define EE 800000
#define HID 64
#define NOUT 10
#define CH 512

#define NB 391        // ceil(50000/128) buckets of 128 nodes
#define CAP 2400      // region capacity (mean 2047, +7.8 sigma)
#define K1_EPB 4096   // edges per K1 block

typedef __attribute__((ext_vector_type(8))) short bf16x8;
typedef __attribute__((ext_vector_type(4))) float f32x4;

// ---------------- bf16 helpers ----------------
__device__ __forceinline__ unsigned bf16rnd(float x) {
    unsigned u = __float_as_uint(x);
    return (u + 0x7FFFu + ((u >> 16) & 1u)) >> 16;
}
__device__ __forceinline__ unsigned packbf2(float a, float b) {
    return bf16rnd(a) | (bf16rnd(b) << 16);
}
__device__ __forceinline__ float bflo(unsigned u) { return __uint_as_float(u << 16); }
__device__ __forceinline__ float bfhi(unsigned u) { return __uint_as_float(u & 0xFFFF0000u); }

// ---------------- K1: coarse bucket scatter (512 thr) ----------------
__global__ __launch_bounds__(512) void bucket_scatter_kernel(
        const int* __restrict__ src, const int* __restrict__ dst,
        const float* __restrict__ ea, int* __restrict__ cursor,
        int2* __restrict__ regions, int e) {
    __shared__ int hist[NB];
    __shared__ int base[NB];
    int tid = threadIdx.x;
    int e0 = blockIdx.x * K1_EPB;
    int e1 = e0 + K1_EPB; if (e1 > e) e1 = e;
    for (int i = tid; i < NB; i += 512) hist[i] = 0;
    __syncthreads();
    for (int i = e0 + tid; i < e1; i += 512)
        atomicAdd(&hist[dst[i] >> 7], 1);
    __syncthreads();
    for (int b = tid; b < NB; b += 512) {
        int c = hist[b];
        base[b] = (c > 0) ? atomicAdd(&cursor[b], c) : 0;
        hist[b] = 0;   // reuse as local cursor
    }
    __syncthreads();
    for (int i = e0 + tid; i < e1; i += 512) {
        int d = dst[i];
        int b = d >> 7;
        int r = atomicAdd(&hist[b], 1);
        int pos = base[b] + r;
        if (pos < CAP)
            regions[(size_t)b * CAP + pos] =
                make_int2(((d & 127) << 16) | src[i], __float_as_int(ea[i]));
    }
}

// ---------------- K2: per-bucket fine sort + row_start + dinv + w0 (512 thr) ----------------
__global__ __launch_bounds__(512) void bucket_build_kernel(
        const int* __restrict__ cursor, int2* __restrict__ regions,
        float* __restrict__ dinv, int* __restrict__ row_start, int n) {
    __shared__ int2 rec[CAP];
    __shared__ int hist[128];
    __shared__ float easum[128];
    __shared__ float dl[128];
    __shared__ int off[129];
    __shared__ int lcur[128];
    int b = blockIdx.x;
    int tid = threadIdx.x;
    int cnt = cursor[b]; if (cnt > CAP) cnt = CAP;
    size_t rb = (size_t)b * CAP;
    if (tid < 128) { hist[tid] = 0; easum[tid] = 0.f; lcur[tid] = 0; }
    __syncthreads();
    for (int i = tid; i < cnt; i += 512) {
        int2 r = regions[rb + i];
        rec[i] = r;
        int f = r.x >> 16;
        atomicAdd(&hist[f], 1);
        atomicAdd(&easum[f], __int_as_float(r.y));
    }
    __syncthreads();
    if (tid < 128) {
        int lane = tid & 63;
        int v = hist[tid];
        for (int o2 = 1; o2 < 64; o2 <<= 1) {
            int y = __shfl_up(v, o2, 64);
            if (lane >= o2) v += y;
        }
        off[tid + 1] = v;     // wave-local inclusive
        float s2 = easum[tid];
        dl[tid] = (s2 > 0.f) ? rsqrtf(s2) : 0.f;
    }
    __syncthreads();
    if (tid == 255) off[0] = 0;
    if (tid >= 64 && tid < 128) off[tid + 1] += off[64];
    __syncthreads();
    if (tid < 128) {
        int node = b * 128 + tid;
        if (node <= n) row_start[node] = b * CAP + off[tid];
        if (node < n)  dinv[node] = dl[tid];
    }
    __syncthreads();
    for (int i = tid; i < cnt; i += 512) {
        int2 r = rec[i];
        int f = r.x >> 16;
        int s = r.x & 0xFFFF;
        int p = atomicAdd(&lcur[f], 1);
        float w0 = __int_as_float(r.y) * dl[f];
        regions[rb + off[f] + p] = make_int2(s, __float_as_int(w0));
    }
}

// ---------------- K3: w *= dinv[src] ----------------
__global__ __launch_bounds__(256) void srcscale_kernel(
        const int* __restrict__ cursor, const float* __restrict__ dinv,
        int2* __restrict__ regions) {
    int i = blockIdx.x * blockDim.x + threadIdx.x;
    int b = i / CAP;
    if (b >= NB) return;
    int off = i - b * CAP;
    int cnt = cursor[b]; if (cnt > CAP) cnt = CAP;
    if (off >= cnt) return;
    int2 r = regions[i];
    r.y = __float_as_int(__int_as_float(r.y) * dinv[r.x]);
    regions[i] = r;
}

// ---------------- pack x,pos -> B1 chunk0 (bf16, stride 32 ushorts) ----------------
__global__ __launch_bounds__(256) void pack1_kernel(const float* __restrict__ x,
                                                    const float* __restrict__ pos,
                                                    unsigned short* __restrict__ B1, int n) {
    int i = blockIdx.x * blockDim.x + threadIdx.x;
    if (i >= n) return;
    float2 a = *reinterpret_cast<const float2*>(x + (size_t)i * 6);
    float2 b = *reinterpret_cast<const float2*>(x + (size_t)i * 6 + 2);
    float2 c = *reinterpret_cast<const float2*>(x + (size_t)i * 6 + 4);
    float2 p = *reinterpret_cast<const float2*>(pos + (size_t)i * 2);
    uint4 o;
    o.x = packbf2(a.x, a.y);
    o.y = packbf2(b.x, b.y);
    o.z = packbf2(c.x, c.y);
    o.w = packbf2(p.x, p.y);
    *reinterpret_cast<uint4*>(B1 + (size_t)i * 32) = o;
}

// ---------------- bf16 width-8 propagation (layer 1): 1 load/edge ----------------
__global__ __launch_bounds__(256) void prop8b_kernel(const int* __restrict__ row_start,
                                                     const int* __restrict__ cursor,
                                                     const int2* __restrict__ edges,
                                                     const unsigned short* __restrict__ Gin,
                                                     unsigned short* __restrict__ Gout, int n) {
    constexpr int TEAM = 8, NPB = 32;
    __shared__ int2 se[CH];
    int tid = threadIdx.x;
    int nb = blockIdx.x * NPB;
    int node = nb + tid / TEAM;
    int es = tid % TEAM;
    int nbEnd = (nb + NPB < n) ? (nb + NPB) : n;
    int bkt = nb >> 7;
    int cc = cursor[bkt]; if (cc > CAP) cc = CAP;
    int ce = bkt * CAP + cc;
    int blkBeg = row_start[nb];
    int blkEnd = row_start[nbEnd]; if (blkEnd > ce) blkEnd = ce;
    int beg = 0, end = 0;
    if (node < n) {
        beg = row_start[node];
        end = row_start[node + 1]; if (end > ce) end = ce;
    }
    float a0 = 0.f, a1 = 0.f, a2 = 0.f, a3 = 0.f, a4 = 0.f, a5 = 0.f, a6 = 0.f, a7 = 0.f;
    for (int base = blkBeg; base < blkEnd; base += CH) {
        int m = blkEnd - base; if (m > CH) m = CH;
        __syncthreads();
        for (int i = tid; i < m; i += 256) se[i] = edges[base + i];
        __syncthreads();
        int lo = (beg > base) ? (beg - base) : 0;
        int hi = ((end < base + m) ? end : (base + m)) - base;
        for (int i = lo + es; i < hi; i += TEAM) {
            int2 e = se[i];
            float w = __int_as_float(e.y);
            const uint4 v = *reinterpret_cast<const uint4*>(Gin + (size_t)e.x * 32);
            a0 += w * bflo(v.x); a1 += w * bfhi(v.x);
            a2 += w * bflo(v.y); a3 += w * bfhi(v.y);
            a4 += w * bflo(v.z); a5 += w * bfhi(v.z);
            a6 += w * bflo(v.w); a7 += w * bfhi(v.w);
        }
    }
    #pragma unroll
    for (int msk = 1; msk < TEAM; msk <<= 1) {
        a0 += __shfl_xor(a0, msk); a1 += __shfl_xor(a1, msk);
        a2 += __shfl_xor(a2, msk); a3 += __shfl_xor(a3, msk);
        a4 += __shfl_xor(a4, msk); a5 += __shfl_xor(a5, msk);
        a6 += __shfl_xor(a6, msk); a7 += __shfl_xor(a7, msk);
    }
    if (node < n && es == 0) {
        uint4 o;
        o.x = packbf2(a0, a1);
        o.y = packbf2(a2, a3);
        o.z = packbf2(a4, a5);
        o.w = packbf2(a6, a7);
        *reinterpret_cast<uint4*>(Gout + (size_t)node * 32) = o;
    }
}

// ---------------- fp32 propagation (layer 3) ----------------
template <int TPN, int ES, bool ACC>
__global__ __launch_bounds__(256) void prop_kernel(const int* __restrict__ row_start,
                                                   const int* __restrict__ cursor,
                                                   const int2* __restrict__ edges,
                                                   const float* __restrict__ hin, int in_stride,
                                                   float* __restrict__ hout, int out_stride, int n) {
    constexpr int TEAM = TPN * ES;
    constexpr int NPB = 256 / TEAM;
    __shared__ int2 se[CH];
    int tid = threadIdx.x;
    int nb = blockIdx.x * NPB;
    int node = nb + tid / TEAM;
    int t = tid % TEAM;
    int es = t / TPN;
    int lane = t % TPN;
    int nbEnd = (nb + NPB < n) ? (nb + NPB) : n;
    int bkt = nb >> 7;
    int cc = cursor[bkt]; if (cc > CAP) cc = CAP;
    int ce = bkt * CAP + cc;
    int blkBeg = row_start[nb];
    int blkEnd = row_start[nbEnd]; if (blkEnd > ce) blkEnd = ce;
    int beg = 0, end = 0;
    if (node < n) {
        beg = row_start[node];
        end = row_start[node + 1]; if (end > ce) end = ce;
    }
    float ax = 0.f, ay = 0.f, az = 0.f, aw = 0.f;
    for (int base = blkBeg; base < blkEnd; base += CH) {
        int m = blkEnd - base; if (m > CH) m = CH;
        __syncthreads();
        for (int i = tid; i < m; i += 256) se[i] = edges[base + i];
        __syncthreads();
        int lo = (beg > base) ? (beg - base) : 0;
        int hi = ((end < base + m) ? end : (base + m)) - base;
        for (int i = lo + es; i < hi; i += ES) {
            int2 e = se[i];
            float w = __int_as_float(e.y);
            const float4 v = *reinterpret_cast<const float4*>(hin + (size_t)e.x * in_stride + lane * 4);
            ax += w * v.x; ay += w * v.y; az += w * v.z; aw += w * v.w;
        }
    }
    #pragma unroll
    for (int msk = TPN; msk < TEAM; msk <<= 1) {
        ax += __shfl_xor(ax, msk);
        ay += __shfl_xor(ay, msk);
        az += __shfl_xor(az, msk);
        aw += __shfl_xor(aw, msk);
    }
    if (node < n && es == 0) {
        float4* po = reinterpret_cast<float4*>(hout + (size_t)node * out_stride + lane * 4);
        float4 r = make_float4(ax, ay, az, aw);
        if (ACC) { float4 o = *po; r.x += o.x; r.y += o.y; r.z += o.z; r.w += o.w; }
        *po = r;
    }
}

// ---------------- bf16 width-64 propagation (layer 2): Gout = A * Gin ----------------
__global__ __launch_bounds__(256) void prop64b_kernel(const int* __restrict__ row_start,
                                                      const int* __restrict__ cursor,
                                                      const int2* __restrict__ edges,
                                                      const unsigned short* __restrict__ Gin,
                                                      unsigned short* __restrict__ Gout, int n) {
    constexpr int TPN = 8, ES = 4, TEAM = 32, NPB = 8;
    __shared__ int2 se[CH];
    int tid = threadIdx.x;
    int nb = blockIdx.x * NPB;
    int node = nb + tid / TEAM;
    int t = tid % TEAM;
    int es = t / TPN;
    int lane = t % TPN;
    int nbEnd = (nb + NPB < n) ? (nb + NPB) : n;
    int bkt = nb >> 7;
    int cc = cursor[bkt]; if (cc > CAP) cc = CAP;
    int ce = bkt * CAP + cc;
    int blkBeg = row_start[nb];
    int blkEnd = row_start[nbEnd]; if (blkEnd > ce) blkEnd = ce;
    int beg = 0, end = 0;
    if (node < n) {
        beg = row_start[node];
        end = row_start[node + 1]; if (end > ce) end = ce;
    }
    float a0 = 0.f, a1 = 0.f, a2 = 0.f, a3 = 0.f, a4 = 0.f, a5 = 0.f, a6 = 0.f, a7 = 0.f;
    for (int base = blkBeg; base < blkEnd; base += CH) {
        int m = blkEnd - base; if (m > CH) m = CH;
        __syncthreads();
        for (int i = tid; i < m; i += 256) se[i] = edges[base + i];
        __syncthreads();
        int lo = (beg > base) ? (beg - base) : 0;
        int hi = ((end < base + m) ? end : (base + m)) - base;
        for (int i = lo + es; i < hi; i += ES) {
            int2 e = se[i];
            float w = __int_as_float(e.y);
            const uint4 v = *reinterpret_cast<const uint4*>(Gin + (size_t)e.x * 256 + lane * 8);
            a0 += w * bflo(v.x); a1 += w * bfhi(v.x);
            a2 += w * bflo(v.y); a3 += w * bfhi(v.y);
            a4 += w * bflo(v.z); a5 += w * bfhi(v.z);
            a6 += w * bflo(v.w); a7 += w * bfhi(v.w);
        }
    }
    #pragma unroll
    for (int msk = TPN; msk < TEAM; msk <<= 1) {
        a0 += __shfl_xor(a0, msk); a1 += __shfl_xor(a1, msk);
        a2 += __shfl_xor(a2, msk); a3 += __shfl_xor(a3, msk);
        a4 += __shfl_xor(a4, msk); a5 += __shfl_xor(a5, msk);
        a6 += __shfl_xor(a6, msk); a7 += __shfl_xor(a7, msk);
    }
    if (node < n && es == 0) {
        uint4 o;
        o.x = packbf2(a0, a1);
        o.y = packbf2(a2, a3);
        o.z = packbf2(a4, a5);
        o.w = packbf2(a6, a7);
        *reinterpret_cast<uint4*>(Gout + (size_t)node * 256 + lane * 8) = o;
    }
}

// ---------------- final prop: out = log_softmax(g0 + A*t1 + b3) ----------------
__global__ __launch_bounds__(256) void prop_final_kernel(const int* __restrict__ row_start,
                                                         const int* __restrict__ cursor,
                                                         const int2* __restrict__ edges,
                                                         const float* __restrict__ hin,
                                                         const float* __restrict__ g0,
                                                         const float* __restrict__ b3,
                                                         float* __restrict__ out, int n) {
    constexpr int TPN = 4, ES = 2, TEAM = 8, NPB = 32;
    __shared__ int2 se[CH];
    int tid = threadIdx.x;
    int nb = blockIdx.x * NPB;
    int node = nb + tid / TEAM;
    int t = tid % TEAM;
    int es = t / TPN;
    int lane = t % TPN;
    int nbEnd = (nb + NPB < n) ? (nb + NPB) : n;
    int bkt = nb >> 7;
    int cc = cursor[bkt]; if (cc > CAP) cc = CAP;
    int ce = bkt * CAP + cc;
    int blkBeg = row_start[nb];
    int blkEnd = row_start[nbEnd]; if (blkEnd > ce) blkEnd = ce;
    int beg = 0, end = 0;
    if (node < n) {
        beg = row_start[node];
        end = row_start[node + 1]; if (end > ce) end = ce;
    }
    float ax = 0.f, ay = 0.f, az = 0.f, aw = 0.f;
    for (int base = blkBeg; base < blkEnd; base += CH) {
        int m = blkEnd - base; if (m > CH) m = CH;
        __syncthreads();
        for (int i = tid; i < m; i += 256) se[i] = edges[base + i];
        __syncthreads();
        int lo = (beg > base) ? (beg - base) : 0;
        int hi = ((end < base + m) ? end : (base + m)) - base;
        for (int i = lo + es; i < hi; i += ES) {
            int2 e = se[i];
            float w = __int_as_float(e.y);
            const float4 v = *reinterpret_cast<const float4*>(hin + (size_t)e.x * 64 + lane * 4);
            ax += w * v.x; ay += w * v.y; az += w * v.z; aw += w * v.w;
        }
    }
    ax += __shfl_xor(ax, TPN);
    ay += __shfl_xor(ay, TPN);
    az += __shfl_xor(az, TPN);
    aw += __shfl_xor(aw, TPN);
    if (node < n && es == 0) {
        const float4 g = *reinterpret_cast<const float4*>(g0 + (size_t)node * 64 + lane * 4);
        float vv[4] = {ax + g.x, ay + g.y, az + g.z, aw + g.w};
        int c0 = lane * 4;
        float mloc = -1e30f;
        #pragma unroll
        for (int c = 0; c < 4; ++c) {
            int col = c0 + c;
            if (col < NOUT) { vv[c] += b3[col]; mloc = fmaxf(mloc, vv[c]); }
        }
        float mo = fmaxf(mloc, __shfl_xor(mloc, 1));
        mo = fmaxf(mo, __shfl_xor(mo, 2));
        float sl = 0.f;
        #pragma unroll
        for (int c = 0; c < 4; ++c) {
            int col = c0 + c;
            if (col < NOUT) sl += __expf(vv[c] - mo);
        }
        sl += __shfl_xor(sl, 1);
        sl += __shfl_xor(sl, 2);
        float ls = __logf(sl);
        #pragma unroll
        for (int c = 0; c < 4; ++c) {
            int col = c0 + c;
            if (col < NOUT) out[(size_t)node * NOUT + col] = vv[c] - mo - ls;
        }
    }
}

// ---------------- register-blocked matmul (layer 1): 64 nodes x 64 outs ----------------
template <int FIN, int KC, int EPI, int WMODE, int INBF16, int OUTBF16>
__global__ __launch_bounds__(256) void mm2_kernel(const void* __restrict__ hraw, int hstride,
                                                  const float* __restrict__ W,
                                                  const float* __restrict__ bias,
                                                  void* __restrict__ outraw, int ostride, int n) {
    constexpr int HP = 68;
    __shared__ float HsT[KC * HP];
    __shared__ float Ws[KC * 64];
    int tid = threadIdx.x;
    int ndq = tid >> 4;
    int f4  = tid & 15;
    int nd  = tid & 63;
    int wv  = tid >> 6;
    int nodeBase = blockIdx.x * 64;

    float4 acc0 = make_float4(0.f, 0.f, 0.f, 0.f);
    float4 acc1 = make_float4(0.f, 0.f, 0.f, 0.f);
    float4 acc2 = make_float4(0.f, 0.f, 0.f, 0.f);
    float4 acc3 = make_float4(0.f, 0.f, 0.f, 0.f);

    for (int kc = 0; kc < FIN; kc += KC) {
        if (WMODE == 0) {
            for (int i = tid * 4; i < KC * 64; i += 1024)
                *reinterpret_cast<float4*>(&Ws[i]) =
                    *reinterpret_cast<const float4*>(&W[(size_t)kc * 64 + i]);
        } else {
            for (int i = tid; i < KC * 64; i += 256) {
                int r = i >> 6, c = i & 63;
                int k = c >> 4, j = c & 15;
                Ws[i] = (j < NOUT) ? W[((size_t)k * FIN + kc + r) * NOUT + j] : 0.f;
            }
        }
        int node = nodeBase + nd;
        if constexpr (INBF16) {
            const unsigned short* hb = (const unsigned short*)hraw;
            constexpr int KPT = KC / 4;
            int k0 = wv * KPT;
            #pragma unroll
            for (int q = 0; q < KPT / 8; ++q) {
                uint4 v = make_uint4(0, 0, 0, 0);
                if (node < n)
                    v = *reinterpret_cast<const uint4*>(hb + (size_t)node * hstride + kc + k0 + q * 8);
                int kk = k0 + q * 8;
                HsT[(kk + 0) * HP + nd] = bflo(v.x); HsT[(kk + 1) * HP + nd] = bfhi(v.x);
                HsT[(kk + 2) * HP + nd] = bflo(v.y); HsT[(kk + 3) * HP + nd] = bfhi(v.y);
                HsT[(kk + 4) * HP + nd] = bflo(v.z); HsT[(kk + 5) * HP + nd] = bfhi(v.z);
                HsT[(kk + 6) * HP + nd] = bflo(v.w); HsT[(kk + 7) * HP + nd] = bfhi(v.w);
            }
        } else {
            const float* hf = (const float*)hraw;
            #pragma unroll
            for (int r = 0; r < KC / 16; ++r) {
                int k0 = wv * 4 + r * 16;
                float4 hv = make_float4(0.f, 0.f, 0.f, 0.f);
                if (node < n)
                    hv = *reinterpret_cast<const float4*>(&hf[(size_t)node * hstride + kc + k0]);
                HsT[(k0 + 0) * HP + nd] = hv.x;
                HsT[(k0 + 1) * HP + nd] = hv.y;
                HsT[(k0 + 2) * HP + nd] = hv.z;
                HsT[(k0 + 3) * HP + nd] = hv.w;
            }
        }
        __syncthreads();
        #pragma unroll 8
        for (int k = 0; k < KC; ++k) {
            const float4 hq = *reinterpret_cast<const float4*>(&HsT[k * HP + ndq * 4]);
            const float4 wq = *reinterpret_cast<const float4*>(&Ws[k * 64 + f4 * 4]);
            acc0.x += hq.x * wq.x; acc0.y += hq.x * wq.y; acc0.z += hq.x * wq.z; acc0.w += hq.x * wq.w;
            acc1.x += hq.y * wq.x; acc1.y += hq.y * wq.y; acc1.z += hq.y * wq.z; acc1.w += hq.y * wq.w;
            acc2.x += hq.z * wq.x; acc2.y += hq.z * wq.y; acc2.z += hq.z * wq.z; acc2.w += hq.z * wq.w;
            acc3.x += hq.w * wq.x; acc3.y += hq.w * wq.y; acc3.z += hq.w * wq.z; acc3.w += hq.w * wq.w;
        }
        __syncthreads();
    }

    float4 bv = make_float4(0.f, 0.f, 0.f, 0.f);
    if (EPI == 1) bv = *reinterpret_cast<const float4*>(&bias[f4 * 4]);
    float4 accs[4] = {acc0, acc1, acc2, acc3};
    #pragma unroll
    for (int i = 0; i < 4; ++i) {
        int node = nodeBase + ndq * 4 + i;
        if (node < n) {
            float4 a = accs[i];
            if (EPI == 1) {
                a.x = fmaxf(a.x + bv.x, 0.f); a.y = fmaxf(a.y + bv.y, 0.f);
                a.z = fmaxf(a.z + bv.z, 0.f); a.w = fmaxf(a.w + bv.w, 0.f);
            }
            if constexpr (OUTBF16) {
                unsigned short* ob = (unsigned short*)outraw;
                uint2 o;
                o.x = packbf2(a.x, a.y);
                o.y = packbf2(a.z, a.w);
                *reinterpret_cast<uint2*>(ob + (size_t)node * ostride + f4 * 4) = o;
            } else {
                float* of = (float*)outraw;
                *reinterpret_cast<float4*>(of + (size_t)node * ostride + f4 * 4) = a;
            }
        }
    }
}

// ---------------- fused mm2+mm3 with MFMA phase 1 ----------------
// Phase 1: h2 = relu(G@W2+b2) via v_mfma_f32_16x16x32_bf16.
//   A-frag: lane m=lane&15 (node row), k=(lane>>4)*8+j -> one 16B load from G row.
//   B-frag: W2 bf16 pre-swizzled in LDS as [t][s][lane][8] (t=n-tile, s=K-step).
//   C/D: col=lane&15, row=(lane>>4)*4+reg (m89-verified).
// Phase 2: T = h2 @ W3pad, fp32 VALU (as v7). LDS aliased across phases (33792 B).
__global__ __launch_bounds__(256) void mm23_kernel(const unsigned short* __restrict__ G,
                                                   const float* __restrict__ W2,
                                                   const float* __restrict__ b2,
                                                   const float* __restrict__ W3,
                                                   float* __restrict__ T, int n) {
    constexpr int HP = 68;
    __shared__ __align__(16) char smem[33792];
    unsigned short* w2s = (unsigned short*)smem;              // phase1: [4][8][64][8] bf16 = 32768 B
    float* HsT = (float*)smem;                                // phase2: [64*HP] = 17408 B
    float* Ws  = (float*)(smem + 64 * HP * 4);                // phase2: [64*64] = 16384 B
    int tid = threadIdx.x;
    int wave = tid >> 6;
    int lane = tid & 63;
    int nodeBase = blockIdx.x * 64;

    // ---- stage swizzled bf16 W2 fragments ----
    for (int slot = tid; slot < 2048; slot += 256) {
        int l = slot & 63;
        int s = (slot >> 6) & 7;
        int t = slot >> 9;
        int k0 = s * 32 + ((l >> 4) << 3);
        int col = t * 16 + (l & 15);
        unsigned short tmp[8];
        #pragma unroll
        for (int j = 0; j < 8; ++j)
            tmp[j] = (unsigned short)bf16rnd(W2[(size_t)(k0 + j) * 64 + col]);
        *reinterpret_cast<uint4*>(w2s + slot * 8) = *reinterpret_cast<const uint4*>(tmp);
    }
    __syncthreads();

    // ---- phase 1: MFMA over K=256 (8 steps), wave owns 16-node strip, 4 n-tiles ----
    int arow = nodeBase + wave * 16 + (lane & 15);
    bool aval = (arow < n);
    const unsigned short* arp = G + (size_t)arow * 256 + ((lane >> 4) << 3);
    f32x4 acc0 = {0.f, 0.f, 0.f, 0.f}, acc1 = {0.f, 0.f, 0.f, 0.f};
    f32x4 acc2 = {0.f, 0.f, 0.f, 0.f}, acc3 = {0.f, 0.f, 0.f, 0.f};
    #pragma unroll
    for (int s = 0; s < 8; ++s) {
        bf16x8 a = {};
        if (aval) a = *reinterpret_cast<const bf16x8*>(arp + s * 32);
        const unsigned short* wb = w2s + ((size_t)s * 64 + lane) * 8;
        bf16x8 bf0 = *reinterpret_cast<const bf16x8*>(wb);
        bf16x8 bf1 = *reinterpret_cast<const bf16x8*>(wb + 4096);
        bf16x8 bf2 = *reinterpret_cast<const bf16x8*>(wb + 8192);
        bf16x8 bf3 = *reinterpret_cast<const bf16x8*>(wb + 12288);
        acc0 = __builtin_amdgcn_mfma_f32_16x16x32_bf16(a, bf0, acc0, 0, 0, 0);
        acc1 = __builtin_amdgcn_mfma_f32_16x16x32_bf16(a, bf1, acc1, 0, 0, 0);
        acc2 = __builtin_amdgcn_mfma_f32_16x16x32_bf16(a, bf2, acc2, 0, 0, 0);
        acc3 = __builtin_amdgcn_mfma_f32_16x16x32_bf16(a, bf3, acc3, 0, 0, 0);
    }
    __syncthreads();   // all waves done reading w2s; LDS re-used below

    // ---- bias+relu epilogue; write h2 k-major into HsT[feature][nodeLocal] ----
    {
        int c = lane & 15;
        int rbase = wave * 16 + (lane >> 4) * 4;
        f32x4 accs[4] = {acc0, acc1, acc2, acc3};
        #pragma unroll
        for (int t = 0; t < 4; ++t) {
            int col = t * 16 + c;
            float bb = b2[col];
            #pragma unroll
            for (int r = 0; r < 4; ++r) {
                float v = accs[t][r] + bb;
                HsT[col * HP + rbase + r] = v > 0.f ? v : 0.f;
            }
        }
    }
    // ---- stage padded W3 (4,64,10) -> 64x64 ----
    for (int i = tid; i < 64 * 64; i += 256) {
        int r = i >> 6, c2 = i & 63;
        int k = c2 >> 4, j = c2 & 15;
        Ws[i] = (j < NOUT) ? W3[((size_t)k * 64 + r) * NOUT + j] : 0.f;
    }
    __syncthreads();

    // ---- phase 2: T = h2 @ W3pad (fp32 VALU) ----
    int ndq = tid >> 4;
    int f4  = tid & 15;
    float4 t0 = make_float4(0.f, 0.f, 0.f, 0.f);
    float4 t1 = make_float4(0.f, 0.f, 0.f, 0.f);
    float4 t2 = make_float4(0.f, 0.f, 0.f, 0.f);
    float4 t3 = make_float4(0.f, 0.f, 0.f, 0.f);
    #pragma unroll 8
    for (int k = 0; k < 64; ++k) {
        const float4 hq = *reinterpret_cast<const float4*>(&HsT[k * HP + ndq * 4]);
        const float4 wq = *reinterpret_cast<const float4*>(&Ws[k * 64 + f4 * 4]);
        t0.x += hq.x * wq.x; t0.y += hq.x * wq.y; t0.z += hq.x * wq.z; t0.w += hq.x * wq.w;
        t1.x += hq.y * wq.x; t1.y += hq.y * wq.y; t1.z += hq.y * wq.z; t1.w += hq.y * wq.w;
        t2.x += hq.z * wq.x; t2.y += hq.z * wq.y; t2.z += hq.z * wq.z; t2.w += hq.z * wq.w;
        t3.x += hq.w * wq.x; t3.y += hq.w * wq.y; t3.z += hq.w * wq.z; t3.w += hq.w * wq.w;
    }
    float4 ts[4] = {t0, t1, t2, t3};
    #pragma unroll
    for (int i = 0; i < 4; ++i) {
        int node = nodeBase + ndq * 4 + i;
        if (node < n)
            *reinterpret_cast<float4*>(T + (size_t)node * 64 + f4 * 4) = ts[i];
    }
}

extern "C" void kernel_launch(void* const* d_in, const int* in_sizes, int n_in,
                              void* d_out, int out_size, void* d_ws, size_t ws_size,
                              hipStream_t stream) {
    const float* x   = (const float*)d_in[0];
    const float* pos = (const float*)d_in[1];
    const float* ea  = (const float*)d_in[2];
    const float* W1  = (const float*)d_in[3];   // (4,8,64) == (32,64)
    const float* b1  = (const float*)d_in[4];
    const float* W2  = (const float*)d_in[5];   // (4,64,64) == (256,64)
    const float* b2  = (const float*)d_in[6];
    const float* W3  = (const float*)d_in[7];   // (4,64,10)
    const float* b3  = (const float*)d_in[8];
    const int* eidx  = (const int*)d_in[9];
    const int* src = eidx;
    const int* dst = eidx + EE;
    float* outp = (float*)d_out;

    size_t off = 0;
    char* base = (char*)d_ws;
    auto alloc = [&](size_t bytes) -> void* {
        void* p = base + off;
        off += (bytes + 255) & ~(size_t)255;
        return p;
    };
    int*   cursor    = (int*)alloc(NB * 4);
    int*   row_start = (int*)alloc((NN + 1) * 4);
    float* dinv      = (float*)alloc(NN * 4);
    int2*  edges     = (int2*)alloc((size_t)NB * CAP * 8);        // strided bucket regions
    unsigned short* G  = (unsigned short*)alloc((size_t)NN * 256 * 2); // bf16 [h1|Ah1|A2h1|A3h1]
    unsigned short* B1 = (unsigned short*)alloc((size_t)NN * 32 * 2);  // bf16 [h0|Ah0|A2h0|A3h0]
    float* T         = (float*)alloc((size_t)NN * 64 * 4);        // layer-3 Horner buffer
    (void)ws_size;

    const int B = 256;
    const int gN = (NN + B - 1) / B;
    const int gK1 = (EE + K1_EPB - 1) / K1_EPB;      // 196
    const int gK3 = (NB * CAP + B - 1) / B;          // 3666
    const int gMM2 = (NN + 63) / 64;                 // 782
    const int gP32 = (NN + 31) / 32;                 // 1563 (TEAM=8,  NPB=32)
    const int gP8  = (NN + 7) / 8;                   // 6250 (TEAM=32, NPB=8)

    hipMemsetAsync(cursor, 0, NB * 4, stream);

    // ---- CSR build (bucketed, atomic-light, 512 thr) ----
    bucket_scatter_kernel<<<gK1, 512, 0, stream>>>(src, dst, ea, cursor, edges, EE);
    bucket_build_kernel<<<NB, 512, 0, stream>>>(cursor, edges, dinv, row_start, NN);
    srcscale_kernel<<<gK3, B, 0, stream>>>(cursor, dinv, edges);

    // ---- layer 1 (bf16): B1 = [h0|Ah0|A2h0|A3h0]; h1 = relu(B1@W1+b1) -> G chunk0 ----
    pack1_kernel<<<gN, B, 0, stream>>>(x, pos, B1, NN);
    prop8b_kernel<<<gP32, B, 0, stream>>>(row_start, cursor, edges, B1,      B1 + 8,  NN);
    prop8b_kernel<<<gP32, B, 0, stream>>>(row_start, cursor, edges, B1 + 8,  B1 + 16, NN);
    prop8b_kernel<<<gP32, B, 0, stream>>>(row_start, cursor, edges, B1 + 16, B1 + 24, NN);
    mm2_kernel<32, 32, 1, 0, 1, 1><<<gMM2, B, 0, stream>>>(B1, 32, W1, b1, G, 256, NN);

    // ---- layer 2 (bf16): G chunks 1..3 = A^k h1; T = relu(G@W2+b2) @ W3pad (fused MFMA) ----
    prop64b_kernel<<<gP8, B, 0, stream>>>(row_start, cursor, edges, G,       G + 64,  NN);
    prop64b_kernel<<<gP8, B, 0, stream>>>(row_start, cursor, edges, G + 64,  G + 128, NN);
    prop64b_kernel<<<gP8, B, 0, stream>>>(row_start, cursor, edges, G + 128, G + 192, NN);
    mm23_kernel<<<gMM2, B, 0, stream>>>(G, W2, b2, W3, T, NN);

    // ---- layer 3 (Horner, fp32): t2 = G2 + A*G3 ; t1 = G1 + A*t2 ; out = lsm(G0 + A*t1 + b3) ----
    prop_kernel<4, 2, true><<<gP32, B, 0, stream>>>(row_start, cursor, edges, T + 48, 64, T + 32, 64, NN);
    prop_kernel<4, 2, true><<<gP32, B, 0, stream>>>(row_start, cursor, edges, T + 32, 64, T + 16, 64, NN);
    prop_final_kernel<<<gP32, B, 0, stream>>>(row_start, cursor, edges, T + 16, T, b3, outp, NN);
}

// Round 9
// 273.665 us; speedup vs baseline: 2.5559x; 1.0210x over previous
//
#include <hip/hip_runtime.h>
#include <math.h>

// TAGConv GNN: N=50000, E=800000, K=3, layers (8->64, 64->64, 64->10)
// v9: bucket_scatter at 391 blocks w/ register-cached edges; srcscale folded
// into layer-1 hop-1 edge staging (writes corrected w back); layer-1 matmul
// (mm1) rewritten with MFMA (port of v8's mm23 phase-1 pattern).
// Rest identical to v8.

#define NN 50000
#define EE 800000
#define HID 64
#define NOUT 10
#define CH 512

#define NB 391        // ceil(50000/128) buckets of 128 nodes
#define CAP 2400      // region capacity (mean 2047, +7.8 sigma)
#define K1_EPB 2048   // edges per K1 block (391 blocks)

typedef __attribute__((ext_vector_type(8))) short bf16x8;
typedef __attribute__((ext_vector_type(4))) float f32x4;

// ---------------- bf16 helpers ----------------
__device__ __forceinline__ unsigned bf16rnd(float x) {
    unsigned u = __float_as_uint(x);
    return (u + 0x7FFFu + ((u >> 16) & 1u)) >> 16;
}
__device__ __forceinline__ unsigned packbf2(float a, float b) {
    return bf16rnd(a) | (bf16rnd(b) << 16);
}
__device__ __forceinline__ float bflo(unsigned u) { return __uint_as_float(u << 16); }
__device__ __forceinline__ float bfhi(unsigned u) { return __uint_as_float(u & 0xFFFF0000u); }

// ---------------- K1: coarse bucket scatter (391 blocks, reg-cached) ----------------
__global__ __launch_bounds__(512) void bucket_scatter_kernel(
        const int* __restrict__ src, const int* __restrict__ dst,
        const float* __restrict__ ea, int* __restrict__ cursor,
        int2* __restrict__ regions, int e) {
    __shared__ int hist[NB];
    __shared__ int base_s[NB];
    int tid = threadIdx.x;
    int e0 = blockIdx.x * K1_EPB;
    int e1 = e0 + K1_EPB; if (e1 > e) e1 = e;
    int d[4], s[4];
    float w[4];
    int cnt = 0;
    for (int i = e0 + tid; i < e1; i += 512) {
        d[cnt] = dst[i]; s[cnt] = src[i]; w[cnt] = ea[i];
        ++cnt;
    }
    for (int i = tid; i < NB; i += 512) hist[i] = 0;
    __syncthreads();
    for (int j = 0; j < cnt; ++j)
        atomicAdd(&hist[d[j] >> 7], 1);
    __syncthreads();
    for (int b = tid; b < NB; b += 512) {
        int c = hist[b];
        base_s[b] = (c > 0) ? atomicAdd(&cursor[b], c) : 0;
        hist[b] = 0;   // reuse as local cursor
    }
    __syncthreads();
    for (int j = 0; j < cnt; ++j) {
        int b = d[j] >> 7;
        int r = atomicAdd(&hist[b], 1);
        int pos = base_s[b] + r;
        if (pos < CAP)
            regions[(size_t)b * CAP + pos] =
                make_int2(((d[j] & 127) << 16) | s[j], __float_as_int(w[j]));
    }
}

// ---------------- K2: per-bucket fine sort + row_start + dinv + w0 (512 thr) ----------------
__global__ __launch_bounds__(512) void bucket_build_kernel(
        const int* __restrict__ cursor, int2* __restrict__ regions,
        float* __restrict__ dinv, int* __restrict__ row_start, int n) {
    __shared__ int2 rec[CAP];
    __shared__ int hist[128];
    __shared__ float easum[128];
    __shared__ float dl[128];
    __shared__ int off[129];
    __shared__ int lcur[128];
    int b = blockIdx.x;
    int tid = threadIdx.x;
    int cnt = cursor[b]; if (cnt > CAP) cnt = CAP;
    size_t rb = (size_t)b * CAP;
    if (tid < 128) { hist[tid] = 0; easum[tid] = 0.f; lcur[tid] = 0; }
    __syncthreads();
    for (int i = tid; i < cnt; i += 512) {
        int2 r = regions[rb + i];
        rec[i] = r;
        int f = r.x >> 16;
        atomicAdd(&hist[f], 1);
        atomicAdd(&easum[f], __int_as_float(r.y));
    }
    __syncthreads();
    if (tid < 128) {
        int lane = tid & 63;
        int v = hist[tid];
        for (int o2 = 1; o2 < 64; o2 <<= 1) {
            int y = __shfl_up(v, o2, 64);
            if (lane >= o2) v += y;
        }
        off[tid + 1] = v;     // wave-local inclusive
        float s2 = easum[tid];
        dl[tid] = (s2 > 0.f) ? rsqrtf(s2) : 0.f;
    }
    __syncthreads();
    if (tid == 255) off[0] = 0;
    if (tid >= 64 && tid < 128) off[tid + 1] += off[64];
    __syncthreads();
    if (tid < 128) {
        int node = b * 128 + tid;
        if (node <= n) row_start[node] = b * CAP + off[tid];
        if (node < n)  dinv[node] = dl[tid];
    }
    __syncthreads();
    for (int i = tid; i < cnt; i += 512) {
        int2 r = rec[i];
        int f = r.x >> 16;
        int s = r.x & 0xFFFF;
        int p = atomicAdd(&lcur[f], 1);
        float w0 = __int_as_float(r.y) * dl[f];
        regions[rb + off[f] + p] = make_int2(s, __float_as_int(w0));
    }
}

// ---------------- pack x,pos -> B1 chunk0 (bf16, stride 32 ushorts) ----------------
__global__ __launch_bounds__(256) void pack1_kernel(const float* __restrict__ x,
                                                    const float* __restrict__ pos,
                                                    unsigned short* __restrict__ B1, int n) {
    int i = blockIdx.x * blockDim.x + threadIdx.x;
    if (i >= n) return;
    float2 a = *reinterpret_cast<const float2*>(x + (size_t)i * 6);
    float2 b = *reinterpret_cast<const float2*>(x + (size_t)i * 6 + 2);
    float2 c = *reinterpret_cast<const float2*>(x + (size_t)i * 6 + 4);
    float2 p = *reinterpret_cast<const float2*>(pos + (size_t)i * 2);
    uint4 o;
    o.x = packbf2(a.x, a.y);
    o.y = packbf2(b.x, b.y);
    o.z = packbf2(c.x, c.y);
    o.w = packbf2(p.x, p.y);
    *reinterpret_cast<uint4*>(B1 + (size_t)i * 32) = o;
}

// ---------------- bf16 width-8 propagation (layer 1): 1 load/edge ----------------
// SCALE=1 (hop 1): staging multiplies w by dinv[src] and writes the corrected
// record back to the edges array (replaces the srcscale pass).
template <int SCALE>
__global__ __launch_bounds__(256) void prop8b_kernel(const int* __restrict__ row_start,
                                                     const int* __restrict__ cursor,
                                                     int2* __restrict__ edges,
                                                     const float* __restrict__ dinv,
                                                     const unsigned short* __restrict__ Gin,
                                                     unsigned short* __restrict__ Gout, int n) {
    constexpr int TEAM = 8, NPB = 32;
    __shared__ int2 se[CH];
    int tid = threadIdx.x;
    int nb = blockIdx.x * NPB;
    int node = nb + tid / TEAM;
    int es = tid % TEAM;
    int nbEnd = (nb + NPB < n) ? (nb + NPB) : n;
    int bkt = nb >> 7;
    int cc = cursor[bkt]; if (cc > CAP) cc = CAP;
    int ce = bkt * CAP + cc;
    int blkBeg = row_start[nb];
    int blkEnd = row_start[nbEnd]; if (blkEnd > ce) blkEnd = ce;
    int beg = 0, end = 0;
    if (node < n) {
        beg = row_start[node];
        end = row_start[node + 1]; if (end > ce) end = ce;
    }
    float a0 = 0.f, a1 = 0.f, a2 = 0.f, a3 = 0.f, a4 = 0.f, a5 = 0.f, a6 = 0.f, a7 = 0.f;
    for (int base = blkBeg; base < blkEnd; base += CH) {
        int m = blkEnd - base; if (m > CH) m = CH;
        __syncthreads();
        for (int i = tid; i < m; i += 256) {
            int2 r = edges[base + i];
            if (SCALE) {
                r.y = __float_as_int(__int_as_float(r.y) * dinv[r.x]);
                edges[base + i] = r;
            }
            se[i] = r;
        }
        __syncthreads();
        int lo = (beg > base) ? (beg - base) : 0;
        int hi = ((end < base + m) ? end : (base + m)) - base;
        for (int i = lo + es; i < hi; i += TEAM) {
            int2 e = se[i];
            float w = __int_as_float(e.y);
            const uint4 v = *reinterpret_cast<const uint4*>(Gin + (size_t)e.x * 32);
            a0 += w * bflo(v.x); a1 += w * bfhi(v.x);
            a2 += w * bflo(v.y); a3 += w * bfhi(v.y);
            a4 += w * bflo(v.z); a5 += w * bfhi(v.z);
            a6 += w * bflo(v.w); a7 += w * bfhi(v.w);
        }
    }
    #pragma unroll
    for (int msk = 1; msk < TEAM; msk <<= 1) {
        a0 += __shfl_xor(a0, msk); a1 += __shfl_xor(a1, msk);
        a2 += __shfl_xor(a2, msk); a3 += __shfl_xor(a3, msk);
        a4 += __shfl_xor(a4, msk); a5 += __shfl_xor(a5, msk);
        a6 += __shfl_xor(a6, msk); a7 += __shfl_xor(a7, msk);
    }
    if (node < n && es == 0) {
        uint4 o;
        o.x = packbf2(a0, a1);
        o.y = packbf2(a2, a3);
        o.z = packbf2(a4, a5);
        o.w = packbf2(a6, a7);
        *reinterpret_cast<uint4*>(Gout + (size_t)node * 32) = o;
    }
}

// ---------------- fp32 propagation (layer 3) ----------------
template <int TPN, int ES, bool ACC>
__global__ __launch_bounds__(256) void prop_kernel(const int* __restrict__ row_start,
                                                   const int* __restrict__ cursor,
                                                   const int2* __restrict__ edges,
                                                   const float* __restrict__ hin, int in_stride,
                                                   float* __restrict__ hout, int out_stride, int n) {
    constexpr int TEAM = TPN * ES;
    constexpr int NPB = 256 / TEAM;
    __shared__ int2 se[CH];
    int tid = threadIdx.x;
    int nb = blockIdx.x * NPB;
    int node = nb + tid / TEAM;
    int t = tid % TEAM;
    int es = t / TPN;
    int lane = t % TPN;
    int nbEnd = (nb + NPB < n) ? (nb + NPB) : n;
    int bkt = nb >> 7;
    int cc = cursor[bkt]; if (cc > CAP) cc = CAP;
    int ce = bkt * CAP + cc;
    int blkBeg = row_start[nb];
    int blkEnd = row_start[nbEnd]; if (blkEnd > ce) blkEnd = ce;
    int beg = 0, end = 0;
    if (node < n) {
        beg = row_start[node];
        end = row_start[node + 1]; if (end > ce) end = ce;
    }
    float ax = 0.f, ay = 0.f, az = 0.f, aw = 0.f;
    for (int base = blkBeg; base < blkEnd; base += CH) {
        int m = blkEnd - base; if (m > CH) m = CH;
        __syncthreads();
        for (int i = tid; i < m; i += 256) se[i] = edges[base + i];
        __syncthreads();
        int lo = (beg > base) ? (beg - base) : 0;
        int hi = ((end < base + m) ? end : (base + m)) - base;
        for (int i = lo + es; i < hi; i += ES) {
            int2 e = se[i];
            float w = __int_as_float(e.y);
            const float4 v = *reinterpret_cast<const float4*>(hin + (size_t)e.x * in_stride + lane * 4);
            ax += w * v.x; ay += w * v.y; az += w * v.z; aw += w * v.w;
        }
    }
    #pragma unroll
    for (int msk = TPN; msk < TEAM; msk <<= 1) {
        ax += __shfl_xor(ax, msk);
        ay += __shfl_xor(ay, msk);
        az += __shfl_xor(az, msk);
        aw += __shfl_xor(aw, msk);
    }
    if (node < n && es == 0) {
        float4* po = reinterpret_cast<float4*>(hout + (size_t)node * out_stride + lane * 4);
        float4 r = make_float4(ax, ay, az, aw);
        if (ACC) { float4 o = *po; r.x += o.x; r.y += o.y; r.z += o.z; r.w += o.w; }
        *po = r;
    }
}

// ---------------- bf16 width-64 propagation (layer 2): Gout = A * Gin ----------------
__global__ __launch_bounds__(256) void prop64b_kernel(const int* __restrict__ row_start,
                                                      const int* __restrict__ cursor,
                                                      const int2* __restrict__ edges,
                                                      const unsigned short* __restrict__ Gin,
                                                      unsigned short* __restrict__ Gout, int n) {
    constexpr int TPN = 8, ES = 4, TEAM = 32, NPB = 8;
    __shared__ int2 se[CH];
    int tid = threadIdx.x;
    int nb = blockIdx.x * NPB;
    int node = nb + tid / TEAM;
    int t = tid % TEAM;
    int es = t / TPN;
    int lane = t % TPN;
    int nbEnd = (nb + NPB < n) ? (nb + NPB) : n;
    int bkt = nb >> 7;
    int cc = cursor[bkt]; if (cc > CAP) cc = CAP;
    int ce = bkt * CAP + cc;
    int blkBeg = row_start[nb];
    int blkEnd = row_start[nbEnd]; if (blkEnd > ce) blkEnd = ce;
    int beg = 0, end = 0;
    if (node < n) {
        beg = row_start[node];
        end = row_start[node + 1]; if (end > ce) end = ce;
    }
    float a0 = 0.f, a1 = 0.f, a2 = 0.f, a3 = 0.f, a4 = 0.f, a5 = 0.f, a6 = 0.f, a7 = 0.f;
    for (int base = blkBeg; base < blkEnd; base += CH) {
        int m = blkEnd - base; if (m > CH) m = CH;
        __syncthreads();
        for (int i = tid; i < m; i += 256) se[i] = edges[base + i];
        __syncthreads();
        int lo = (beg > base) ? (beg - base) : 0;
        int hi = ((end < base + m) ? end : (base + m)) - base;
        for (int i = lo + es; i < hi; i += ES) {
            int2 e = se[i];
            float w = __int_as_float(e.y);
            const uint4 v = *reinterpret_cast<const uint4*>(Gin + (size_t)e.x * 256 + lane * 8);
            a0 += w * bflo(v.x); a1 += w * bfhi(v.x);
            a2 += w * bflo(v.y); a3 += w * bfhi(v.y);
            a4 += w * bflo(v.z); a5 += w * bfhi(v.z);
            a6 += w * bflo(v.w); a7 += w * bfhi(v.w);
        }
    }
    #pragma unroll
    for (int msk = TPN; msk < TEAM; msk <<= 1) {
        a0 += __shfl_xor(a0, msk); a1 += __shfl_xor(a1, msk);
        a2 += __shfl_xor(a2, msk); a3 += __shfl_xor(a3, msk);
        a4 += __shfl_xor(a4, msk); a5 += __shfl_xor(a5, msk);
        a6 += __shfl_xor(a6, msk); a7 += __shfl_xor(a7, msk);
    }
    if (node < n && es == 0) {
        uint4 o;
        o.x = packbf2(a0, a1);
        o.y = packbf2(a2, a3);
        o.z = packbf2(a4, a5);
        o.w = packbf2(a6, a7);
        *reinterpret_cast<uint4*>(Gout + (size_t)node * 256 + lane * 8) = o;
    }
}

// ---------------- final prop: out = log_softmax(g0 + A*t1 + b3) ----------------
__global__ __launch_bounds__(256) void prop_final_kernel(const int* __restrict__ row_start,
                                                         const int* __restrict__ cursor,
                                                         const int2* __restrict__ edges,
                                                         const float* __restrict__ hin,
                                                         const float* __restrict__ g0,
                                                         const float* __restrict__ b3,
                                                         float* __restrict__ out, int n) {
    constexpr int TPN = 4, ES = 2, TEAM = 8, NPB = 32;
    __shared__ int2 se[CH];
    int tid = threadIdx.x;
    int nb = blockIdx.x * NPB;
    int node = nb + tid / TEAM;
    int t = tid % TEAM;
    int es = t / TPN;
    int lane = t % TPN;
    int nbEnd = (nb + NPB < n) ? (nb + NPB) : n;
    int bkt = nb >> 7;
    int cc = cursor[bkt]; if (cc > CAP) cc = CAP;
    int ce = bkt * CAP + cc;
    int blkBeg = row_start[nb];
    int blkEnd = row_start[nbEnd]; if (blkEnd > ce) blkEnd = ce;
    int beg = 0, end = 0;
    if (node < n) {
        beg = row_start[node];
        end = row_start[node + 1]; if (end > ce) end = ce;
    }
    float ax = 0.f, ay = 0.f, az = 0.f, aw = 0.f;
    for (int base = blkBeg; base < blkEnd; base += CH) {
        int m = blkEnd - base; if (m > CH) m = CH;
        __syncthreads();
        for (int i = tid; i < m; i += 256) se[i] = edges[base + i];
        __syncthreads();
        int lo = (beg > base) ? (beg - base) : 0;
        int hi = ((end < base + m) ? end : (base + m)) - base;
        for (int i = lo + es; i < hi; i += ES) {
            int2 e = se[i];
            float w = __int_as_float(e.y);
            const float4 v = *reinterpret_cast<const float4*>(hin + (size_t)e.x * 64 + lane * 4);
            ax += w * v.x; ay += w * v.y; az += w * v.z; aw += w * v.w;
        }
    }
    ax += __shfl_xor(ax, TPN);
    ay += __shfl_xor(ay, TPN);
    az += __shfl_xor(az, TPN);
    aw += __shfl_xor(aw, TPN);
    if (node < n && es == 0) {
        const float4 g = *reinterpret_cast<const float4*>(g0 + (size_t)node * 64 + lane * 4);
        float vv[4] = {ax + g.x, ay + g.y, az + g.z, aw + g.w};
        int c0 = lane * 4;
        float mloc = -1e30f;
        #pragma unroll
        for (int c = 0; c < 4; ++c) {
            int col = c0 + c;
            if (col < NOUT) { vv[c] += b3[col]; mloc = fmaxf(mloc, vv[c]); }
        }
        float mo = fmaxf(mloc, __shfl_xor(mloc, 1));
        mo = fmaxf(mo, __shfl_xor(mo, 2));
        float sl = 0.f;
        #pragma unroll
        for (int c = 0; c < 4; ++c) {
            int col = c0 + c;
            if (col < NOUT) sl += __expf(vv[c] - mo);
        }
        sl += __shfl_xor(sl, 1);
        sl += __shfl_xor(sl, 2);
        float ls = __logf(sl);
        #pragma unroll
        for (int c = 0; c < 4; ++c) {
            int col = c0 + c;
            if (col < NOUT) out[(size_t)node * NOUT + col] = vv[c] - mo - ls;
        }
    }
}

// ---------------- MFMA layer-1 matmul: G0 = relu(B1 @ W1 + b1) as bf16 ----------------
// K=32: one mfma_f32_16x16x32_bf16 per 16-col tile. A-frag straight from B1 row.
__global__ __launch_bounds__(256) void mm1_kernel(const unsigned short* __restrict__ B1,
                                                  const float* __restrict__ W1,
                                                  const float* __restrict__ b1,
                                                  unsigned short* __restrict__ G, int n) {
    __shared__ unsigned short w1s[2048];   // [t(4)][lane(64)][8] bf16 = 4 KB
    __shared__ unsigned short hs[64 * 64]; // h1 tile bf16 [nodeLocal][col] = 8 KB
    int tid = threadIdx.x;
    int wave = tid >> 6;
    int lane = tid & 63;
    int nodeBase = blockIdx.x * 64;

    // stage swizzled bf16 W1 fragments (256 slots, 1 per thread)
    {
        int l = tid & 63;
        int t = tid >> 6;
        int k0 = (l >> 4) << 3;
        int col = t * 16 + (l & 15);
        unsigned short tmp[8];
        #pragma unroll
        for (int j = 0; j < 8; ++j)
            tmp[j] = (unsigned short)bf16rnd(W1[(size_t)(k0 + j) * 64 + col]);
        *reinterpret_cast<uint4*>(w1s + tid * 8) = *reinterpret_cast<const uint4*>(tmp);
    }
    __syncthreads();

    int arow = nodeBase + wave * 16 + (lane & 15);
    bf16x8 a = {};
    if (arow < n)
        a = *reinterpret_cast<const bf16x8*>(B1 + (size_t)arow * 32 + ((lane >> 4) << 3));
    const unsigned short* wb = w1s + lane * 8;
    f32x4 acc0 = {0.f, 0.f, 0.f, 0.f}, acc1 = {0.f, 0.f, 0.f, 0.f};
    f32x4 acc2 = {0.f, 0.f, 0.f, 0.f}, acc3 = {0.f, 0.f, 0.f, 0.f};
    acc0 = __builtin_amdgcn_mfma_f32_16x16x32_bf16(a, *reinterpret_cast<const bf16x8*>(wb),        acc0, 0, 0, 0);
    acc1 = __builtin_amdgcn_mfma_f32_16x16x32_bf16(a, *reinterpret_cast<const bf16x8*>(wb + 512),  acc1, 0, 0, 0);
    acc2 = __builtin_amdgcn_mfma_f32_16x16x32_bf16(a, *reinterpret_cast<const bf16x8*>(wb + 1024), acc2, 0, 0, 0);
    acc3 = __builtin_amdgcn_mfma_f32_16x16x32_bf16(a, *reinterpret_cast<const bf16x8*>(wb + 1536), acc3, 0, 0, 0);

    // epilogue: bias+relu, bf16, into LDS tile [nodeLocal][col]
    {
        int c = lane & 15;
        int rbase = wave * 16 + (lane >> 4) * 4;
        f32x4 accs[4] = {acc0, acc1, acc2, acc3};
        #pragma unroll
        for (int t = 0; t < 4; ++t) {
            int col = t * 16 + c;
            float bb = b1[col];
            #pragma unroll
            for (int r = 0; r < 4; ++r) {
                float v = accs[t][r] + bb;
                hs[(rbase + r) * 64 + col] = (unsigned short)bf16rnd(v > 0.f ? v : 0.f);
            }
        }
    }
    __syncthreads();
    // coalesced write-out: 64 rows x 8 uint4 chunks
    for (int i = tid; i < 512; i += 256) {
        int nd = i >> 3, ch = i & 7;
        int node = nodeBase + nd;
        if (node < n)
            *reinterpret_cast<uint4*>(G + (size_t)node * 256 + ch * 8) =
                *reinterpret_cast<const uint4*>(hs + nd * 64 + ch * 8);
    }
}

// ---------------- fused mm2+mm3 with MFMA phase 1 (v8) ----------------
__global__ __launch_bounds__(256) void mm23_kernel(const unsigned short* __restrict__ G,
                                                   const float* __restrict__ W2,
                                                   const float* __restrict__ b2,
                                                   const float* __restrict__ W3,
                                                   float* __restrict__ T, int n) {
    constexpr int HP = 68;
    __shared__ __align__(16) char smem[33792];
    unsigned short* w2s = (unsigned short*)smem;              // phase1: [4][8][64][8] bf16 = 32768 B
    float* HsT = (float*)smem;                                // phase2: [64*HP] = 17408 B
    float* Ws  = (float*)(smem + 64 * HP * 4);                // phase2: [64*64] = 16384 B
    int tid = threadIdx.x;
    int wave = tid >> 6;
    int lane = tid & 63;
    int nodeBase = blockIdx.x * 64;

    // ---- stage swizzled bf16 W2 fragments ----
    for (int slot = tid; slot < 2048; slot += 256) {
        int l = slot & 63;
        int s = (slot >> 6) & 7;
        int t = slot >> 9;
        int k0 = s * 32 + ((l >> 4) << 3);
        int col = t * 16 + (l & 15);
        unsigned short tmp[8];
        #pragma unroll
        for (int j = 0; j < 8; ++j)
            tmp[j] = (unsigned short)bf16rnd(W2[(size_t)(k0 + j) * 64 + col]);
        *reinterpret_cast<uint4*>(w2s + slot * 8) = *reinterpret_cast<const uint4*>(tmp);
    }
    __syncthreads();

    // ---- phase 1: MFMA over K=256 (8 steps), wave owns 16-node strip, 4 n-tiles ----
    int arow = nodeBase + wave * 16 + (lane & 15);
    bool aval = (arow < n);
    const unsigned short* arp = G + (size_t)arow * 256 + ((lane >> 4) << 3);
    f32x4 acc0 = {0.f, 0.f, 0.f, 0.f}, acc1 = {0.f, 0.f, 0.f, 0.f};
    f32x4 acc2 = {0.f, 0.f, 0.f, 0.f}, acc3 = {0.f, 0.f, 0.f, 0.f};
    #pragma unroll
    for (int s = 0; s < 8; ++s) {
        bf16x8 a = {};
        if (aval) a = *reinterpret_cast<const bf16x8*>(arp + s * 32);
        const unsigned short* wb = w2s + ((size_t)s * 64 + lane) * 8;
        bf16x8 bf0 = *reinterpret_cast<const bf16x8*>(wb);
        bf16x8 bf1 = *reinterpret_cast<const bf16x8*>(wb + 4096);
        bf16x8 bf2 = *reinterpret_cast<const bf16x8*>(wb + 8192);
        bf16x8 bf3 = *reinterpret_cast<const bf16x8*>(wb + 12288);
        acc0 = __builtin_amdgcn_mfma_f32_16x16x32_bf16(a, bf0, acc0, 0, 0, 0);
        acc1 = __builtin_amdgcn_mfma_f32_16x16x32_bf16(a, bf1, acc1, 0, 0, 0);
        acc2 = __builtin_amdgcn_mfma_f32_16x16x32_bf16(a, bf2, acc2, 0, 0, 0);
        acc3 = __builtin_amdgcn_mfma_f32_16x16x32_bf16(a, bf3, acc3, 0, 0, 0);
    }
    __syncthreads();   // all waves done reading w2s; LDS re-used below

    // ---- bias+relu epilogue; write h2 k-major into HsT[feature][nodeLocal] ----
    {
        int c = lane & 15;
        int rbase = wave * 16 + (lane >> 4) * 4;
        f32x4 accs[4] = {acc0, acc1, acc2, acc3};
        #pragma unroll
        for (int t = 0; t < 4; ++t) {
            int col = t * 16 + c;
            float bb = b2[col];
            #pragma unroll
            for (int r = 0; r < 4; ++r) {
                float v = accs[t][r] + bb;
                HsT[col * HP + rbase + r] = v > 0.f ? v : 0.f;
            }
        }
    }
    // ---- stage padded W3 (4,64,10) -> 64x64 ----
    for (int i = tid; i < 64 * 64; i += 256) {
        int r = i >> 6, c2 = i & 63;
        int k = c2 >> 4, j = c2 & 15;
        Ws[i] = (j < NOUT) ? W3[((size_t)k * 64 + r) * NOUT + j] : 0.f;
    }
    __syncthreads();

    // ---- phase 2: T = h2 @ W3pad (fp32 VALU) ----
    int ndq = tid >> 4;
    int f4  = tid & 15;
    float4 t0 = make_float4(0.f, 0.f, 0.f, 0.f);
    float4 t1 = make_float4(0.f, 0.f, 0.f, 0.f);
    float4 t2 = make_float4(0.f, 0.f, 0.f, 0.f);
    float4 t3 = make_float4(0.f, 0.f, 0.f, 0.f);
    #pragma unroll 8
    for (int k = 0; k < 64; ++k) {
        const float4 hq = *reinterpret_cast<const float4*>(&HsT[k * HP + ndq * 4]);
        const float4 wq = *reinterpret_cast<const float4*>(&Ws[k * 64 + f4 * 4]);
        t0.x += hq.x * wq.x; t0.y += hq.x * wq.y; t0.z += hq.x * wq.z; t0.w += hq.x * wq.w;
        t1.x += hq.y * wq.x; t1.y += hq.y * wq.y; t1.z += hq.y * wq.z; t1.w += hq.y * wq.w;
        t2.x += hq.z * wq.x; t2.y += hq.z * wq.y; t2.z += hq.z * wq.z; t2.w += hq.z * wq.w;
        t3.x += hq.w * wq.x; t3.y += hq.w * wq.y; t3.z += hq.w * wq.z; t3.w += hq.w * wq.w;
    }
    float4 ts[4] = {t0, t1, t2, t3};
    #pragma unroll
    for (int i = 0; i < 4; ++i) {
        int node = nodeBase + ndq * 4 + i;
        if (node < n)
            *reinterpret_cast<float4*>(T + (size_t)node * 64 + f4 * 4) = ts[i];
    }
}

extern "C" void kernel_launch(void* const* d_in, const int* in_sizes, int n_in,
                              void* d_out, int out_size, void* d_ws, size_t ws_size,
                              hipStream_t stream) {
    const float* x   = (const float*)d_in[0];
    const float* pos = (const float*)d_in[1];
    const float* ea  = (const float*)d_in[2];
    const float* W1  = (const float*)d_in[3];   // (4,8,64) == (32,64)
    const float* b1  = (const float*)d_in[4];
    const float* W2  = (const float*)d_in[5];   // (4,64,64) == (256,64)
    const float* b2  = (const float*)d_in[6];
    const float* W3  = (const float*)d_in[7];   // (4,64,10)
    const float* b3  = (const float*)d_in[8];
    const int* eidx  = (const int*)d_in[9];
    const int* src = eidx;
    const int* dst = eidx + EE;
    float* outp = (float*)d_out;

    size_t off = 0;
    char* base = (char*)d_ws;
    auto alloc = [&](size_t bytes) -> void* {
        void* p = base + off;
        off += (bytes + 255) & ~(size_t)255;
        return p;
    };
    int*   cursor    = (int*)alloc(NB * 4);
    int*   row_start = (int*)alloc((NN + 1) * 4);
    float* dinv      = (float*)alloc(NN * 4);
    int2*  edges     = (int2*)alloc((size_t)NB * CAP * 8);        // strided bucket regions
    unsigned short* G  = (unsigned short*)alloc((size_t)NN * 256 * 2); // bf16 [h1|Ah1|A2h1|A3h1]
    unsigned short* B1 = (unsigned short*)alloc((size_t)NN * 32 * 2);  // bf16 [h0|Ah0|A2h0|A3h0]
    float* T         = (float*)alloc((size_t)NN * 64 * 4);        // layer-3 Horner buffer
    (void)ws_size;

    const int B = 256;
    const int gN = (NN + B - 1) / B;
    const int gK1 = (EE + K1_EPB - 1) / K1_EPB;      // 391
    const int gMM2 = (NN + 63) / 64;                 // 782
    const int gP32 = (NN + 31) / 32;                 // 1563 (TEAM=8,  NPB=32)
    const int gP8  = (NN + 7) / 8;                   // 6250 (TEAM=32, NPB=8)

    hipMemsetAsync(cursor, 0, NB * 4, stream);

    // ---- CSR build (bucketed, atomic-light) ----
    bucket_scatter_kernel<<<gK1, 512, 0, stream>>>(src, dst, ea, cursor, edges, EE);
    bucket_build_kernel<<<NB, 512, 0, stream>>>(cursor, edges, dinv, row_start, NN);

    // ---- layer 1 (bf16): B1 = [h0|Ah0|A2h0|A3h0]; h1 = relu(B1@W1+b1) -> G chunk0 ----
    // hop 1 folds the src-side dinv scaling into edge staging (replaces srcscale).
    pack1_kernel<<<gN, B, 0, stream>>>(x, pos, B1, NN);
    prop8b_kernel<1><<<gP32, B, 0, stream>>>(row_start, cursor, edges, dinv, B1,      B1 + 8,  NN);
    prop8b_kernel<0><<<gP32, B, 0, stream>>>(row_start, cursor, edges, dinv, B1 + 8,  B1 + 16, NN);
    prop8b_kernel<0><<<gP32, B, 0, stream>>>(row_start, cursor, edges, dinv, B1 + 16, B1 + 24, NN);
    mm1_kernel<<<gMM2, B, 0, stream>>>(B1, W1, b1, G, NN);

    // ---- layer 2 (bf16): G chunks 1..3 = A^k h1; T = relu(G@W2+b2) @ W3pad (fused MFMA) ----
    prop64b_kernel<<<gP8, B, 0, stream>>>(row_start, cursor, edges, G,       G + 64,  NN);
    prop64b_kernel<<<gP8, B, 0, stream>>>(row_start, cursor, edges, G + 64,  G + 128, NN);
    prop64b_kernel<<<gP8, B, 0, stream>>>(row_start, cursor, edges, G + 128, G + 192, NN);
    mm23_kernel<<<gMM2, B, 0, stream>>>(G, W2, b2, W3, T, NN);

    // ---- layer 3 (Horner, fp32): t2 = G2 + A*G3 ; t1 = G1 + A*t2 ; out = lsm(G0 + A*t1 + b3) ----
    prop_kernel<4, 2, true><<<gP32, B, 0, stream>>>(row_start, cursor, edges, T + 48, 64, T + 32, 64, NN);
    prop_kernel<4, 2, true><<<gP32, B, 0, stream>>>(row_start, cursor, edges, T + 32, 64, T + 16, 64, NN);
    prop_final_kernel<<<gP32, B, 0, stream>>>(row_start, cursor, edges, T + 16, T, b3, outp, NN);
}

// Round 10
// 262.103 us; speedup vs baseline: 2.6686x; 1.0441x over previous
//
#include <hip/hip_runtime.h>
#include <hip/hip_fp16.h>
#include <math.h>

// TAGConv GNN: N=50000, E=800000, K=3, layers (8->64, 64->64, 64->10)
// v10: 4-byte edge records {src:u16 | fp16(w):u16} for all propagations
// (halves edge traffic, CH=1024 staging); layer-3 props/final at ES=4.
// From v9: bucketed CSR build, bf16 feature chains, MFMA mm1/mm23, Horner L3.

#define NN 50000
#define EE 800000
#define HID 64
#define NOUT 10
#define CH 1024

#define NB 391        // ceil(50000/128) buckets of 128 nodes
#define CAP 2400      // region capacity (mean 2047, +7.8 sigma)
#define K1_EPB 2048   // edges per K1 block (391 blocks)

typedef __attribute__((ext_vector_type(8))) short bf16x8;
typedef __attribute__((ext_vector_type(4))) float f32x4;

// ---------------- bf16 / fp16 helpers ----------------
__device__ __forceinline__ unsigned bf16rnd(float x) {
    unsigned u = __float_as_uint(x);
    return (u + 0x7FFFu + ((u >> 16) & 1u)) >> 16;
}
__device__ __forceinline__ unsigned packbf2(float a, float b) {
    return bf16rnd(a) | (bf16rnd(b) << 16);
}
__device__ __forceinline__ float bflo(unsigned u) { return __uint_as_float(u << 16); }
__device__ __forceinline__ float bfhi(unsigned u) { return __uint_as_float(u & 0xFFFF0000u); }
__device__ __forceinline__ unsigned f16b(float x) {
    __half h = __float2half_rn(x);
    return (unsigned)*reinterpret_cast<unsigned short*>(&h);
}
__device__ __forceinline__ float f16f(unsigned u) {
    unsigned short us = (unsigned short)u;
    __half h = *reinterpret_cast<__half*>(&us);
    return __half2float(h);
}

// ---------------- K1: coarse bucket scatter (391 blocks, reg-cached) ----------------
__global__ __launch_bounds__(512) void bucket_scatter_kernel(
        const int* __restrict__ src, const int* __restrict__ dst,
        const float* __restrict__ ea, int* __restrict__ cursor,
        int2* __restrict__ regions, int e) {
    __shared__ int hist[NB];
    __shared__ int base_s[NB];
    int tid = threadIdx.x;
    int e0 = blockIdx.x * K1_EPB;
    int e1 = e0 + K1_EPB; if (e1 > e) e1 = e;
    int d[4], s[4];
    float w[4];
    int cnt = 0;
    for (int i = e0 + tid; i < e1; i += 512) {
        d[cnt] = dst[i]; s[cnt] = src[i]; w[cnt] = ea[i];
        ++cnt;
    }
    for (int i = tid; i < NB; i += 512) hist[i] = 0;
    __syncthreads();
    for (int j = 0; j < cnt; ++j)
        atomicAdd(&hist[d[j] >> 7], 1);
    __syncthreads();
    for (int b = tid; b < NB; b += 512) {
        int c = hist[b];
        base_s[b] = (c > 0) ? atomicAdd(&cursor[b], c) : 0;
        hist[b] = 0;   // reuse as local cursor
    }
    __syncthreads();
    for (int j = 0; j < cnt; ++j) {
        int b = d[j] >> 7;
        int r = atomicAdd(&hist[b], 1);
        int pos = base_s[b] + r;
        if (pos < CAP)
            regions[(size_t)b * CAP + pos] =
                make_int2(((d[j] & 127) << 16) | s[j], __float_as_int(w[j]));
    }
}

// ---------------- K2: per-bucket fine sort -> row_start, dinv, 4B records ----------------
__global__ __launch_bounds__(512) void bucket_build_kernel(
        const int* __restrict__ cursor, const int2* __restrict__ regions,
        unsigned* __restrict__ erec,
        float* __restrict__ dinv, int* __restrict__ row_start, int n) {
    __shared__ int2 rec[CAP];
    __shared__ int hist[128];
    __shared__ float easum[128];
    __shared__ float dl[128];
    __shared__ int off[129];
    __shared__ int lcur[128];
    int b = blockIdx.x;
    int tid = threadIdx.x;
    int cnt = cursor[b]; if (cnt > CAP) cnt = CAP;
    size_t rb = (size_t)b * CAP;
    if (tid < 128) { hist[tid] = 0; easum[tid] = 0.f; lcur[tid] = 0; }
    __syncthreads();
    for (int i = tid; i < cnt; i += 512) {
        int2 r = regions[rb + i];
        rec[i] = r;
        int f = r.x >> 16;
        atomicAdd(&hist[f], 1);
        atomicAdd(&easum[f], __int_as_float(r.y));
    }
    __syncthreads();
    if (tid < 128) {
        int lane = tid & 63;
        int v = hist[tid];
        for (int o2 = 1; o2 < 64; o2 <<= 1) {
            int y = __shfl_up(v, o2, 64);
            if (lane >= o2) v += y;
        }
        off[tid + 1] = v;     // wave-local inclusive
        float s2 = easum[tid];
        dl[tid] = (s2 > 0.f) ? rsqrtf(s2) : 0.f;
    }
    __syncthreads();
    if (tid == 255) off[0] = 0;
    if (tid >= 64 && tid < 128) off[tid + 1] += off[64];
    __syncthreads();
    if (tid < 128) {
        int node = b * 128 + tid;
        if (node <= n) row_start[node] = b * CAP + off[tid];
        if (node < n)  dinv[node] = dl[tid];
    }
    __syncthreads();
    for (int i = tid; i < cnt; i += 512) {
        int2 r = rec[i];
        int f = r.x >> 16;
        unsigned s = (unsigned)(r.x & 0xFFFF);
        int p = atomicAdd(&lcur[f], 1);
        float w0 = __int_as_float(r.y) * dl[f];
        erec[rb + off[f] + p] = s | (f16b(w0) << 16);
    }
}

// ---------------- pack x,pos -> B1 chunk0 (bf16, stride 32 ushorts) ----------------
__global__ __launch_bounds__(256) void pack1_kernel(const float* __restrict__ x,
                                                    const float* __restrict__ pos,
                                                    unsigned short* __restrict__ B1, int n) {
    int i = blockIdx.x * blockDim.x + threadIdx.x;
    if (i >= n) return;
    float2 a = *reinterpret_cast<const float2*>(x + (size_t)i * 6);
    float2 b = *reinterpret_cast<const float2*>(x + (size_t)i * 6 + 2);
    float2 c = *reinterpret_cast<const float2*>(x + (size_t)i * 6 + 4);
    float2 p = *reinterpret_cast<const float2*>(pos + (size_t)i * 2);
    uint4 o;
    o.x = packbf2(a.x, a.y);
    o.y = packbf2(b.x, b.y);
    o.z = packbf2(c.x, c.y);
    o.w = packbf2(p.x, p.y);
    *reinterpret_cast<uint4*>(B1 + (size_t)i * 32) = o;
}

// ---------------- bf16 width-8 propagation (layer 1): 1 load/edge ----------------
// SCALE=1 (hop 1): staging multiplies w by dinv[src] and writes back.
template <int SCALE>
__global__ __launch_bounds__(256) void prop8b_kernel(const int* __restrict__ row_start,
                                                     const int* __restrict__ cursor,
                                                     unsigned* __restrict__ erec,
                                                     const float* __restrict__ dinv,
                                                     const unsigned short* __restrict__ Gin,
                                                     unsigned short* __restrict__ Gout, int n) {
    constexpr int TEAM = 8, NPB = 32;
    __shared__ unsigned se[CH];
    int tid = threadIdx.x;
    int nb = blockIdx.x * NPB;
    int node = nb + tid / TEAM;
    int es = tid % TEAM;
    int nbEnd = (nb + NPB < n) ? (nb + NPB) : n;
    int bkt = nb >> 7;
    int cc = cursor[bkt]; if (cc > CAP) cc = CAP;
    int ce = bkt * CAP + cc;
    int blkBeg = row_start[nb];
    int blkEnd = row_start[nbEnd]; if (blkEnd > ce) blkEnd = ce;
    int beg = 0, end = 0;
    if (node < n) {
        beg = row_start[node];
        end = row_start[node + 1]; if (end > ce) end = ce;
    }
    float a0 = 0.f, a1 = 0.f, a2 = 0.f, a3 = 0.f, a4 = 0.f, a5 = 0.f, a6 = 0.f, a7 = 0.f;
    for (int base = blkBeg; base < blkEnd; base += CH) {
        int m = blkEnd - base; if (m > CH) m = CH;
        __syncthreads();
        for (int i = tid; i < m; i += 256) {
            unsigned r = erec[base + i];
            if (SCALE) {
                float w = f16f(r >> 16) * dinv[r & 0xFFFF];
                r = (r & 0xFFFFu) | (f16b(w) << 16);
                erec[base + i] = r;
            }
            se[i] = r;
        }
        __syncthreads();
        int lo = (beg > base) ? (beg - base) : 0;
        int hi = ((end < base + m) ? end : (base + m)) - base;
        for (int i = lo + es; i < hi; i += TEAM) {
            unsigned e = se[i];
            float w = f16f(e >> 16);
            const uint4 v = *reinterpret_cast<const uint4*>(Gin + (size_t)(e & 0xFFFF) * 32);
            a0 += w * bflo(v.x); a1 += w * bfhi(v.x);
            a2 += w * bflo(v.y); a3 += w * bfhi(v.y);
            a4 += w * bflo(v.z); a5 += w * bfhi(v.z);
            a6 += w * bflo(v.w); a7 += w * bfhi(v.w);
        }
    }
    #pragma unroll
    for (int msk = 1; msk < TEAM; msk <<= 1) {
        a0 += __shfl_xor(a0, msk); a1 += __shfl_xor(a1, msk);
        a2 += __shfl_xor(a2, msk); a3 += __shfl_xor(a3, msk);
        a4 += __shfl_xor(a4, msk); a5 += __shfl_xor(a5, msk);
        a6 += __shfl_xor(a6, msk); a7 += __shfl_xor(a7, msk);
    }
    if (node < n && es == 0) {
        uint4 o;
        o.x = packbf2(a0, a1);
        o.y = packbf2(a2, a3);
        o.z = packbf2(a4, a5);
        o.w = packbf2(a6, a7);
        *reinterpret_cast<uint4*>(Gout + (size_t)node * 32) = o;
    }
}

// ---------------- fp32 propagation (layer 3) ----------------
template <int TPN, int ES, bool ACC>
__global__ __launch_bounds__(256) void prop_kernel(const int* __restrict__ row_start,
                                                   const int* __restrict__ cursor,
                                                   const unsigned* __restrict__ erec,
                                                   const float* __restrict__ hin, int in_stride,
                                                   float* __restrict__ hout, int out_stride, int n) {
    constexpr int TEAM = TPN * ES;
    constexpr int NPB = 256 / TEAM;
    __shared__ unsigned se[CH];
    int tid = threadIdx.x;
    int nb = blockIdx.x * NPB;
    int node = nb + tid / TEAM;
    int t = tid % TEAM;
    int es = t / TPN;
    int lane = t % TPN;
    int nbEnd = (nb + NPB < n) ? (nb + NPB) : n;
    int bkt = nb >> 7;
    int cc = cursor[bkt]; if (cc > CAP) cc = CAP;
    int ce = bkt * CAP + cc;
    int blkBeg = row_start[nb];
    int blkEnd = row_start[nbEnd]; if (blkEnd > ce) blkEnd = ce;
    int beg = 0, end = 0;
    if (node < n) {
        beg = row_start[node];
        end = row_start[node + 1]; if (end > ce) end = ce;
    }
    float ax = 0.f, ay = 0.f, az = 0.f, aw = 0.f;
    for (int base = blkBeg; base < blkEnd; base += CH) {
        int m = blkEnd - base; if (m > CH) m = CH;
        __syncthreads();
        for (int i = tid; i < m; i += 256) se[i] = erec[base + i];
        __syncthreads();
        int lo = (beg > base) ? (beg - base) : 0;
        int hi = ((end < base + m) ? end : (base + m)) - base;
        for (int i = lo + es; i < hi; i += ES) {
            unsigned e = se[i];
            float w = f16f(e >> 16);
            const float4 v = *reinterpret_cast<const float4*>(hin + (size_t)(e & 0xFFFF) * in_stride + lane * 4);
            ax += w * v.x; ay += w * v.y; az += w * v.z; aw += w * v.w;
        }
    }
    #pragma unroll
    for (int msk = TPN; msk < TEAM; msk <<= 1) {
        ax += __shfl_xor(ax, msk);
        ay += __shfl_xor(ay, msk);
        az += __shfl_xor(az, msk);
        aw += __shfl_xor(aw, msk);
    }
    if (node < n && es == 0) {
        float4* po = reinterpret_cast<float4*>(hout + (size_t)node * out_stride + lane * 4);
        float4 r = make_float4(ax, ay, az, aw);
        if (ACC) { float4 o = *po; r.x += o.x; r.y += o.y; r.z += o.z; r.w += o.w; }
        *po = r;
    }
}

// ---------------- bf16 width-64 propagation (layer 2): Gout = A * Gin ----------------
__global__ __launch_bounds__(256) void prop64b_kernel(const int* __restrict__ row_start,
                                                      const int* __restrict__ cursor,
                                                      const unsigned* __restrict__ erec,
                                                      const unsigned short* __restrict__ Gin,
                                                      unsigned short* __restrict__ Gout, int n) {
    constexpr int TPN = 8, ES = 4, TEAM = 32, NPB = 8;
    __shared__ unsigned se[CH];
    int tid = threadIdx.x;
    int nb = blockIdx.x * NPB;
    int node = nb + tid / TEAM;
    int t = tid % TEAM;
    int es = t / TPN;
    int lane = t % TPN;
    int nbEnd = (nb + NPB < n) ? (nb + NPB) : n;
    int bkt = nb >> 7;
    int cc = cursor[bkt]; if (cc > CAP) cc = CAP;
    int ce = bkt * CAP + cc;
    int blkBeg = row_start[nb];
    int blkEnd = row_start[nbEnd]; if (blkEnd > ce) blkEnd = ce;
    int beg = 0, end = 0;
    if (node < n) {
        beg = row_start[node];
        end = row_start[node + 1]; if (end > ce) end = ce;
    }
    float a0 = 0.f, a1 = 0.f, a2 = 0.f, a3 = 0.f, a4 = 0.f, a5 = 0.f, a6 = 0.f, a7 = 0.f;
    for (int base = blkBeg; base < blkEnd; base += CH) {
        int m = blkEnd - base; if (m > CH) m = CH;
        __syncthreads();
        for (int i = tid; i < m; i += 256) se[i] = erec[base + i];
        __syncthreads();
        int lo = (beg > base) ? (beg - base) : 0;
        int hi = ((end < base + m) ? end : (base + m)) - base;
        for (int i = lo + es; i < hi; i += ES) {
            unsigned e = se[i];
            float w = f16f(e >> 16);
            const uint4 v = *reinterpret_cast<const uint4*>(Gin + (size_t)(e & 0xFFFF) * 256 + lane * 8);
            a0 += w * bflo(v.x); a1 += w * bfhi(v.x);
            a2 += w * bflo(v.y); a3 += w * bfhi(v.y);
            a4 += w * bflo(v.z); a5 += w * bfhi(v.z);
            a6 += w * bflo(v.w); a7 += w * bfhi(v.w);
        }
    }
    #pragma unroll
    for (int msk = TPN; msk < TEAM; msk <<= 1) {
        a0 += __shfl_xor(a0, msk); a1 += __shfl_xor(a1, msk);
        a2 += __shfl_xor(a2, msk); a3 += __shfl_xor(a3, msk);
        a4 += __shfl_xor(a4, msk); a5 += __shfl_xor(a5, msk);
        a6 += __shfl_xor(a6, msk); a7 += __shfl_xor(a7, msk);
    }
    if (node < n && es == 0) {
        uint4 o;
        o.x = packbf2(a0, a1);
        o.y = packbf2(a2, a3);
        o.z = packbf2(a4, a5);
        o.w = packbf2(a6, a7);
        *reinterpret_cast<uint4*>(Gout + (size_t)node * 256 + lane * 8) = o;
    }
}

// ---------------- final prop: out = log_softmax(g0 + A*t1 + b3) ----------------
__global__ __launch_bounds__(256) void prop_final_kernel(const int* __restrict__ row_start,
                                                         const int* __restrict__ cursor,
                                                         const unsigned* __restrict__ erec,
                                                         const float* __restrict__ hin,
                                                         const float* __restrict__ g0,
                                                         const float* __restrict__ b3,
                                                         float* __restrict__ out, int n) {
    constexpr int TPN = 4, ES = 4, TEAM = 16, NPB = 16;
    __shared__ unsigned se[CH];
    int tid = threadIdx.x;
    int nb = blockIdx.x * NPB;
    int node = nb + tid / TEAM;
    int t = tid % TEAM;
    int es = t / TPN;
    int lane = t % TPN;
    int nbEnd = (nb + NPB < n) ? (nb + NPB) : n;
    int bkt = nb >> 7;
    int cc = cursor[bkt]; if (cc > CAP) cc = CAP;
    int ce = bkt * CAP + cc;
    int blkBeg = row_start[nb];
    int blkEnd = row_start[nbEnd]; if (blkEnd > ce) blkEnd = ce;
    int beg = 0, end = 0;
    if (node < n) {
        beg = row_start[node];
        end = row_start[node + 1]; if (end > ce) end = ce;
    }
    float ax = 0.f, ay = 0.f, az = 0.f, aw = 0.f;
    for (int base = blkBeg; base < blkEnd; base += CH) {
        int m = blkEnd - base; if (m > CH) m = CH;
        __syncthreads();
        for (int i = tid; i < m; i += 256) se[i] = erec[base + i];
        __syncthreads();
        int lo = (beg > base) ? (beg - base) : 0;
        int hi = ((end < base + m) ? end : (base + m)) - base;
        for (int i = lo + es; i < hi; i += ES) {
            unsigned e = se[i];
            float w = f16f(e >> 16);
            const float4 v = *reinterpret_cast<const float4*>(hin + (size_t)(e & 0xFFFF) * 64 + lane * 4);
            ax += w * v.x; ay += w * v.y; az += w * v.z; aw += w * v.w;
        }
    }
    #pragma unroll
    for (int msk = TPN; msk < TEAM; msk <<= 1) {
        ax += __shfl_xor(ax, msk);
        ay += __shfl_xor(ay, msk);
        az += __shfl_xor(az, msk);
        aw += __shfl_xor(aw, msk);
    }
    if (node < n && es == 0) {
        const float4 g = *reinterpret_cast<const float4*>(g0 + (size_t)node * 64 + lane * 4);
        float vv[4] = {ax + g.x, ay + g.y, az + g.z, aw + g.w};
        int c0 = lane * 4;
        float mloc = -1e30f;
        #pragma unroll
        for (int c = 0; c < 4; ++c) {
            int col = c0 + c;
            if (col < NOUT) { vv[c] += b3[col]; mloc = fmaxf(mloc, vv[c]); }
        }
        float mo = fmaxf(mloc, __shfl_xor(mloc, 1));
        mo = fmaxf(mo, __shfl_xor(mo, 2));
        float sl = 0.f;
        #pragma unroll
        for (int c = 0; c < 4; ++c) {
            int col = c0 + c;
            if (col < NOUT) sl += __expf(vv[c] - mo);
        }
        sl += __shfl_xor(sl, 1);
        sl += __shfl_xor(sl, 2);
        float ls = __logf(sl);
        #pragma unroll
        for (int c = 0; c < 4; ++c) {
            int col = c0 + c;
            if (col < NOUT) out[(size_t)node * NOUT + col] = vv[c] - mo - ls;
        }
    }
}

// ---------------- MFMA layer-1 matmul: G0 = relu(B1 @ W1 + b1) as bf16 ----------------
__global__ __launch_bounds__(256) void mm1_kernel(const unsigned short* __restrict__ B1,
                                                  const float* __restrict__ W1,
                                                  const float* __restrict__ b1,
                                                  unsigned short* __restrict__ G, int n) {
    __shared__ unsigned short w1s[2048];   // [t(4)][lane(64)][8] bf16 = 4 KB
    __shared__ unsigned short hs[64 * 64]; // h1 tile bf16 [nodeLocal][col] = 8 KB
    int tid = threadIdx.x;
    int wave = tid >> 6;
    int lane = tid & 63;
    int nodeBase = blockIdx.x * 64;

    {
        int l = tid & 63;
        int t = tid >> 6;
        int k0 = (l >> 4) << 3;
        int col = t * 16 + (l & 15);
        unsigned short tmp[8];
        #pragma unroll
        for (int j = 0; j < 8; ++j)
            tmp[j] = (unsigned short)bf16rnd(W1[(size_t)(k0 + j) * 64 + col]);
        *reinterpret_cast<uint4*>(w1s + tid * 8) = *reinterpret_cast<const uint4*>(tmp);
    }
    __syncthreads();

    int arow = nodeBase + wave * 16 + (lane & 15);
    bf16x8 a = {};
    if (arow < n)
        a = *reinterpret_cast<const bf16x8*>(B1 + (size_t)arow * 32 + ((lane >> 4) << 3));
    const unsigned short* wb = w1s + lane * 8;
    f32x4 acc0 = {0.f, 0.f, 0.f, 0.f}, acc1 = {0.f, 0.f, 0.f, 0.f};
    f32x4 acc2 = {0.f, 0.f, 0.f, 0.f}, acc3 = {0.f, 0.f, 0.f, 0.f};
    acc0 = __builtin_amdgcn_mfma_f32_16x16x32_bf16(a, *reinterpret_cast<const bf16x8*>(wb),        acc0, 0, 0, 0);
    acc1 = __builtin_amdgcn_mfma_f32_16x16x32_bf16(a, *reinterpret_cast<const bf16x8*>(wb + 512),  acc1, 0, 0, 0);
    acc2 = __builtin_amdgcn_mfma_f32_16x16x32_bf16(a, *reinterpret_cast<const bf16x8*>(wb + 1024), acc2, 0, 0, 0);
    acc3 = __builtin_amdgcn_mfma_f32_16x16x32_bf16(a, *reinterpret_cast<const bf16x8*>(wb + 1536), acc3, 0, 0, 0);

    {
        int c = lane & 15;
        int rbase = wave * 16 + (lane >> 4) * 4;
        f32x4 accs[4] = {acc0, acc1, acc2, acc3};
        #pragma unroll
        for (int t = 0; t < 4; ++t) {
            int col = t * 16 + c;
            float bb = b1[col];
            #pragma unroll
            for (int r = 0; r < 4; ++r) {
                float v = accs[t][r] + bb;
                hs[(rbase + r) * 64 + col] = (unsigned short)bf16rnd(v > 0.f ? v : 0.f);
            }
        }
    }
    __syncthreads();
    for (int i = tid; i < 512; i += 256) {
        int nd = i >> 3, ch = i & 7;
        int node = nodeBase + nd;
        if (node < n)
            *reinterpret_cast<uint4*>(G + (size_t)node * 256 + ch * 8) =
                *reinterpret_cast<const uint4*>(hs + nd * 64 + ch * 8);
    }
}

// ---------------- fused mm2+mm3 with MFMA phase 1 ----------------
__global__ __launch_bounds__(256) void mm23_kernel(const unsigned short* __restrict__ G,
                                                   const float* __restrict__ W2,
                                                   const float* __restrict__ b2,
                                                   const float* __restrict__ W3,
                                                   float* __restrict__ T, int n) {
    constexpr int HP = 68;
    __shared__ __align__(16) char smem[33792];
    unsigned short* w2s = (unsigned short*)smem;              // phase1: 32768 B
    float* HsT = (float*)smem;                                // phase2: 17408 B
    float* Ws  = (float*)(smem + 64 * HP * 4);                // phase2: 16384 B
    int tid = threadIdx.x;
    int wave = tid >> 6;
    int lane = tid & 63;
    int nodeBase = blockIdx.x * 64;

    for (int slot = tid; slot < 2048; slot += 256) {
        int l = slot & 63;
        int s = (slot >> 6) & 7;
        int t = slot >> 9;
        int k0 = s * 32 + ((l >> 4) << 3);
        int col = t * 16 + (l & 15);
        unsigned short tmp[8];
        #pragma unroll
        for (int j = 0; j < 8; ++j)
            tmp[j] = (unsigned short)bf16rnd(W2[(size_t)(k0 + j) * 64 + col]);
        *reinterpret_cast<uint4*>(w2s + slot * 8) = *reinterpret_cast<const uint4*>(tmp);
    }
    __syncthreads();

    int arow = nodeBase + wave * 16 + (lane & 15);
    bool aval = (arow < n);
    const unsigned short* arp = G + (size_t)arow * 256 + ((lane >> 4) << 3);
    f32x4 acc0 = {0.f, 0.f, 0.f, 0.f}, acc1 = {0.f, 0.f, 0.f, 0.f};
    f32x4 acc2 = {0.f, 0.f, 0.f, 0.f}, acc3 = {0.f, 0.f, 0.f, 0.f};
    #pragma unroll
    for (int s = 0; s < 8; ++s) {
        bf16x8 a = {};
        if (aval) a = *reinterpret_cast<const bf16x8*>(arp + s * 32);
        const unsigned short* wb = w2s + ((size_t)s * 64 + lane) * 8;
        bf16x8 bf0 = *reinterpret_cast<const bf16x8*>(wb);
        bf16x8 bf1 = *reinterpret_cast<const bf16x8*>(wb + 4096);
        bf16x8 bf2 = *reinterpret_cast<const bf16x8*>(wb + 8192);
        bf16x8 bf3 = *reinterpret_cast<const bf16x8*>(wb + 12288);
        acc0 = __builtin_amdgcn_mfma_f32_16x16x32_bf16(a, bf0, acc0, 0, 0, 0);
        acc1 = __builtin_amdgcn_mfma_f32_16x16x32_bf16(a, bf1, acc1, 0, 0, 0);
        acc2 = __builtin_amdgcn_mfma_f32_16x16x32_bf16(a, bf2, acc2, 0, 0, 0);
        acc3 = __builtin_amdgcn_mfma_f32_16x16x32_bf16(a, bf3, acc3, 0, 0, 0);
    }
    __syncthreads();

    {
        int c = lane & 15;
        int rbase = wave * 16 + (lane >> 4) * 4;
        f32x4 accs[4] = {acc0, acc1, acc2, acc3};
        #pragma unroll
        for (int t = 0; t < 4; ++t) {
            int col = t * 16 + c;
            float bb = b2[col];
            #pragma unroll
            for (int r = 0; r < 4; ++r) {
                float v = accs[t][r] + bb;
                HsT[col * HP + rbase + r] = v > 0.f ? v : 0.f;
            }
        }
    }
    for (int i = tid; i < 64 * 64; i += 256) {
        int r = i >> 6, c2 = i & 63;
        int k = c2 >> 4, j = c2 & 15;
        Ws[i] = (j < NOUT) ? W3[((size_t)k * 64 + r) * NOUT + j] : 0.f;
    }
    __syncthreads();

    int ndq = tid >> 4;
    int f4  = tid & 15;
    float4 t0 = make_float4(0.f, 0.f, 0.f, 0.f);
    float4 t1 = make_float4(0.f, 0.f, 0.f, 0.f);
    float4 t2 = make_float4(0.f, 0.f, 0.f, 0.f);
    float4 t3 = make_float4(0.f, 0.f, 0.f, 0.f);
    #pragma unroll 8
    for (int k = 0; k < 64; ++k) {
        const float4 hq = *reinterpret_cast<const float4*>(&HsT[k * HP + ndq * 4]);
        const float4 wq = *reinterpret_cast<const float4*>(&Ws[k * 64 + f4 * 4]);
        t0.x += hq.x * wq.x; t0.y += hq.x * wq.y; t0.z += hq.x * wq.z; t0.w += hq.x * wq.w;
        t1.x += hq.y * wq.x; t1.y += hq.y * wq.y; t1.z += hq.y * wq.z; t1.w += hq.y * wq.w;
        t2.x += hq.z * wq.x; t2.y += hq.z * wq.y; t2.z += hq.z * wq.z; t2.w += hq.z * wq.w;
        t3.x += hq.w * wq.x; t3.y += hq.w * wq.y; t3.z += hq.w * wq.z; t3.w += hq.w * wq.w;
    }
    float4 ts[4] = {t0, t1, t2, t3};
    #pragma unroll
    for (int i = 0; i < 4; ++i) {
        int node = nodeBase + ndq * 4 + i;
        if (node < n)
            *reinterpret_cast<float4*>(T + (size_t)node * 64 + f4 * 4) = ts[i];
    }
}

extern "C" void kernel_launch(void* const* d_in, const int* in_sizes, int n_in,
                              void* d_out, int out_size, void* d_ws, size_t ws_size,
                              hipStream_t stream) {
    const float* x   = (const float*)d_in[0];
    const float* pos = (const float*)d_in[1];
    const float* ea  = (const float*)d_in[2];
    const float* W1  = (const float*)d_in[3];   // (4,8,64) == (32,64)
    const float* b1  = (const float*)d_in[4];
    const float* W2  = (const float*)d_in[5];   // (4,64,64) == (256,64)
    const float* b2  = (const float*)d_in[6];
    const float* W3  = (const float*)d_in[7];   // (4,64,10)
    const float* b3  = (const float*)d_in[8];
    const int* eidx  = (const int*)d_in[9];
    const int* src = eidx;
    const int* dst = eidx + EE;
    float* outp = (float*)d_out;

    size_t off = 0;
    char* base = (char*)d_ws;
    auto alloc = [&](size_t bytes) -> void* {
        void* p = base + off;
        off += (bytes + 255) & ~(size_t)255;
        return p;
    };
    int*   cursor    = (int*)alloc(NB * 4);
    int*   row_start = (int*)alloc((NN + 1) * 4);
    float* dinv      = (float*)alloc(NN * 4);
    int2*  regions   = (int2*)alloc((size_t)NB * CAP * 8);        // 8B scatter records
    unsigned* erec   = (unsigned*)alloc((size_t)NB * CAP * 4);    // 4B final records
    unsigned short* G  = (unsigned short*)alloc((size_t)NN * 256 * 2); // bf16 [h1|Ah1|A2h1|A3h1]
    unsigned short* B1 = (unsigned short*)alloc((size_t)NN * 32 * 2);  // bf16 [h0|Ah0|A2h0|A3h0]
    float* T         = (float*)alloc((size_t)NN * 64 * 4);        // layer-3 Horner buffer
    (void)ws_size;

    const int B = 256;
    const int gN = (NN + B - 1) / B;
    const int gK1 = (EE + K1_EPB - 1) / K1_EPB;      // 391
    const int gMM2 = (NN + 63) / 64;                 // 782
    const int gP32 = (NN + 31) / 32;                 // 1563 (TEAM=8,  NPB=32)
    const int gP16 = (NN + 15) / 16;                 // 3125 (TEAM=16, NPB=16)
    const int gP8  = (NN + 7) / 8;                   // 6250 (TEAM=32, NPB=8)

    hipMemsetAsync(cursor, 0, NB * 4, stream);

    // ---- CSR build (bucketed, atomic-light) ----
    bucket_scatter_kernel<<<gK1, 512, 0, stream>>>(src, dst, ea, cursor, regions, EE);
    bucket_build_kernel<<<NB, 512, 0, stream>>>(cursor, regions, erec, dinv, row_start, NN);

    // ---- layer 1 (bf16): B1 = [h0|Ah0|A2h0|A3h0]; h1 = relu(B1@W1+b1) -> G chunk0 ----
    pack1_kernel<<<gN, B, 0, stream>>>(x, pos, B1, NN);
    prop8b_kernel<1><<<gP32, B, 0, stream>>>(row_start, cursor, erec, dinv, B1,      B1 + 8,  NN);
    prop8b_kernel<0><<<gP32, B, 0, stream>>>(row_start, cursor, erec, dinv, B1 + 8,  B1 + 16, NN);
    prop8b_kernel<0><<<gP32, B, 0, stream>>>(row_start, cursor, erec, dinv, B1 + 16, B1 + 24, NN);
    mm1_kernel<<<gMM2, B, 0, stream>>>(B1, W1, b1, G, NN);

    // ---- layer 2 (bf16): G chunks 1..3 = A^k h1; T = relu(G@W2+b2) @ W3pad (fused MFMA) ----
    prop64b_kernel<<<gP8, B, 0, stream>>>(row_start, cursor, erec, G,       G + 64,  NN);
    prop64b_kernel<<<gP8, B, 0, stream>>>(row_start, cursor, erec, G + 64,  G + 128, NN);
    prop64b_kernel<<<gP8, B, 0, stream>>>(row_start, cursor, erec, G + 128, G + 192, NN);
    mm23_kernel<<<gMM2, B, 0, stream>>>(G, W2, b2, W3, T, NN);

    // ---- layer 3 (Horner, fp32): t2 = G2 + A*G3 ; t1 = G1 + A*t2 ; out = lsm(G0 + A*t1 + b3) ----
    prop_kernel<4, 4, true><<<gP16, B, 0, stream>>>(row_start, cursor, erec, T + 48, 64, T + 32, 64, NN);
    prop_kernel<4, 4, true><<<gP16, B, 0, stream>>>(row_start, cursor, erec, T + 32, 64, T + 16, 64, NN);
    prop_final_kernel<<<gP16, B, 0, stream>>>(row_start, cursor, erec, T + 16, T, b3, outp, NN);
}

// Round 11
// 252.279 us; speedup vs baseline: 2.7725x; 1.0389x over previous
//
#include <hip/hip_runtime.h>
#include <hip/hip_fp16.h>
#include <math.h>

// TAGConv GNN: N=50000, E=800000, K=3, layers (8->64, 64->64, 64->10)
// v11: layer-3 Horner chain repacked to contiguous N x 16 bf16 chunks
// (1.6 MB L2-resident gather table, 32B/edge instead of 64B over 12.8MB);
// fused bf16 Horner props + final log-softmax. Rest identical to v10.

#define NN 50000
#define EE 800000
#define HID 64
#define NOUT 10
#define CH 1024

#define NB 391        // ceil(50000/128) buckets of 128 nodes
#define CAP 2400      // region capacity (mean 2047, +7.8 sigma)
#define K1_EPB 2048   // edges per K1 block (391 blocks)
#define N16 ((size_t)NN * 16)

typedef __attribute__((ext_vector_type(8))) short bf16x8;
typedef __attribute__((ext_vector_type(4))) float f32x4;

// ---------------- bf16 / fp16 helpers ----------------
__device__ __forceinline__ unsigned bf16rnd(float x) {
    unsigned u = __float_as_uint(x);
    return (u + 0x7FFFu + ((u >> 16) & 1u)) >> 16;
}
__device__ __forceinline__ unsigned packbf2(float a, float b) {
    return bf16rnd(a) | (bf16rnd(b) << 16);
}
__device__ __forceinline__ float bflo(unsigned u) { return __uint_as_float(u << 16); }
__device__ __forceinline__ float bfhi(unsigned u) { return __uint_as_float(u & 0xFFFF0000u); }
__device__ __forceinline__ unsigned f16b(float x) {
    __half h = __float2half_rn(x);
    return (unsigned)*reinterpret_cast<unsigned short*>(&h);
}
__device__ __forceinline__ float f16f(unsigned u) {
    unsigned short us = (unsigned short)u;
    __half h = *reinterpret_cast<__half*>(&us);
    return __half2float(h);
}

// ---------------- K1: coarse bucket scatter (391 blocks, reg-cached) ----------------
__global__ __launch_bounds__(512) void bucket_scatter_kernel(
        const int* __restrict__ src, const int* __restrict__ dst,
        const float* __restrict__ ea, int* __restrict__ cursor,
        int2* __restrict__ regions, int e) {
    __shared__ int hist[NB];
    __shared__ int base_s[NB];
    int tid = threadIdx.x;
    int e0 = blockIdx.x * K1_EPB;
    int e1 = e0 + K1_EPB; if (e1 > e) e1 = e;
    int d[4], s[4];
    float w[4];
    int cnt = 0;
    for (int i = e0 + tid; i < e1; i += 512) {
        d[cnt] = dst[i]; s[cnt] = src[i]; w[cnt] = ea[i];
        ++cnt;
    }
    for (int i = tid; i < NB; i += 512) hist[i] = 0;
    __syncthreads();
    for (int j = 0; j < cnt; ++j)
        atomicAdd(&hist[d[j] >> 7], 1);
    __syncthreads();
    for (int b = tid; b < NB; b += 512) {
        int c = hist[b];
        base_s[b] = (c > 0) ? atomicAdd(&cursor[b], c) : 0;
        hist[b] = 0;   // reuse as local cursor
    }
    __syncthreads();
    for (int j = 0; j < cnt; ++j) {
        int b = d[j] >> 7;
        int r = atomicAdd(&hist[b], 1);
        int pos = base_s[b] + r;
        if (pos < CAP)
            regions[(size_t)b * CAP + pos] =
                make_int2(((d[j] & 127) << 16) | s[j], __float_as_int(w[j]));
    }
}

// ---------------- K2: per-bucket fine sort -> row_start, dinv, 4B records ----------------
__global__ __launch_bounds__(512) void bucket_build_kernel(
        const int* __restrict__ cursor, const int2* __restrict__ regions,
        unsigned* __restrict__ erec,
        float* __restrict__ dinv, int* __restrict__ row_start, int n) {
    __shared__ int2 rec[CAP];
    __shared__ int hist[128];
    __shared__ float easum[128];
    __shared__ float dl[128];
    __shared__ int off[129];
    __shared__ int lcur[128];
    int b = blockIdx.x;
    int tid = threadIdx.x;
    int cnt = cursor[b]; if (cnt > CAP) cnt = CAP;
    size_t rb = (size_t)b * CAP;
    if (tid < 128) { hist[tid] = 0; easum[tid] = 0.f; lcur[tid] = 0; }
    __syncthreads();
    for (int i = tid; i < cnt; i += 512) {
        int2 r = regions[rb + i];
        rec[i] = r;
        int f = r.x >> 16;
        atomicAdd(&hist[f], 1);
        atomicAdd(&easum[f], __int_as_float(r.y));
    }
    __syncthreads();
    if (tid < 128) {
        int lane = tid & 63;
        int v = hist[tid];
        for (int o2 = 1; o2 < 64; o2 <<= 1) {
            int y = __shfl_up(v, o2, 64);
            if (lane >= o2) v += y;
        }
        off[tid + 1] = v;     // wave-local inclusive
        float s2 = easum[tid];
        dl[tid] = (s2 > 0.f) ? rsqrtf(s2) : 0.f;
    }
    __syncthreads();
    if (tid == 255) off[0] = 0;
    if (tid >= 64 && tid < 128) off[tid + 1] += off[64];
    __syncthreads();
    if (tid < 128) {
        int node = b * 128 + tid;
        if (node <= n) row_start[node] = b * CAP + off[tid];
        if (node < n)  dinv[node] = dl[tid];
    }
    __syncthreads();
    for (int i = tid; i < cnt; i += 512) {
        int2 r = rec[i];
        int f = r.x >> 16;
        unsigned s = (unsigned)(r.x & 0xFFFF);
        int p = atomicAdd(&lcur[f], 1);
        float w0 = __int_as_float(r.y) * dl[f];
        erec[rb + off[f] + p] = s | (f16b(w0) << 16);
    }
}

// ---------------- pack x,pos -> B1 chunk0 (bf16, stride 32 ushorts) ----------------
__global__ __launch_bounds__(256) void pack1_kernel(const float* __restrict__ x,
                                                    const float* __restrict__ pos,
                                                    unsigned short* __restrict__ B1, int n) {
    int i = blockIdx.x * blockDim.x + threadIdx.x;
    if (i >= n) return;
    float2 a = *reinterpret_cast<const float2*>(x + (size_t)i * 6);
    float2 b = *reinterpret_cast<const float2*>(x + (size_t)i * 6 + 2);
    float2 c = *reinterpret_cast<const float2*>(x + (size_t)i * 6 + 4);
    float2 p = *reinterpret_cast<const float2*>(pos + (size_t)i * 2);
    uint4 o;
    o.x = packbf2(a.x, a.y);
    o.y = packbf2(b.x, b.y);
    o.z = packbf2(c.x, c.y);
    o.w = packbf2(p.x, p.y);
    *reinterpret_cast<uint4*>(B1 + (size_t)i * 32) = o;
}

// ---------------- bf16 width-8 propagation (layer 1): 1 load/edge ----------------
// SCALE=1 (hop 1): staging multiplies w by dinv[src] and writes back.
template <int SCALE>
__global__ __launch_bounds__(256) void prop8b_kernel(const int* __restrict__ row_start,
                                                     const int* __restrict__ cursor,
                                                     unsigned* __restrict__ erec,
                                                     const float* __restrict__ dinv,
                                                     const unsigned short* __restrict__ Gin,
                                                     unsigned short* __restrict__ Gout, int n) {
    constexpr int TEAM = 8, NPB = 32;
    __shared__ unsigned se[CH];
    int tid = threadIdx.x;
    int nb = blockIdx.x * NPB;
    int node = nb + tid / TEAM;
    int es = tid % TEAM;
    int nbEnd = (nb + NPB < n) ? (nb + NPB) : n;
    int bkt = nb >> 7;
    int cc = cursor[bkt]; if (cc > CAP) cc = CAP;
    int ce = bkt * CAP + cc;
    int blkBeg = row_start[nb];
    int blkEnd = row_start[nbEnd]; if (blkEnd > ce) blkEnd = ce;
    int beg = 0, end = 0;
    if (node < n) {
        beg = row_start[node];
        end = row_start[node + 1]; if (end > ce) end = ce;
    }
    float a0 = 0.f, a1 = 0.f, a2 = 0.f, a3 = 0.f, a4 = 0.f, a5 = 0.f, a6 = 0.f, a7 = 0.f;
    for (int base = blkBeg; base < blkEnd; base += CH) {
        int m = blkEnd - base; if (m > CH) m = CH;
        __syncthreads();
        for (int i = tid; i < m; i += 256) {
            unsigned r = erec[base + i];
            if (SCALE) {
                float w = f16f(r >> 16) * dinv[r & 0xFFFF];
                r = (r & 0xFFFFu) | (f16b(w) << 16);
                erec[base + i] = r;
            }
            se[i] = r;
        }
        __syncthreads();
        int lo = (beg > base) ? (beg - base) : 0;
        int hi = ((end < base + m) ? end : (base + m)) - base;
        for (int i = lo + es; i < hi; i += TEAM) {
            unsigned e = se[i];
            float w = f16f(e >> 16);
            const uint4 v = *reinterpret_cast<const uint4*>(Gin + (size_t)(e & 0xFFFF) * 32);
            a0 += w * bflo(v.x); a1 += w * bfhi(v.x);
            a2 += w * bflo(v.y); a3 += w * bfhi(v.y);
            a4 += w * bflo(v.z); a5 += w * bfhi(v.z);
            a6 += w * bflo(v.w); a7 += w * bfhi(v.w);
        }
    }
    #pragma unroll
    for (int msk = 1; msk < TEAM; msk <<= 1) {
        a0 += __shfl_xor(a0, msk); a1 += __shfl_xor(a1, msk);
        a2 += __shfl_xor(a2, msk); a3 += __shfl_xor(a3, msk);
        a4 += __shfl_xor(a4, msk); a5 += __shfl_xor(a5, msk);
        a6 += __shfl_xor(a6, msk); a7 += __shfl_xor(a7, msk);
    }
    if (node < n && es == 0) {
        uint4 o;
        o.x = packbf2(a0, a1);
        o.y = packbf2(a2, a3);
        o.z = packbf2(a4, a5);
        o.w = packbf2(a6, a7);
        *reinterpret_cast<uint4*>(Gout + (size_t)node * 32) = o;
    }
}

// ---------------- bf16 width-64 propagation (layer 2): Gout = A * Gin ----------------
__global__ __launch_bounds__(256) void prop64b_kernel(const int* __restrict__ row_start,
                                                      const int* __restrict__ cursor,
                                                      const unsigned* __restrict__ erec,
                                                      const unsigned short* __restrict__ Gin,
                                                      unsigned short* __restrict__ Gout, int n) {
    constexpr int TPN = 8, ES = 4, TEAM = 32, NPB = 8;
    __shared__ unsigned se[CH];
    int tid = threadIdx.x;
    int nb = blockIdx.x * NPB;
    int node = nb + tid / TEAM;
    int t = tid % TEAM;
    int es = t / TPN;
    int lane = t % TPN;
    int nbEnd = (nb + NPB < n) ? (nb + NPB) : n;
    int bkt = nb >> 7;
    int cc = cursor[bkt]; if (cc > CAP) cc = CAP;
    int ce = bkt * CAP + cc;
    int blkBeg = row_start[nb];
    int blkEnd = row_start[nbEnd]; if (blkEnd > ce) blkEnd = ce;
    int beg = 0, end = 0;
    if (node < n) {
        beg = row_start[node];
        end = row_start[node + 1]; if (end > ce) end = ce;
    }
    float a0 = 0.f, a1 = 0.f, a2 = 0.f, a3 = 0.f, a4 = 0.f, a5 = 0.f, a6 = 0.f, a7 = 0.f;
    for (int base = blkBeg; base < blkEnd; base += CH) {
        int m = blkEnd - base; if (m > CH) m = CH;
        __syncthreads();
        for (int i = tid; i < m; i += 256) se[i] = erec[base + i];
        __syncthreads();
        int lo = (beg > base) ? (beg - base) : 0;
        int hi = ((end < base + m) ? end : (base + m)) - base;
        for (int i = lo + es; i < hi; i += ES) {
            unsigned e = se[i];
            float w = f16f(e >> 16);
            const uint4 v = *reinterpret_cast<const uint4*>(Gin + (size_t)(e & 0xFFFF) * 256 + lane * 8);
            a0 += w * bflo(v.x); a1 += w * bfhi(v.x);
            a2 += w * bflo(v.y); a3 += w * bfhi(v.y);
            a4 += w * bflo(v.z); a5 += w * bfhi(v.z);
            a6 += w * bflo(v.w); a7 += w * bfhi(v.w);
        }
    }
    #pragma unroll
    for (int msk = TPN; msk < TEAM; msk <<= 1) {
        a0 += __shfl_xor(a0, msk); a1 += __shfl_xor(a1, msk);
        a2 += __shfl_xor(a2, msk); a3 += __shfl_xor(a3, msk);
        a4 += __shfl_xor(a4, msk); a5 += __shfl_xor(a5, msk);
        a6 += __shfl_xor(a6, msk); a7 += __shfl_xor(a7, msk);
    }
    if (node < n && es == 0) {
        uint4 o;
        o.x = packbf2(a0, a1);
        o.y = packbf2(a2, a3);
        o.z = packbf2(a4, a5);
        o.w = packbf2(a6, a7);
        *reinterpret_cast<uint4*>(Gout + (size_t)node * 256 + lane * 8) = o;
    }
}

// ---------------- bf16 width-16 Horner propagation: Tout += A * Tin ----------------
// Rows are contiguous N x 16 bf16 chunks (32 B). TPN=2 x ES=8 teams.
__global__ __launch_bounds__(256) void prop16b_kernel(const int* __restrict__ row_start,
                                                      const int* __restrict__ cursor,
                                                      const unsigned* __restrict__ erec,
                                                      const unsigned short* __restrict__ Tin,
                                                      unsigned short* __restrict__ Tout, int n) {
    constexpr int TPN = 2, ES = 8, TEAM = 16, NPB = 16;
    __shared__ unsigned se[CH];
    int tid = threadIdx.x;
    int nb = blockIdx.x * NPB;
    int node = nb + tid / TEAM;
    int t = tid % TEAM;
    int es = t / TPN;
    int lane = t % TPN;
    int nbEnd = (nb + NPB < n) ? (nb + NPB) : n;
    int bkt = nb >> 7;
    int cc = cursor[bkt]; if (cc > CAP) cc = CAP;
    int ce = bkt * CAP + cc;
    int blkBeg = row_start[nb];
    int blkEnd = row_start[nbEnd]; if (blkEnd > ce) blkEnd = ce;
    int beg = 0, end = 0;
    if (node < n) {
        beg = row_start[node];
        end = row_start[node + 1]; if (end > ce) end = ce;
    }
    float a0 = 0.f, a1 = 0.f, a2 = 0.f, a3 = 0.f, a4 = 0.f, a5 = 0.f, a6 = 0.f, a7 = 0.f;
    for (int base = blkBeg; base < blkEnd; base += CH) {
        int m = blkEnd - base; if (m > CH) m = CH;
        __syncthreads();
        for (int i = tid; i < m; i += 256) se[i] = erec[base + i];
        __syncthreads();
        int lo = (beg > base) ? (beg - base) : 0;
        int hi = ((end < base + m) ? end : (base + m)) - base;
        for (int i = lo + es; i < hi; i += ES) {
            unsigned e = se[i];
            float w = f16f(e >> 16);
            const uint4 v = *reinterpret_cast<const uint4*>(Tin + (size_t)(e & 0xFFFF) * 16 + lane * 8);
            a0 += w * bflo(v.x); a1 += w * bfhi(v.x);
            a2 += w * bflo(v.y); a3 += w * bfhi(v.y);
            a4 += w * bflo(v.z); a5 += w * bfhi(v.z);
            a6 += w * bflo(v.w); a7 += w * bfhi(v.w);
        }
    }
    #pragma unroll
    for (int msk = TPN; msk < TEAM; msk <<= 1) {
        a0 += __shfl_xor(a0, msk); a1 += __shfl_xor(a1, msk);
        a2 += __shfl_xor(a2, msk); a3 += __shfl_xor(a3, msk);
        a4 += __shfl_xor(a4, msk); a5 += __shfl_xor(a5, msk);
        a6 += __shfl_xor(a6, msk); a7 += __shfl_xor(a7, msk);
    }
    if (node < n && es == 0) {
        uint4* po = reinterpret_cast<uint4*>(Tout + (size_t)node * 16 + lane * 8);
        uint4 old = *po;
        a0 += bflo(old.x); a1 += bfhi(old.x);
        a2 += bflo(old.y); a3 += bfhi(old.y);
        a4 += bflo(old.z); a5 += bfhi(old.z);
        a6 += bflo(old.w); a7 += bfhi(old.w);
        uint4 o;
        o.x = packbf2(a0, a1);
        o.y = packbf2(a2, a3);
        o.z = packbf2(a4, a5);
        o.w = packbf2(a6, a7);
        *po = o;
    }
}

// ---------------- final: out = log_softmax(g0 + A*t1 + b3), bf16 chunks ----------------
__global__ __launch_bounds__(256) void prop16b_final_kernel(const int* __restrict__ row_start,
                                                            const int* __restrict__ cursor,
                                                            const unsigned* __restrict__ erec,
                                                            const unsigned short* __restrict__ hin,
                                                            const unsigned short* __restrict__ g0,
                                                            const float* __restrict__ b3,
                                                            float* __restrict__ out, int n) {
    constexpr int TPN = 2, ES = 8, TEAM = 16, NPB = 16;
    __shared__ unsigned se[CH];
    int tid = threadIdx.x;
    int nb = blockIdx.x * NPB;
    int node = nb + tid / TEAM;
    int t = tid % TEAM;
    int es = t / TPN;
    int lane = t % TPN;
    int nbEnd = (nb + NPB < n) ? (nb + NPB) : n;
    int bkt = nb >> 7;
    int cc = cursor[bkt]; if (cc > CAP) cc = CAP;
    int ce = bkt * CAP + cc;
    int blkBeg = row_start[nb];
    int blkEnd = row_start[nbEnd]; if (blkEnd > ce) blkEnd = ce;
    int beg = 0, end = 0;
    if (node < n) {
        beg = row_start[node];
        end = row_start[node + 1]; if (end > ce) end = ce;
    }
    float a0 = 0.f, a1 = 0.f, a2 = 0.f, a3 = 0.f, a4 = 0.f, a5 = 0.f, a6 = 0.f, a7 = 0.f;
    for (int base = blkBeg; base < blkEnd; base += CH) {
        int m = blkEnd - base; if (m > CH) m = CH;
        __syncthreads();
        for (int i = tid; i < m; i += 256) se[i] = erec[base + i];
        __syncthreads();
        int lo = (beg > base) ? (beg - base) : 0;
        int hi = ((end < base + m) ? end : (base + m)) - base;
        for (int i = lo + es; i < hi; i += ES) {
            unsigned e = se[i];
            float w = f16f(e >> 16);
            const uint4 v = *reinterpret_cast<const uint4*>(hin + (size_t)(e & 0xFFFF) * 16 + lane * 8);
            a0 += w * bflo(v.x); a1 += w * bfhi(v.x);
            a2 += w * bflo(v.y); a3 += w * bfhi(v.y);
            a4 += w * bflo(v.z); a5 += w * bfhi(v.z);
            a6 += w * bflo(v.w); a7 += w * bfhi(v.w);
        }
    }
    #pragma unroll
    for (int msk = TPN; msk < TEAM; msk <<= 1) {
        a0 += __shfl_xor(a0, msk); a1 += __shfl_xor(a1, msk);
        a2 += __shfl_xor(a2, msk); a3 += __shfl_xor(a3, msk);
        a4 += __shfl_xor(a4, msk); a5 += __shfl_xor(a5, msk);
        a6 += __shfl_xor(a6, msk); a7 += __shfl_xor(a7, msk);
    }
    if (node < n && es == 0) {
        const uint4 g = *reinterpret_cast<const uint4*>(g0 + (size_t)node * 16 + lane * 8);
        float vv[8] = {a0 + bflo(g.x), a1 + bfhi(g.x), a2 + bflo(g.y), a3 + bfhi(g.y),
                       a4 + bflo(g.z), a5 + bfhi(g.z), a6 + bflo(g.w), a7 + bfhi(g.w)};
        int c0 = lane * 8;
        float mloc = -1e30f;
        #pragma unroll
        for (int c = 0; c < 8; ++c) {
            int col = c0 + c;
            if (col < NOUT) { vv[c] += b3[col]; mloc = fmaxf(mloc, vv[c]); }
        }
        float mo = fmaxf(mloc, __shfl_xor(mloc, 1));
        float sl = 0.f;
        #pragma unroll
        for (int c = 0; c < 8; ++c) {
            int col = c0 + c;
            if (col < NOUT) sl += __expf(vv[c] - mo);
        }
        sl += __shfl_xor(sl, 1);
        float ls = __logf(sl);
        #pragma unroll
        for (int c = 0; c < 8; ++c) {
            int col = c0 + c;
            if (col < NOUT) out[(size_t)node * NOUT + col] = vv[c] - mo - ls;
        }
    }
}

// ---------------- MFMA layer-1 matmul: G0 = relu(B1 @ W1 + b1) as bf16 ----------------
__global__ __launch_bounds__(256) void mm1_kernel(const unsigned short* __restrict__ B1,
                                                  const float* __restrict__ W1,
                                                  const float* __restrict__ b1,
                                                  unsigned short* __restrict__ G, int n) {
    __shared__ unsigned short w1s[2048];   // [t(4)][lane(64)][8] bf16 = 4 KB
    __shared__ unsigned short hs[64 * 64]; // h1 tile bf16 [nodeLocal][col] = 8 KB
    int tid = threadIdx.x;
    int wave = tid >> 6;
    int lane = tid & 63;
    int nodeBase = blockIdx.x * 64;

    {
        int l = tid & 63;
        int t = tid >> 6;
        int k0 = (l >> 4) << 3;
        int col = t * 16 + (l & 15);
        unsigned short tmp[8];
        #pragma unroll
        for (int j = 0; j < 8; ++j)
            tmp[j] = (unsigned short)bf16rnd(W1[(size_t)(k0 + j) * 64 + col]);
        *reinterpret_cast<uint4*>(w1s + tid * 8) = *reinterpret_cast<const uint4*>(tmp);
    }
    __syncthreads();

    int arow = nodeBase + wave * 16 + (lane & 15);
    bf16x8 a = {};
    if (arow < n)
        a = *reinterpret_cast<const bf16x8*>(B1 + (size_t)arow * 32 + ((lane >> 4) << 3));
    const unsigned short* wb = w1s + lane * 8;
    f32x4 acc0 = {0.f, 0.f, 0.f, 0.f}, acc1 = {0.f, 0.f, 0.f, 0.f};
    f32x4 acc2 = {0.f, 0.f, 0.f, 0.f}, acc3 = {0.f, 0.f, 0.f, 0.f};
    acc0 = __builtin_amdgcn_mfma_f32_16x16x32_bf16(a, *reinterpret_cast<const bf16x8*>(wb),        acc0, 0, 0, 0);
    acc1 = __builtin_amdgcn_mfma_f32_16x16x32_bf16(a, *reinterpret_cast<const bf16x8*>(wb + 512),  acc1, 0, 0, 0);
    acc2 = __builtin_amdgcn_mfma_f32_16x16x32_bf16(a, *reinterpret_cast<const bf16x8*>(wb + 1024), acc2, 0, 0, 0);
    acc3 = __builtin_amdgcn_mfma_f32_16x16x32_bf16(a, *reinterpret_cast<const bf16x8*>(wb + 1536), acc3, 0, 0, 0);

    {
        int c = lane & 15;
        int rbase = wave * 16 + (lane >> 4) * 4;
        f32x4 accs[4] = {acc0, acc1, acc2, acc3};
        #pragma unroll
        for (int t = 0; t < 4; ++t) {
            int col = t * 16 + c;
            float bb = b1[col];
            #pragma unroll
            for (int r = 0; r < 4; ++r) {
                float v = accs[t][r] + bb;
                hs[(rbase + r) * 64 + col] = (unsigned short)bf16rnd(v > 0.f ? v : 0.f);
            }
        }
    }
    __syncthreads();
    for (int i = tid; i < 512; i += 256) {
        int nd = i >> 3, ch = i & 7;
        int node = nodeBase + nd;
        if (node < n)
            *reinterpret_cast<uint4*>(G + (size_t)node * 256 + ch * 8) =
                *reinterpret_cast<const uint4*>(hs + nd * 64 + ch * 8);
    }
}

// ---------------- fused mm2+mm3 with MFMA phase 1; bf16 chunk-major T output ----------------
__global__ __launch_bounds__(256) void mm23_kernel(const unsigned short* __restrict__ G,
                                                   const float* __restrict__ W2,
                                                   const float* __restrict__ b2,
                                                   const float* __restrict__ W3,
                                                   unsigned short* __restrict__ Tb, int n) {
    constexpr int HP = 68;
    __shared__ __align__(16) char smem[33792];
    unsigned short* w2s = (unsigned short*)smem;              // phase1: 32768 B
    float* HsT = (float*)smem;                                // phase2: 17408 B
    float* Ws  = (float*)(smem + 64 * HP * 4);                // phase2: 16384 B
    int tid = threadIdx.x;
    int wave = tid >> 6;
    int lane = tid & 63;
    int nodeBase = blockIdx.x * 64;

    for (int slot = tid; slot < 2048; slot += 256) {
        int l = slot & 63;
        int s = (slot >> 6) & 7;
        int t = slot >> 9;
        int k0 = s * 32 + ((l >> 4) << 3);
        int col = t * 16 + (l & 15);
        unsigned short tmp[8];
        #pragma unroll
        for (int j = 0; j < 8; ++j)
            tmp[j] = (unsigned short)bf16rnd(W2[(size_t)(k0 + j) * 64 + col]);
        *reinterpret_cast<uint4*>(w2s + slot * 8) = *reinterpret_cast<const uint4*>(tmp);
    }
    __syncthreads();

    int arow = nodeBase + wave * 16 + (lane & 15);
    bool aval = (arow < n);
    const unsigned short* arp = G + (size_t)arow * 256 + ((lane >> 4) << 3);
    f32x4 acc0 = {0.f, 0.f, 0.f, 0.f}, acc1 = {0.f, 0.f, 0.f, 0.f};
    f32x4 acc2 = {0.f, 0.f, 0.f, 0.f}, acc3 = {0.f, 0.f, 0.f, 0.f};
    #pragma unroll
    for (int s = 0; s < 8; ++s) {
        bf16x8 a = {};
        if (aval) a = *reinterpret_cast<const bf16x8*>(arp + s * 32);
        const unsigned short* wb = w2s + ((size_t)s * 64 + lane) * 8;
        bf16x8 bf0 = *reinterpret_cast<const bf16x8*>(wb);
        bf16x8 bf1 = *reinterpret_cast<const bf16x8*>(wb + 4096);
        bf16x8 bf2 = *reinterpret_cast<const bf16x8*>(wb + 8192);
        bf16x8 bf3 = *reinterpret_cast<const bf16x8*>(wb + 12288);
        acc0 = __builtin_amdgcn_mfma_f32_16x16x32_bf16(a, bf0, acc0, 0, 0, 0);
        acc1 = __builtin_amdgcn_mfma_f32_16x16x32_bf16(a, bf1, acc1, 0, 0, 0);
        acc2 = __builtin_amdgcn_mfma_f32_16x16x32_bf16(a, bf2, acc2, 0, 0, 0);
        acc3 = __builtin_amdgcn_mfma_f32_16x16x32_bf16(a, bf3, acc3, 0, 0, 0);
    }
    __syncthreads();

    {
        int c = lane & 15;
        int rbase = wave * 16 + (lane >> 4) * 4;
        f32x4 accs[4] = {acc0, acc1, acc2, acc3};
        #pragma unroll
        for (int t = 0; t < 4; ++t) {
            int col = t * 16 + c;
            float bb = b2[col];
            #pragma unroll
            for (int r = 0; r < 4; ++r) {
                float v = accs[t][r] + bb;
                HsT[col * HP + rbase + r] = v > 0.f ? v : 0.f;
            }
        }
    }
    for (int i = tid; i < 64 * 64; i += 256) {
        int r = i >> 6, c2 = i & 63;
        int k = c2 >> 4, j = c2 & 15;
        Ws[i] = (j < NOUT) ? W3[((size_t)k * 64 + r) * NOUT + j] : 0.f;
    }
    __syncthreads();

    int ndq = tid >> 4;
    int f4  = tid & 15;
    float4 t0 = make_float4(0.f, 0.f, 0.f, 0.f);
    float4 t1 = make_float4(0.f, 0.f, 0.f, 0.f);
    float4 t2 = make_float4(0.f, 0.f, 0.f, 0.f);
    float4 t3 = make_float4(0.f, 0.f, 0.f, 0.f);
    #pragma unroll 8
    for (int k = 0; k < 64; ++k) {
        const float4 hq = *reinterpret_cast<const float4*>(&HsT[k * HP + ndq * 4]);
        const float4 wq = *reinterpret_cast<const float4*>(&Ws[k * 64 + f4 * 4]);
        t0.x += hq.x * wq.x; t0.y += hq.x * wq.y; t0.z += hq.x * wq.z; t0.w += hq.x * wq.w;
        t1.x += hq.y * wq.x; t1.y += hq.y * wq.y; t1.z += hq.y * wq.z; t1.w += hq.y * wq.w;
        t2.x += hq.z * wq.x; t2.y += hq.z * wq.y; t2.z += hq.z * wq.z; t2.w += hq.z * wq.w;
        t3.x += hq.w * wq.x; t3.y += hq.w * wq.y; t3.z += hq.w * wq.z; t3.w += hq.w * wq.w;
    }
    // write bf16 chunk-major: col c = k*16+j -> Tb[k*N16 + node*16 + j]
    int kc = f4 >> 2;
    int j0 = (f4 & 3) * 4;
    float4 ts[4] = {t0, t1, t2, t3};
    #pragma unroll
    for (int i = 0; i < 4; ++i) {
        int node = nodeBase + ndq * 4 + i;
        if (node < n) {
            uint2 o;
            o.x = packbf2(ts[i].x, ts[i].y);
            o.y = packbf2(ts[i].z, ts[i].w);
            *reinterpret_cast<uint2*>(Tb + (size_t)kc * N16 + (size_t)node * 16 + j0) = o;
        }
    }
}

extern "C" void kernel_launch(void* const* d_in, const int* in_sizes, int n_in,
                              void* d_out, int out_size, void* d_ws, size_t ws_size,
                              hipStream_t stream) {
    const float* x   = (const float*)d_in[0];
    const float* pos = (const float*)d_in[1];
    const float* ea  = (const float*)d_in[2];
    const float* W1  = (const float*)d_in[3];   // (4,8,64) == (32,64)
    const float* b1  = (const float*)d_in[4];
    const float* W2  = (const float*)d_in[5];   // (4,64,64) == (256,64)
    const float* b2  = (const float*)d_in[6];
    const float* W3  = (const float*)d_in[7];   // (4,64,10)
    const float* b3  = (const float*)d_in[8];
    const int* eidx  = (const int*)d_in[9];
    const int* src = eidx;
    const int* dst = eidx + EE;
    float* outp = (float*)d_out;

    size_t off = 0;
    char* base = (char*)d_ws;
    auto alloc = [&](size_t bytes) -> void* {
        void* p = base + off;
        off += (bytes + 255) & ~(size_t)255;
        return p;
    };
    int*   cursor    = (int*)alloc(NB * 4);
    int*   row_start = (int*)alloc((NN + 1) * 4);
    float* dinv      = (float*)alloc(NN * 4);
    int2*  regions   = (int2*)alloc((size_t)NB * CAP * 8);        // 8B scatter records
    unsigned* erec   = (unsigned*)alloc((size_t)NB * CAP * 4);    // 4B final records
    unsigned short* G  = (unsigned short*)alloc((size_t)NN * 256 * 2); // bf16 [h1|Ah1|A2h1|A3h1]
    unsigned short* B1 = (unsigned short*)alloc((size_t)NN * 32 * 2);  // bf16 [h0|Ah0|A2h0|A3h0]
    unsigned short* Tb = (unsigned short*)alloc((size_t)NN * 64 * 2);  // bf16 4 x (N x 16) chunks
    (void)ws_size;

    const int B = 256;
    const int gN = (NN + B - 1) / B;
    const int gK1 = (EE + K1_EPB - 1) / K1_EPB;      // 391
    const int gMM2 = (NN + 63) / 64;                 // 782
    const int gP32 = (NN + 31) / 32;                 // 1563 (TEAM=8,  NPB=32)
    const int gP16 = (NN + 15) / 16;                 // 3125 (TEAM=16, NPB=16)
    const int gP8  = (NN + 7) / 8;                   // 6250 (TEAM=32, NPB=8)

    hipMemsetAsync(cursor, 0, NB * 4, stream);

    // ---- CSR build (bucketed, atomic-light) ----
    bucket_scatter_kernel<<<gK1, 512, 0, stream>>>(src, dst, ea, cursor, regions, EE);
    bucket_build_kernel<<<NB, 512, 0, stream>>>(cursor, regions, erec, dinv, row_start, NN);

    // ---- layer 1 (bf16): B1 = [h0|Ah0|A2h0|A3h0]; h1 = relu(B1@W1+b1) -> G chunk0 ----
    pack1_kernel<<<gN, B, 0, stream>>>(x, pos, B1, NN);
    prop8b_kernel<1><<<gP32, B, 0, stream>>>(row_start, cursor, erec, dinv, B1,      B1 + 8,  NN);
    prop8b_kernel<0><<<gP32, B, 0, stream>>>(row_start, cursor, erec, dinv, B1 + 8,  B1 + 16, NN);
    prop8b_kernel<0><<<gP32, B, 0, stream>>>(row_start, cursor, erec, dinv, B1 + 16, B1 + 24, NN);
    mm1_kernel<<<gMM2, B, 0, stream>>>(B1, W1, b1, G, NN);

    // ---- layer 2 (bf16): G chunks 1..3 = A^k h1; Tb = (relu(G@W2+b2)) @ W3pad (fused MFMA) ----
    prop64b_kernel<<<gP8, B, 0, stream>>>(row_start, cursor, erec, G,       G + 64,  NN);
    prop64b_kernel<<<gP8, B, 0, stream>>>(row_start, cursor, erec, G + 64,  G + 128, NN);
    prop64b_kernel<<<gP8, B, 0, stream>>>(row_start, cursor, erec, G + 128, G + 192, NN);
    mm23_kernel<<<gMM2, B, 0, stream>>>(G, W2, b2, W3, Tb, NN);

    // ---- layer 3 (Horner, bf16 chunks): t2 = G2 + A*G3 ; t1 = G1 + A*t2 ; out = lsm(G0 + A*t1 + b3) ----
    prop16b_kernel<<<gP16, B, 0, stream>>>(row_start, cursor, erec, Tb + 3 * N16, Tb + 2 * N16, NN);
    prop16b_kernel<<<gP16, B, 0, stream>>>(row_start, cursor, erec, Tb + 2 * N16, Tb + 1 * N16, NN);
    prop16b_final_kernel<<<gP16, B, 0, stream>>>(row_start, cursor, erec, Tb + 1 * N16, Tb, b3, outp, NN);
}